// Round 4
// baseline (8070.403 us; speedup 1.0000x reference)
//
#include <hip/hip_runtime.h>
#include <hip/hip_bf16.h>
#include <math.h>

// Problem constants
#define A_DIM 1024      // NB_ATOMS
#define D_DIM 768       // 3*16*16
#define B_DIM 16384     // BATCH
#define TEMP_C 100.0f
#define EPS_C 1e-8f

// Round 10: 256^2 double-buffered pipelined GEMM core (T3+T4 + LDS swizzle)
// for the three K=1024 GEMMs (nondiff fused_grad -> gemm256<0>, diff
// gemm_single<1,2> -> gemm256<1,2>).
//  - 256 blocks (1/CU), 512 threads (8 waves, 2Mx4N), BK=32, LDS dbuf:
//    128 KB (pair-A) / 96 KB (single-A).
//  - stage(t+1) issued at TOP of iteration t via global_load_lds; ONE counted
//    s_waitcnt vmcnt(8|6) (never 0 mid-loop) + raw s_barrier pair per K-step;
//    no compiler-forced vmcnt(0) drains (the ~36% stall in the round-9 PMC:
//    MfmaUtil 34%, VALUBusy 30%, HBM 14% -> schedule-bound).
//  - LDS chunk swizzle c ^= (row>>1)&3 applied on the GLOBAL source (linear
//    LDS dest, per global_load_lds constraint) and on the frag read.
//  - per-fragment accumulation order bitwise-identical to round 9 (same K
//    order, same hh/hl/lh order); epilogue column partition identical
//    (16 chunks of 64) -> same verified semantics (absmax 4.88e-4).
//  - qt_mfma / mfma_recon / setup / small kernels unchanged from round 9.

typedef __attribute__((ext_vector_type(8))) short short8;
typedef __attribute__((ext_vector_type(4))) float f32x4;
#define MFMA16(a, b, c) __builtin_amdgcn_mfma_f32_16x16x32_bf16(a, b, c, 0, 0, 0)

typedef __attribute__((address_space(3))) unsigned char lds_byte;
typedef __attribute__((address_space(1))) const unsigned char g_byte;
__device__ __forceinline__ void async_copy16(const void* gptr, void* lptr) {
    __builtin_amdgcn_global_load_lds((g_byte*)gptr, (lds_byte*)lptr, 16, 0, 0);
}

// XCD-slab swizzle for 1024-block GEMM grids (qt_mfma only)
__device__ __forceinline__ void swz(int i, int& m0, int& n0) {
    int xcd = i & 7, j = i >> 3;
    m0 = ((xcd << 4) + (j >> 3)) << 7;
    n0 = (j & 7) << 7;
}

// ---------------- reductions (wave shuffle + tiny LDS combine) ----------------

__device__ __forceinline__ float wave_sum(float v) {
#pragma unroll
    for (int m = 1; m < 64; m <<= 1) v += __shfl_xor(v, m);
    return v;
}
__device__ __forceinline__ float wave_max(float v) {
#pragma unroll
    for (int m = 1; m < 64; m <<= 1) v = fmaxf(v, __shfl_xor(v, m));
    return v;
}

// red must hold >= 12 floats; 256-thread blocks (4 waves)
__device__ __forceinline__ float block_reduce_sum(float v, float* red) {
    int t = threadIdx.x;
    v = wave_sum(v);
    if ((t & 63) == 0) red[t >> 6] = v;
    __syncthreads();
    float r = red[0] + red[1] + red[2] + red[3];
    __syncthreads();
    return r;
}

__device__ __forceinline__ float block_reduce_max(float v, float* red) {
    int t = threadIdx.x;
    v = wave_max(v);
    if ((t & 63) == 0) red[t >> 6] = v;
    __syncthreads();
    float r = fmaxf(fmaxf(red[0], red[1]), fmaxf(red[2], red[3]));
    __syncthreads();
    return r;
}

// fused 3-way sum (single barrier pair) for stats_kernel
__device__ __forceinline__ void block_reduce_sum3(float& a, float& b, float& c, float* red) {
    int t = threadIdx.x;
    a = wave_sum(a);
    b = wave_sum(b);
    c = wave_sum(c);
    if ((t & 63) == 0) {
        int w = t >> 6;
        red[w] = a; red[4 + w] = b; red[8 + w] = c;
    }
    __syncthreads();
    a = red[0] + red[1] + red[2] + red[3];
    b = red[4] + red[5] + red[6] + red[7];
    c = red[8] + red[9] + red[10] + red[11];
    __syncthreads();
}

// ---------------- small helpers ----------------

__device__ __forceinline__ unsigned int fkey(float v) {
    unsigned int u = __float_as_uint(v);
    return u ^ ((u & 0x80000000u) ? 0xFFFFFFFFu : 0x80000000u);
}

__device__ __forceinline__ unsigned short f2bf(float x) {
    unsigned int u = __float_as_uint(x);
    return (unsigned short)((u + 0x7FFFu + ((u >> 16) & 1u)) >> 16);
}
__device__ __forceinline__ float bf2f(unsigned short h) {
    return __uint_as_float(((unsigned int)h) << 16);
}
__device__ __forceinline__ void split2(float x, unsigned short& hi, unsigned short& lo) {
    hi = f2bf(x);
    lo = f2bf(x - bf2f(hi));
}

// ---------------- 128^2 MFMA building blocks (qt_mfma / mfma_recon) ----------------

__device__ __forceinline__ void stage_tile8(const unsigned short* gsrc, int stride, int k0,
                                            unsigned short* ltile, int lane) {
    int srow = lane >> 2;
    int scol = (lane & 3) * 8;
#pragma unroll
    for (int s = 0; s < 8; s++) {
        const unsigned short* src = gsrc + (size_t)(s * 16 + srow) * stride + k0 + scol;
        async_copy16(src, ltile + s * 512);
    }
}

// 3-product (pair x pair) K=32 step
__device__ __forceinline__ void mfma_k32(const unsigned short* lds, int wm, int wn, int lane,
                                         f32x4 acc[4][4]) {
    int frow = lane & 15, fk = (lane >> 4) * 8;
    short8 ah[4], al[4], bh[4], bl[4];
#pragma unroll
    for (int t = 0; t < 4; t++) {
        int ar = (wm * 64 + t * 16 + frow) * 32 + fk;
        ah[t] = *(const short8*)&lds[ar];
        al[t] = *(const short8*)&lds[4096 + ar];
        int br = (wn * 64 + t * 16 + frow) * 32 + fk;
        bh[t] = *(const short8*)&lds[8192 + br];
        bl[t] = *(const short8*)&lds[12288 + br];
    }
#pragma unroll
    for (int i = 0; i < 4; i++)
#pragma unroll
        for (int j = 0; j < 4; j++) {
            acc[i][j] = MFMA16(ah[i], bh[j], acc[i][j]);
            acc[i][j] = MFMA16(ah[i], bl[j], acc[i][j]);
            acc[i][j] = MFMA16(al[i], bh[j], acc[i][j]);
        }
}

// ---------------- 256^2 pipelined GEMM core ----------------
// MODE 0: A = pair (Chi,Clo), 3 products, nondiff epilogue (argmin/cxc/cq)
// MODE 1: A = single hi, 2 products, epilogue G = acc - qt
// MODE 2: A = single hi, 2 products, epilogue scal3 += sum(acc * (Ahi+Alo pair))

template <int MODE>
__device__ __forceinline__ void stage256(unsigned short* buf,
                                         const unsigned short* Ahi,
                                         const unsigned short* Alo,
                                         const unsigned short* Xhi,
                                         const unsigned short* Xlo,
                                         int m0, int n0, int k0, int t) {
    constexpr int AHI = 0;
    constexpr int ALO = 8192;
    constexpr int BHI = (MODE == 0) ? 16384 : 8192;
    constexpr int BLO = BHI + 8192;
    int r = t >> 2;                       // LDS row 0..127 (and +128 for s=1)
    int cg = (t & 3) ^ ((t >> 3) & 3);    // pre-swizzled source chunk = (t&3)^((r>>1)&3)
    size_t col = (size_t)k0 + cg * 8;
    async_copy16(Ahi + (size_t)(m0 + r) * A_DIM + col,       buf + AHI + t * 8);
    async_copy16(Ahi + (size_t)(m0 + 128 + r) * A_DIM + col, buf + AHI + 4096 + t * 8);
    if constexpr (MODE == 0) {
        async_copy16(Alo + (size_t)(m0 + r) * A_DIM + col,       buf + ALO + t * 8);
        async_copy16(Alo + (size_t)(m0 + 128 + r) * A_DIM + col, buf + ALO + 4096 + t * 8);
    }
    async_copy16(Xhi + (size_t)(n0 + r) * A_DIM + col,       buf + BHI + t * 8);
    async_copy16(Xhi + (size_t)(n0 + 128 + r) * A_DIM + col, buf + BHI + 4096 + t * 8);
    async_copy16(Xlo + (size_t)(n0 + r) * A_DIM + col,       buf + BLO + t * 8);
    async_copy16(Xlo + (size_t)(n0 + 128 + r) * A_DIM + col, buf + BLO + 4096 + t * 8);
}

template <int MODE>
__device__ __forceinline__ void mfma_step256(const unsigned short* buf, int wm, int wn,
                                             int lane, f32x4 acc[8][4]) {
    constexpr int AHI = 0;
    constexpr int ALO = 8192;
    constexpr int BHI = (MODE == 0) ? 16384 : 8192;
    constexpr int BLO = BHI + 8192;
    int frow = lane & 15;
    int sw = ((lane >> 4) ^ ((frow >> 1) & 3)) * 8;   // read-side chunk swizzle
    short8 bh[4], bl[4];
#pragma unroll
    for (int j = 0; j < 4; j++) {
        int br = wn * 64 + j * 16 + frow;
        bh[j] = *(const short8*)&buf[BHI + br * 32 + sw];
        bl[j] = *(const short8*)&buf[BLO + br * 32 + sw];
    }
#pragma unroll
    for (int mi = 0; mi < 8; mi++) {
        int ar = wm * 128 + mi * 16 + frow;
        short8 ah = *(const short8*)&buf[AHI + ar * 32 + sw];
        if constexpr (MODE == 0) {
            short8 al = *(const short8*)&buf[ALO + ar * 32 + sw];
#pragma unroll
            for (int j = 0; j < 4; j++) {
                acc[mi][j] = MFMA16(ah, bh[j], acc[mi][j]);
                acc[mi][j] = MFMA16(ah, bl[j], acc[mi][j]);
                acc[mi][j] = MFMA16(al, bh[j], acc[mi][j]);
            }
        } else {
#pragma unroll
            for (int j = 0; j < 4; j++) {
                acc[mi][j] = MFMA16(ah, bh[j], acc[mi][j]);
                acc[mi][j] = MFMA16(ah, bl[j], acc[mi][j]);
            }
        }
    }
}

template <int MODE>
__global__ __launch_bounds__(512, 2) void gemm256(const unsigned short* __restrict__ Ahi,
                                                  const unsigned short* __restrict__ Alo,
                                                  const unsigned short* __restrict__ Xhi,
                                                  const unsigned short* __restrict__ Xlo,
                                                  const float* __restrict__ qt,
                                                  unsigned long long* __restrict__ keys,
                                                  float* __restrict__ cxc,
                                                  float* __restrict__ cq,
                                                  float* __restrict__ scal,
                                                  float* __restrict__ G,
                                                  float* __restrict__ scal3) {
    constexpr int BUFS = (MODE == 0) ? 32768 : 24576;   // shorts per buffer
    __shared__ unsigned short lds[2 * BUFS];
    __shared__ float red[8];
    int tid = threadIdx.x;
    if (MODE == 0 && blockIdx.x == 0 && tid < 4) scal[tid] = 0.f;
    int w = tid >> 6, lane = tid & 63;
    int wm = w >> 2, wn = w & 3;          // 2 x 4 wave grid
    // XCD-bijective swizzle over 256 blocks: xcd owns an 8-m-slab x 4-n stripe
    int bi = blockIdx.x;
    int xcd = bi & 7, bj = bi >> 3;
    int m0 = ((xcd << 3) + (bj >> 2)) << 8;
    int n0 = (bj & 3) << 8;

    f32x4 acc[8][4];
#pragma unroll
    for (int i = 0; i < 8; i++)
#pragma unroll
        for (int j = 0; j < 4; j++) acc[i][j] = f32x4{0.f, 0.f, 0.f, 0.f};

    // prologue: stage K-step 0 into buf0
    stage256<MODE>(lds, Ahi, Alo, Xhi, Xlo, m0, n0, 0, tid);
    int cur = 0;
    for (int ks = 0; ks < 32; ++ks) {
        if (ks < 31)
            stage256<MODE>(lds + (cur ^ 1) * BUFS, Ahi, Alo, Xhi, Xlo,
                           m0, n0, (ks + 1) * 32, tid);
        // wait for buf[cur]'s loads (older than the just-issued prefetch)
        if (ks < 31) {
            if constexpr (MODE == 0) asm volatile("s_waitcnt vmcnt(8)" ::: "memory");
            else                     asm volatile("s_waitcnt vmcnt(6)" ::: "memory");
        } else {
            asm volatile("s_waitcnt vmcnt(0)" ::: "memory");
        }
        __builtin_amdgcn_sched_barrier(0);
        asm volatile("s_barrier" ::: "memory");    // buf[cur] ready for all waves
        __builtin_amdgcn_sched_barrier(0);
        mfma_step256<MODE>(lds + cur * BUFS, wm, wn, lane, acc);
        __builtin_amdgcn_sched_barrier(0);
        asm volatile("s_barrier" ::: "memory");    // all waves done reading buf[cur]
        __builtin_amdgcn_sched_barrier(0);
        cur ^= 1;
    }

    int crow = (lane >> 4) * 4, ccol = lane & 15;
    if constexpr (MODE == 0) {
        unsigned long long best[4] = {~0ULL, ~0ULL, ~0ULL, ~0ULL};
#pragma unroll
        for (int mi = 0; mi < 8; mi++)
#pragma unroll
            for (int r = 0; r < 4; r++) {
                int gm = m0 + wm * 128 + mi * 16 + crow + r;
                float pcx = 0.f, pcq = 0.f;
#pragma unroll
                for (int jj = 0; jj < 4; jj++) {
                    int gn = n0 + wn * 64 + jj * 16 + ccol;
                    size_t idx = (size_t)gm * A_DIM + gn;
                    float c = bf2f(Ahi[idx]) + bf2f(Alo[idx]);
                    float q = qt[idx];
                    float xc = acc[mi][jj][r];
                    pcx += c * xc;
                    pcq += c * q;
                    unsigned long long key =
                        ((unsigned long long)fkey(xc - q) << 32) | (unsigned int)gm;
                    if (key < best[jj]) best[jj] = key;
                }
                for (int mm = 1; mm < 16; mm <<= 1) {
                    pcx += __shfl_xor(pcx, mm, 16);
                    pcq += __shfl_xor(pcq, mm, 16);
                }
                if (ccol == 0) {
                    atomicAdd(&cxc[gm], pcx);
                    atomicAdd(&cq[gm], pcq);
                }
            }
#pragma unroll
        for (int jj = 0; jj < 4; jj++) {
            int gn = n0 + wn * 64 + jj * 16 + ccol;
            unsigned long long o = __shfl_xor(best[jj], 16);
            if (o < best[jj]) best[jj] = o;
            o = __shfl_xor(best[jj], 32);
            if (o < best[jj]) best[jj] = o;
            if ((lane >> 4) == 0) atomicMin(&keys[gn], best[jj]);
        }
    } else if constexpr (MODE == 1) {
#pragma unroll
        for (int mi = 0; mi < 8; mi++)
#pragma unroll
            for (int r = 0; r < 4; r++) {
                int gm = m0 + wm * 128 + mi * 16 + crow + r;
#pragma unroll
                for (int jj = 0; jj < 4; jj++) {
                    int gn = n0 + wn * 64 + jj * 16 + ccol;
                    size_t idx = (size_t)gm * A_DIM + gn;
                    G[idx] = acc[mi][jj][r] - qt[idx];
                }
            }
    } else {
        float part = 0.f;
#pragma unroll
        for (int mi = 0; mi < 8; mi++)
#pragma unroll
            for (int r = 0; r < 4; r++) {
                int gm = m0 + wm * 128 + mi * 16 + crow + r;
#pragma unroll
                for (int jj = 0; jj < 4; jj++) {
                    int gn = n0 + wn * 64 + jj * 16 + ccol;
                    size_t idx = (size_t)gm * A_DIM + gn;
                    float d = bf2f(Ahi[idx]) + bf2f(Alo[idx]);
                    part += acc[mi][jj][r] * d;
                }
            }
        part = wave_sum(part);
        if (lane == 0) red[w] = part;
        __syncthreads();
        if (tid == 0) {
            float tot = red[0] + red[1] + red[2] + red[3] +
                        red[4] + red[5] + red[6] + red[7];
            atomicAdd(scal3, tot);
        }
    }
}

// ---------------- setup kernels ----------------

__global__ __launch_bounds__(256) void ynorm_kernel(const float* __restrict__ y,
                                                    float* __restrict__ ynorm) {
    __shared__ float red[16];
    int b = blockIdx.x;
    const float* row = y + (size_t)b * D_DIM;
    float s = 0.f;
    for (int i = threadIdx.x; i < D_DIM; i += 256) s += fabsf(row[i]);
    float tot = block_reduce_sum(s, red);
    if (threadIdx.x == 0) ynorm[b] = tot;
}

// Ynh/Ynl = split(y/ynorm)
__global__ __launch_bounds__(256) void yn_split_kernel(const float* __restrict__ y,
                                                       const float* __restrict__ ynorm,
                                                       unsigned short* __restrict__ Ynh,
                                                       unsigned short* __restrict__ Ynl) {
    int b = blockIdx.x;
    float inv = 1.f / ynorm[b];
    const float* row = y + (size_t)b * D_DIM;
    unsigned short* oh = Ynh + (size_t)b * D_DIM;
    unsigned short* ol = Ynl + (size_t)b * D_DIM;
    for (int i = threadIdx.x; i < D_DIM; i += 256) {
        unsigned short h, l;
        split2(row[i] * inv, h, l);
        oh[i] = h; ol[i] = l;
    }
}

__global__ __launch_bounds__(256) void anorm_kernel(const float* __restrict__ atoms,
                                                    float* __restrict__ an,
                                                    float* __restrict__ anrm,
                                                    unsigned short* __restrict__ Anh,
                                                    unsigned short* __restrict__ Anl) {
    __shared__ float red[16];
    int a = blockIdx.x;
    const float* row = atoms + (size_t)a * D_DIM;
    float s = 0.f;
    for (int i = threadIdx.x; i < D_DIM; i += 256) s += fabsf(row[i]);
    float tot = block_reduce_sum(s, red);
    float inv = 1.f / tot;
    for (int i = threadIdx.x; i < D_DIM; i += 256) {
        float v = row[i] * inv;
        an[(size_t)a * D_DIM + i] = v;
        unsigned short h, l;
        split2(v, h, l);
        Anh[(size_t)a * D_DIM + i] = h;
        Anl[(size_t)a * D_DIM + i] = l;
    }
    if (threadIdx.x == 0) anrm[a] = tot;
}

__global__ __launch_bounds__(256) void atrans_split_kernel(const float* __restrict__ atoms,
                                                           const float* __restrict__ anrm,
                                                           unsigned short* __restrict__ AnTh,
                                                           unsigned short* __restrict__ AnTl) {
    int n = blockIdx.x;
    for (int k = threadIdx.x; k < A_DIM; k += 256) {
        float v = atoms[(size_t)k * D_DIM + n] / anrm[k];
        unsigned short h, l;
        split2(v, h, l);
        AnTh[(size_t)n * A_DIM + k] = h;
        AnTl[(size_t)n * A_DIM + k] = l;
    }
}

__global__ __launch_bounds__(256) void split_kernel(const float* __restrict__ src,
                                                    unsigned short* __restrict__ hi,
                                                    unsigned short* __restrict__ lo,
                                                    int n4) {
    int i = blockIdx.x * 256 + threadIdx.x;
    if (i < n4) {
        float4 v = ((const float4*)src)[i];
        ushort4 h, l;
        split2(v.x, h.x, l.x);
        split2(v.y, h.y, l.y);
        split2(v.z, h.z, l.z);
        split2(v.w, h.w, l.w);
        ((ushort4*)hi)[i] = h;
        ((ushort4*)lo)[i] = l;
    }
}

__global__ __launch_bounds__(256) void fill_pair_kernel(unsigned short* __restrict__ Chi,
                                                        unsigned short* __restrict__ Clo,
                                                        size_t n4) {
    size_t i = (size_t)blockIdx.x * 256 + threadIdx.x;
    if (i < n4) {
        unsigned short h, l;
        split2(1.f / A_DIM, h, l);
        ((ushort4*)Chi)[i] = make_ushort4(h, h, h, h);
        ((ushort4*)Clo)[i] = make_ushort4(l, l, l, l);
    }
}

// fp32 vector GEMM, B transposed, setup only: X = an @ an^T
__global__ __launch_bounds__(256) void gemm_xt(const float* __restrict__ Aop,
                                               float* __restrict__ Cout) {
    const int LDT = 132;
    const int N = A_DIM, K = D_DIM;
    __shared__ float As[16 * LDT];
    __shared__ float Bs[16 * LDT];
    int m0 = blockIdx.y * 128, n0 = blockIdx.x * 128;
    int tid = threadIdx.x;
    int tx = tid & 15, ty = tid >> 4;
    float acc[8][8];
#pragma unroll
    for (int i = 0; i < 8; i++)
#pragma unroll
        for (int j = 0; j < 8; j++) acc[i][j] = 0.f;
    for (int k0 = 0; k0 < K; k0 += 16) {
#pragma unroll
        for (int s = 0; s < 2; s++) {
            int idx = tid + s * 256;
            int row = idx >> 2, kq = (idx & 3) * 4;
            float4 v = *(const float4*)(Aop + (size_t)(m0 + row) * K + k0 + kq);
            As[(kq + 0) * LDT + row] = v.x;
            As[(kq + 1) * LDT + row] = v.y;
            As[(kq + 2) * LDT + row] = v.z;
            As[(kq + 3) * LDT + row] = v.w;
        }
#pragma unroll
        for (int s = 0; s < 2; s++) {
            int idx = tid + s * 256;
            int row = idx >> 2, kq = (idx & 3) * 4;
            float4 v = *(const float4*)(Aop + (size_t)(n0 + row) * K + k0 + kq);
            Bs[(kq + 0) * LDT + row] = v.x;
            Bs[(kq + 1) * LDT + row] = v.y;
            Bs[(kq + 2) * LDT + row] = v.z;
            Bs[(kq + 3) * LDT + row] = v.w;
        }
        __syncthreads();
#pragma unroll
        for (int kk = 0; kk < 16; kk++) {
            float a[8], b[8];
            *(float4*)(a)     = *(const float4*)(As + kk * LDT + ty * 8);
            *(float4*)(a + 4) = *(const float4*)(As + kk * LDT + ty * 8 + 4);
            *(float4*)(b)     = *(const float4*)(Bs + kk * LDT + tx * 8);
            *(float4*)(b + 4) = *(const float4*)(Bs + kk * LDT + tx * 8 + 4);
#pragma unroll
            for (int i = 0; i < 8; i++)
#pragma unroll
                for (int j = 0; j < 8; j++) acc[i][j] = fmaf(a[i], b[j], acc[i][j]);
        }
        __syncthreads();
    }
#pragma unroll
    for (int i = 0; i < 8; i++) {
        int row = m0 + ty * 8 + i;
#pragma unroll
        for (int j = 0; j < 8; j += 4) {
            int col = n0 + tx * 8 + j;
            float4 v = make_float4(acc[i][j], acc[i][j + 1], acc[i][j + 2], acc[i][j + 3]);
            *(float4*)(Cout + (size_t)row * N + col) = v;
        }
    }
}

// qt = Yn @ An^T  (bf16x2 pair-pair MFMA, K=768), swizzled 1D grid of 1024
__global__ __launch_bounds__(256) void qt_mfma(const unsigned short* __restrict__ Ynh,
                                               const unsigned short* __restrict__ Ynl,
                                               const unsigned short* __restrict__ Anh,
                                               const unsigned short* __restrict__ Anl,
                                               float* __restrict__ qt) {
    __shared__ unsigned short lds[16384];
    int tid = threadIdx.x;
    int w = tid >> 6, lane = tid & 63;
    int wm = w >> 1, wn = w & 1;
    int m0, n0;
    swz(blockIdx.x, m0, n0);

    f32x4 acc[4][4];
#pragma unroll
    for (int i = 0; i < 4; i++)
#pragma unroll
        for (int j = 0; j < 4; j++) acc[i][j] = f32x4{0.f, 0.f, 0.f, 0.f};

    const unsigned short* gsrc;
    if (w == 0) gsrc = Ynh + (size_t)m0 * D_DIM;
    else if (w == 1) gsrc = Ynl + (size_t)m0 * D_DIM;
    else if (w == 2) gsrc = Anh + (size_t)n0 * D_DIM;
    else gsrc = Anl + (size_t)n0 * D_DIM;
    unsigned short* ltile = lds + w * 4096;
    for (int k0 = 0; k0 < D_DIM; k0 += 32) {
        stage_tile8(gsrc, D_DIM, k0, ltile, lane);
        __syncthreads();
        mfma_k32(lds, wm, wn, lane, acc);
        __syncthreads();
    }

    int crow = (lane >> 4) * 4, ccol = lane & 15;
#pragma unroll
    for (int i = 0; i < 4; i++) {
        int gm = m0 + wm * 64 + i * 16 + crow;
#pragma unroll
        for (int j = 0; j < 4; j++) {
            int gn = n0 + wn * 64 + j * 16 + ccol;
#pragma unroll
            for (int r = 0; r < 4; r++)
                qt[(size_t)(gm + r) * A_DIM + gn] = acc[i][j][r];
        }
    }
}

// ---------------- nondiff per-iteration kernels ----------------

// one-time init before the nondiff loop: zero keys / num_amg / cxc / cq / scal
__global__ __launch_bounds__(256) void init_kernel(unsigned long long* __restrict__ keys,
                                                   float* __restrict__ num_amg,
                                                   float* __restrict__ cxc,
                                                   float* __restrict__ cq,
                                                   float* __restrict__ scal) {
    int i = blockIdx.x * 256 + threadIdx.x;
    num_amg[i] = 0.f;
    cxc[i] = 0.f;
    cq[i] = 0.f;
    if (i < A_DIM) keys[i] = ~0ULL;
    if (i < 4) scal[i] = 0.f;
}

// merged stats. Block per atom a:
//   ba = keys[a].low; bstar[a] = ba
//   scal0 += sum_{i: keys[i].low==ba} Xf[a,i]          (pairs)
//   xc = Xf[a,:] . c[ba,:] (fp32-exact);  scal2 += xc; num_amg[ba] += xc - qt[ba,a]
//   scal1 += sum of cxc[16a .. 16a+16)                 (Sum_b c.Xc)
__global__ __launch_bounds__(256) void stats_kernel(const float* __restrict__ Xf,
                                                    const unsigned long long* __restrict__ keys,
                                                    const unsigned short* __restrict__ Chi,
                                                    const unsigned short* __restrict__ Clo,
                                                    const float* __restrict__ qt,
                                                    const float* __restrict__ cxc,
                                                    int* __restrict__ bstar,
                                                    float* __restrict__ num_amg,
                                                    float* __restrict__ scal) {
    __shared__ float red[16];
    int a = blockIdx.x;
    int ba = (int)(unsigned int)(keys[a] & 0xFFFFFFFFULL);
    const float* xr = Xf + (size_t)a * A_DIM;
    const unsigned short* ch = Chi + (size_t)ba * A_DIM;
    const unsigned short* cl = Clo + (size_t)ba * A_DIM;
    float ps = 0.f, xs = 0.f;
    for (int i = threadIdx.x; i < A_DIM; i += 256) {
        float xv = xr[i];
        if ((int)(unsigned int)(keys[i] & 0xFFFFFFFFULL) == ba) ps += xv;
        xs += xv * (bf2f(ch[i]) + bf2f(cl[i]));
    }
    float s1p = (threadIdx.x < 16) ? cxc[(a << 4) + threadIdx.x] : 0.f;
    block_reduce_sum3(ps, xs, s1p, red);
    if (threadIdx.x == 0) {
        bstar[a] = ba;
        atomicAdd(&scal[0], ps);
        atomicAdd(&scal[2], xs);
        atomicAdd(&scal[1], s1p);
        atomicAdd(&num_amg[ba], xs - qt[(size_t)ba * A_DIM + a]);
    }
}

// nondiff update: lam = clip((cxc-cq-amg)/(scal0+scal1-2*scal2+eps));
// c' = (1-lam)c + lam*am; refresh splits; tail resets for next iteration.
__global__ __launch_bounds__(256) void ndupdate_kernel(unsigned short* __restrict__ Chi,
                                                       unsigned short* __restrict__ Clo,
                                                       const int* __restrict__ bstar,
                                                       float* __restrict__ cxc,
                                                       float* __restrict__ cq,
                                                       float* __restrict__ num_amg,
                                                       const float* __restrict__ scal,
                                                       unsigned long long* __restrict__ keys) {
    int b = blockIdx.x;
    float den = scal[0] + scal[1] - 2.f * scal[2] + EPS_C;
    float lam = fminf(fmaxf((cxc[b] - cq[b] - num_amg[b]) / den, 0.f), 1.f);
    float om = 1.f - lam;
    int i = threadIdx.x;
    ushort4* h4 = (ushort4*)(Chi + (size_t)b * A_DIM);
    ushort4* l4 = (ushort4*)(Clo + (size_t)b * A_DIM);
    ushort4 h = h4[i], l = l4[i];
    int4 bs = ((const int4*)bstar)[i];
    float c0 = om * (bf2f(h.x) + bf2f(l.x)) + ((bs.x == b) ? lam : 0.f);
    float c1 = om * (bf2f(h.y) + bf2f(l.y)) + ((bs.y == b) ? lam : 0.f);
    float c2 = om * (bf2f(h.z) + bf2f(l.z)) + ((bs.z == b) ? lam : 0.f);
    float c3 = om * (bf2f(h.w) + bf2f(l.w)) + ((bs.w == b) ? lam : 0.f);
    split2(c0, h.x, l.x);
    split2(c1, h.y, l.y);
    split2(c2, h.z, l.z);
    split2(c3, h.w, l.w);
    h4[i] = h; l4[i] = l;
    __syncthreads();  // drains all reads above before the resets below
    if (i == 0) {
        cxc[b] = 0.f;
        cq[b] = 0.f;
        num_amg[b] = 0.f;
        if (b < A_DIM) keys[b] = ~0ULL;
    }
}

// ---------------- diff-phase small kernels ----------------

__global__ __launch_bounds__(256) void softmax_kernel(float* __restrict__ G,
                                                      unsigned short* __restrict__ Chi,
                                                      unsigned short* __restrict__ Clo,
                                                      float* __restrict__ num_cg,
                                                      float* __restrict__ scal3) {
    __shared__ float red[16];
    int b = blockIdx.x;
    int i = threadIdx.x;
    if (b == 0 && i == 0) *scal3 = 0.f;  // reset before the dot dispatch
    float4* g4 = (float4*)(G + (size_t)b * A_DIM);
    ushort4* h4 = (ushort4*)(Chi + (size_t)b * A_DIM);
    ushort4* l4 = (ushort4*)(Clo + (size_t)b * A_DIM);
    float4 g = g4[i];
    ushort4 h = h4[i], l = l4[i];
    float c0 = bf2f(h.x) + bf2f(l.x);
    float c1 = bf2f(h.y) + bf2f(l.y);
    float c2 = bf2f(h.z) + bf2f(l.z);
    float c3 = bf2f(h.w) + bf2f(l.w);
    float4 t = make_float4(-TEMP_C * g.x, -TEMP_C * g.y, -TEMP_C * g.z, -TEMP_C * g.w);
    float m = fmaxf(fmaxf(t.x, t.y), fmaxf(t.z, t.w));
    float M = block_reduce_max(m, red);
    float4 e = make_float4(expf(t.x - M), expf(t.y - M), expf(t.z - M), expf(t.w - M));
    float S = block_reduce_sum(e.x + e.y + e.z + e.w, red);
    float inv = 1.f / S;
    float4 sm = make_float4(e.x * inv, e.y * inv, e.z * inv, e.w * inv);
    float np = (c0 - sm.x) * g.x + (c1 - sm.y) * g.y + (c2 - sm.z) * g.z + (c3 - sm.w) * g.w;
    g4[i] = sm;
    split2(sm.x - c0, h.x, l.x);
    split2(sm.y - c1, h.y, l.y);
    split2(sm.z - c2, h.z, l.z);
    split2(sm.w - c3, h.w, l.w);
    h4[i] = h; l4[i] = l;
    float nt = block_reduce_sum(np, red);
    if (i == 0) num_cg[b] = nt;
}

__global__ __launch_bounds__(256) void dupdate_kernel(const float* __restrict__ G,
                                                      unsigned short* __restrict__ Chi,
                                                      unsigned short* __restrict__ Clo,
                                                      const float* __restrict__ num_cg,
                                                      const float* __restrict__ scal3) {
    int b = blockIdx.x;
    float den = *scal3 + EPS_C;
    float lam = fminf(fmaxf(num_cg[b] / den, 0.f), 1.f);
    float om = 1.f - lam;
    int i = threadIdx.x;
    const float4* g4 = (const float4*)(G + (size_t)b * A_DIM);
    ushort4* h4 = (ushort4*)(Chi + (size_t)b * A_DIM);
    ushort4* l4 = (ushort4*)(Clo + (size_t)b * A_DIM);
    float4 sm = g4[i];
    ushort4 h = h4[i], l = l4[i];
    float c0 = sm.x - om * (bf2f(h.x) + bf2f(l.x));
    float c1 = sm.y - om * (bf2f(h.y) + bf2f(l.y));
    float c2 = sm.z - om * (bf2f(h.z) + bf2f(l.z));
    float c3 = sm.w - om * (bf2f(h.w) + bf2f(l.w));
    split2(c0, h.x, l.x);
    split2(c1, h.y, l.y);
    split2(c2, h.z, l.z);
    split2(c3, h.w, l.w);
    h4[i] = h; l4[i] = l;
}

// recon: out[b, n] = (c_b . anT[:,n]) * ynorm[b]
__global__ __launch_bounds__(256) void mfma_recon(const unsigned short* __restrict__ Chi,
                                                  const unsigned short* __restrict__ Clo,
                                                  const unsigned short* __restrict__ AnTh,
                                                  const unsigned short* __restrict__ AnTl,
                                                  const float* __restrict__ ynorm,
                                                  float* __restrict__ out) {
    __shared__ unsigned short lds[16384];
    int tid = threadIdx.x;
    int w = tid >> 6, lane = tid & 63;
    int wm = w >> 1, wn = w & 1;
    int m0 = blockIdx.y * 128, n0 = blockIdx.x * 128;

    f32x4 acc[4][4];
#pragma unroll
    for (int i = 0; i < 4; i++)
#pragma unroll
        for (int j = 0; j < 4; j++) acc[i][j] = f32x4{0.f, 0.f, 0.f, 0.f};

    const unsigned short* gsrc;
    if (w == 0) gsrc = Chi + (size_t)m0 * A_DIM;
    else if (w == 1) gsrc = Clo + (size_t)m0 * A_DIM;
    else if (w == 2) gsrc = AnTh + (size_t)n0 * A_DIM;
    else gsrc = AnTl + (size_t)n0 * A_DIM;
    unsigned short* ltile = lds + w * 4096;
    for (int k0 = 0; k0 < A_DIM; k0 += 32) {
        stage_tile8(gsrc, A_DIM, k0, ltile, lane);
        __syncthreads();
        mfma_k32(lds, wm, wn, lane, acc);
        __syncthreads();
    }

    int crow = (lane >> 4) * 4, ccol = lane & 15;
#pragma unroll
    for (int i = 0; i < 4; i++) {
        int gm = m0 + wm * 64 + i * 16 + crow;
#pragma unroll
        for (int j = 0; j < 4; j++) {
            int gn = n0 + wn * 64 + j * 16 + ccol;
#pragma unroll
            for (int r = 0; r < 4; r++)
                out[(size_t)(gm + r) * D_DIM + gn] = acc[i][j][r] * ynorm[gm + r];
        }
    }
}

// ---------------- host launch ----------------

extern "C" void kernel_launch(void* const* d_in, const int* in_sizes, int n_in,
                              void* d_out, int out_size, void* d_ws, size_t ws_size,
                              hipStream_t stream) {
    const float* y = (const float*)d_in[0];      // [B, 768]
    const float* atoms = (const float*)d_in[1];  // [A, 768]
    float* out = (float*)d_out;                  // [B, 768]

    char* ws = (char*)d_ws;
    size_t off = 0;
    auto alloc = [&](size_t bytes) -> void* {
        void* p = ws + off;
        off += (bytes + 255) & ~(size_t)255;
        return p;
    };
    const size_t BA = (size_t)B_DIM * A_DIM;
    unsigned short* Chi = (unsigned short*)alloc(BA * 2);            // 32 MiB
    unsigned short* Clo = (unsigned short*)alloc(BA * 2);            // 32 MiB
    float* Greg = (float*)alloc(BA * 4);                             // 64 MiB (aliased)
    float* qt = (float*)alloc(BA * 4);                               // 64 MiB
    unsigned short* Xhi = (unsigned short*)alloc((size_t)A_DIM * A_DIM * 2);  // 2 MiB
    unsigned short* Xlo = (unsigned short*)alloc((size_t)A_DIM * A_DIM * 2);  // 2 MiB
    float* ynorm = (float*)alloc(B_DIM * 4);
    float* anrm  = (float*)alloc(A_DIM * 4);
    float* cxc   = (float*)alloc(B_DIM * 4);
    float* cq    = (float*)alloc(B_DIM * 4);
    float* num_amg = (float*)alloc(B_DIM * 4);
    float* num_cg  = (float*)alloc(B_DIM * 4);
    unsigned long long* keys = (unsigned long long*)alloc(A_DIM * 8);
    int* bstar = (int*)alloc(A_DIM * 4);
    float* scal = (float*)alloc(256);
    (void)ws_size; (void)in_sizes; (void)n_in; (void)out_size;

    // Greg aliases (floats):
    float* Xf = Greg;                                         // 4 MiB, live thru nondiff
    float* an = Greg + (size_t)A_DIM * A_DIM;                 // 3 MiB, setup only
    unsigned short* Anh = (unsigned short*)(an + (size_t)A_DIM * D_DIM);          // 1.5 MiB
    unsigned short* Anl = Anh + (size_t)A_DIM * D_DIM;                            // 1.5 MiB
    unsigned short* Ynh = Anl + (size_t)A_DIM * D_DIM;                            // 24 MiB
    unsigned short* Ynl = Ynh + (size_t)B_DIM * D_DIM;                            // 24 MiB
    float* G = Greg;                                          // diff phase (clobbers all)
    unsigned short* AnTh = (unsigned short*)Greg;             // post-diff recon
    unsigned short* AnTl = (unsigned short*)Greg + (size_t)D_DIM * A_DIM;

    // ---- setup ----
    ynorm_kernel<<<B_DIM, 256, 0, stream>>>(y, ynorm);
    yn_split_kernel<<<B_DIM, 256, 0, stream>>>(y, ynorm, Ynh, Ynl);
    anorm_kernel<<<A_DIM, 256, 0, stream>>>(atoms, an, anrm, Anh, Anl);
    gemm_xt<<<dim3(A_DIM / 128, A_DIM / 128), 256, 0, stream>>>(an, Xf);
    split_kernel<<<A_DIM * A_DIM / 4 / 256, 256, 0, stream>>>(Xf, Xhi, Xlo, A_DIM * A_DIM / 4);
    qt_mfma<<<1024, 256, 0, stream>>>(Ynh, Ynl, Anh, Anl, qt);
    fill_pair_kernel<<<(int)(BA / 4 / 256), 256, 0, stream>>>(Chi, Clo, BA / 4);
    init_kernel<<<B_DIM / 256, 256, 0, stream>>>(keys, num_amg, cxc, cq, scal);

    // ---- 30 nondiff steps ----
    for (int it = 0; it < 30; it++) {
        gemm256<0><<<256, 512, 0, stream>>>(Chi, Clo, Xhi, Xlo, qt,
                                            keys, cxc, cq, scal, nullptr, nullptr);
        stats_kernel<<<A_DIM, 256, 0, stream>>>(Xf, keys, Chi, Clo, qt, cxc,
                                                bstar, num_amg, scal);
        ndupdate_kernel<<<B_DIM, 256, 0, stream>>>(Chi, Clo, bstar, cxc, cq,
                                                   num_amg, scal, keys);
    }

    // ---- 10 diff steps (G clobbers Xf/setup region) ----
    for (int it = 0; it < 10; it++) {
        gemm256<1><<<256, 512, 0, stream>>>(Chi, nullptr, Xhi, Xlo, qt,
                                            nullptr, nullptr, nullptr, nullptr, G, nullptr);
        softmax_kernel<<<B_DIM, 256, 0, stream>>>(G, Chi, Clo, num_cg, &scal[3]);
        gemm256<2><<<256, 512, 0, stream>>>(Chi, Clo, Xhi, Xlo, nullptr,
                                            nullptr, nullptr, nullptr, nullptr, nullptr,
                                            &scal[3]);
        dupdate_kernel<<<B_DIM, 256, 0, stream>>>(G, Chi, Clo, num_cg, &scal[3]);
    }

    // ---- recon ----
    atrans_split_kernel<<<D_DIM, 256, 0, stream>>>(atoms, anrm, AnTh, AnTl);
    mfma_recon<<<dim3(D_DIM / 128, B_DIM / 128), 256, 0, stream>>>(Chi, Clo, AnTh, AnTl,
                                                                   ynorm, out);
}

// Round 5
// 7551.997 us; speedup vs baseline: 1.0686x; 1.0686x over previous
//
#include <hip/hip_runtime.h>
#include <hip/hip_bf16.h>
#include <math.h>

// Problem constants
#define A_DIM 1024      // NB_ATOMS
#define D_DIM 768       // 3*16*16
#define B_DIM 16384     // BATCH
#define TEMP_C 100.0f
#define EPS_C 1e-8f

// Round 11: phase-split K-loop for gemm256 (true 8-phase-style schedule).
// Round-10 PMC: MfmaUtil 30%, VALUBusy 15%, bank-conflict 0, HBM 18% ->
// waves idle at vmcnt/barrier = the known "2-phase" stall (m233/m248).
// Fix: 4 phases per K-step {ds_read mi-pair || stage-part issue -> barrier ->
// lgkmcnt(0) -> setprio(1) MFMA setprio(0) -> barrier}, vmcnt(2) counted once
// per K-step (never 0 mid-loop; 2 newest loads stay in flight across it).
// Stage addresses, LDS swizzle, MFMA order, epilogues bitwise-identical to
// round 10 (verified absmax 4.88e-4). Everything else unchanged.

typedef __attribute__((ext_vector_type(8))) short short8;
typedef __attribute__((ext_vector_type(4))) float f32x4;
#define MFMA16(a, b, c) __builtin_amdgcn_mfma_f32_16x16x32_bf16(a, b, c, 0, 0, 0)

typedef __attribute__((address_space(3))) unsigned char lds_byte;
typedef __attribute__((address_space(1))) const unsigned char g_byte;
__device__ __forceinline__ void async_copy16(const void* gptr, void* lptr) {
    __builtin_amdgcn_global_load_lds((g_byte*)gptr, (lds_byte*)lptr, 16, 0, 0);
}

#define SCHED0 __builtin_amdgcn_sched_barrier(0)
#define ASM_BAR asm volatile("s_barrier" ::: "memory")

// XCD-slab swizzle for 1024-block GEMM grids (qt_mfma only)
__device__ __forceinline__ void swz(int i, int& m0, int& n0) {
    int xcd = i & 7, j = i >> 3;
    m0 = ((xcd << 4) + (j >> 3)) << 7;
    n0 = (j & 7) << 7;
}

// ---------------- reductions (wave shuffle + tiny LDS combine) ----------------

__device__ __forceinline__ float wave_sum(float v) {
#pragma unroll
    for (int m = 1; m < 64; m <<= 1) v += __shfl_xor(v, m);
    return v;
}
__device__ __forceinline__ float wave_max(float v) {
#pragma unroll
    for (int m = 1; m < 64; m <<= 1) v = fmaxf(v, __shfl_xor(v, m));
    return v;
}

__device__ __forceinline__ float block_reduce_sum(float v, float* red) {
    int t = threadIdx.x;
    v = wave_sum(v);
    if ((t & 63) == 0) red[t >> 6] = v;
    __syncthreads();
    float r = red[0] + red[1] + red[2] + red[3];
    __syncthreads();
    return r;
}

__device__ __forceinline__ float block_reduce_max(float v, float* red) {
    int t = threadIdx.x;
    v = wave_max(v);
    if ((t & 63) == 0) red[t >> 6] = v;
    __syncthreads();
    float r = fmaxf(fmaxf(red[0], red[1]), fmaxf(red[2], red[3]));
    __syncthreads();
    return r;
}

__device__ __forceinline__ void block_reduce_sum3(float& a, float& b, float& c, float* red) {
    int t = threadIdx.x;
    a = wave_sum(a);
    b = wave_sum(b);
    c = wave_sum(c);
    if ((t & 63) == 0) {
        int w = t >> 6;
        red[w] = a; red[4 + w] = b; red[8 + w] = c;
    }
    __syncthreads();
    a = red[0] + red[1] + red[2] + red[3];
    b = red[4] + red[5] + red[6] + red[7];
    c = red[8] + red[9] + red[10] + red[11];
    __syncthreads();
}

// ---------------- small helpers ----------------

__device__ __forceinline__ unsigned int fkey(float v) {
    unsigned int u = __float_as_uint(v);
    return u ^ ((u & 0x80000000u) ? 0xFFFFFFFFu : 0x80000000u);
}

__device__ __forceinline__ unsigned short f2bf(float x) {
    unsigned int u = __float_as_uint(x);
    return (unsigned short)((u + 0x7FFFu + ((u >> 16) & 1u)) >> 16);
}
__device__ __forceinline__ float bf2f(unsigned short h) {
    return __uint_as_float(((unsigned int)h) << 16);
}
__device__ __forceinline__ void split2(float x, unsigned short& hi, unsigned short& lo) {
    hi = f2bf(x);
    lo = f2bf(x - bf2f(hi));
}

// ---------------- 128^2 MFMA building blocks (qt_mfma / mfma_recon) ----------------

__device__ __forceinline__ void stage_tile8(const unsigned short* gsrc, int stride, int k0,
                                            unsigned short* ltile, int lane) {
    int srow = lane >> 2;
    int scol = (lane & 3) * 8;
#pragma unroll
    for (int s = 0; s < 8; s++) {
        const unsigned short* src = gsrc + (size_t)(s * 16 + srow) * stride + k0 + scol;
        async_copy16(src, ltile + s * 512);
    }
}

// 3-product (pair x pair) K=32 step
__device__ __forceinline__ void mfma_k32(const unsigned short* lds, int wm, int wn, int lane,
                                         f32x4 acc[4][4]) {
    int frow = lane & 15, fk = (lane >> 4) * 8;
    short8 ah[4], al[4], bh[4], bl[4];
#pragma unroll
    for (int t = 0; t < 4; t++) {
        int ar = (wm * 64 + t * 16 + frow) * 32 + fk;
        ah[t] = *(const short8*)&lds[ar];
        al[t] = *(const short8*)&lds[4096 + ar];
        int br = (wn * 64 + t * 16 + frow) * 32 + fk;
        bh[t] = *(const short8*)&lds[8192 + br];
        bl[t] = *(const short8*)&lds[12288 + br];
    }
#pragma unroll
    for (int i = 0; i < 4; i++)
#pragma unroll
        for (int j = 0; j < 4; j++) {
            acc[i][j] = MFMA16(ah[i], bh[j], acc[i][j]);
            acc[i][j] = MFMA16(ah[i], bl[j], acc[i][j]);
            acc[i][j] = MFMA16(al[i], bh[j], acc[i][j]);
        }
}

// ---------------- 256^2 phase-split pipelined GEMM core ----------------
// MODE 0: A = pair (Chi,Clo), 3 products, nondiff epilogue (argmin/cxc/cq)
// MODE 1: A = single hi, 2 products, epilogue G = acc - qt
// MODE 2: A = single hi, 2 products, epilogue scal3 += sum(acc * (Ahi+Alo pair))

// stage-part: MODE 0 -> 4 parts x 2 loads (Ahi, Alo, Xhi, Xlo row pairs);
//             MODE 1/2 -> parts 0..2 x 2 loads (Ahi, Xhi, Xlo), part 3 empty.
template <int MODE, int PART>
__device__ __forceinline__ void stage_part(unsigned short* buf,
                                           const unsigned short* Ahi,
                                           const unsigned short* Alo,
                                           const unsigned short* Xhi,
                                           const unsigned short* Xlo,
                                           int m0, int n0, int k0, int t) {
    constexpr int AHI = 0;
    constexpr int ALO = 8192;
    constexpr int BHI = (MODE == 0) ? 16384 : 8192;
    constexpr int BLO = BHI + 8192;
    int r = t >> 2;
    int cg = (t & 3) ^ ((t >> 3) & 3);    // pre-swizzled source chunk
    size_t col = (size_t)k0 + cg * 8;
    if constexpr (MODE == 0) {
        if constexpr (PART == 0) {
            async_copy16(Ahi + (size_t)(m0 + r) * A_DIM + col,       buf + AHI + t * 8);
            async_copy16(Ahi + (size_t)(m0 + 128 + r) * A_DIM + col, buf + AHI + 4096 + t * 8);
        } else if constexpr (PART == 1) {
            async_copy16(Alo + (size_t)(m0 + r) * A_DIM + col,       buf + ALO + t * 8);
            async_copy16(Alo + (size_t)(m0 + 128 + r) * A_DIM + col, buf + ALO + 4096 + t * 8);
        } else if constexpr (PART == 2) {
            async_copy16(Xhi + (size_t)(n0 + r) * A_DIM + col,       buf + BHI + t * 8);
            async_copy16(Xhi + (size_t)(n0 + 128 + r) * A_DIM + col, buf + BHI + 4096 + t * 8);
        } else {
            async_copy16(Xlo + (size_t)(n0 + r) * A_DIM + col,       buf + BLO + t * 8);
            async_copy16(Xlo + (size_t)(n0 + 128 + r) * A_DIM + col, buf + BLO + 4096 + t * 8);
        }
    } else {
        if constexpr (PART == 0) {
            async_copy16(Ahi + (size_t)(m0 + r) * A_DIM + col,       buf + AHI + t * 8);
            async_copy16(Ahi + (size_t)(m0 + 128 + r) * A_DIM + col, buf + AHI + 4096 + t * 8);
        } else if constexpr (PART == 1) {
            async_copy16(Xhi + (size_t)(n0 + r) * A_DIM + col,       buf + BHI + t * 8);
            async_copy16(Xhi + (size_t)(n0 + 128 + r) * A_DIM + col, buf + BHI + 4096 + t * 8);
        } else if constexpr (PART == 2) {
            async_copy16(Xlo + (size_t)(n0 + r) * A_DIM + col,       buf + BLO + t * 8);
            async_copy16(Xlo + (size_t)(n0 + 128 + r) * A_DIM + col, buf + BLO + 4096 + t * 8);
        }
        // PART 3: nothing
    }
}

// one mi: 3-product (pair-A) accumulate, order identical to round 10
__device__ __forceinline__ void mfma_mi3(short8 ah, short8 al,
                                         const short8 bh[4], const short8 bl[4],
                                         f32x4* accRow) {
#pragma unroll
    for (int j = 0; j < 4; j++) {
        accRow[j] = MFMA16(ah, bh[j], accRow[j]);
        accRow[j] = MFMA16(ah, bl[j], accRow[j]);
        accRow[j] = MFMA16(al, bh[j], accRow[j]);
    }
}
// one mi: 2-product (single-A)
__device__ __forceinline__ void mfma_mi2(short8 ah,
                                         const short8 bh[4], const short8 bl[4],
                                         f32x4* accRow) {
#pragma unroll
    for (int j = 0; j < 4; j++) {
        accRow[j] = MFMA16(ah, bh[j], accRow[j]);
        accRow[j] = MFMA16(ah, bl[j], accRow[j]);
    }
}

template <int MODE>
__global__ __launch_bounds__(512, 2) void gemm256(const unsigned short* __restrict__ Ahi,
                                                  const unsigned short* __restrict__ Alo,
                                                  const unsigned short* __restrict__ Xhi,
                                                  const unsigned short* __restrict__ Xlo,
                                                  const float* __restrict__ qt,
                                                  unsigned long long* __restrict__ keys,
                                                  float* __restrict__ cxc,
                                                  float* __restrict__ cq,
                                                  float* __restrict__ scal,
                                                  float* __restrict__ G,
                                                  float* __restrict__ scal3) {
    constexpr int BUFS = (MODE == 0) ? 32768 : 24576;   // shorts per buffer
    constexpr int AHI = 0;
    constexpr int ALO = 8192;
    constexpr int BHI = (MODE == 0) ? 16384 : 8192;
    constexpr int BLO = BHI + 8192;
    __shared__ unsigned short lds[2 * BUFS];
    __shared__ float red[8];
    int tid = threadIdx.x;
    if (MODE == 0 && blockIdx.x == 0 && tid < 4) scal[tid] = 0.f;
    int w = tid >> 6, lane = tid & 63;
    int wm = w >> 2, wn = w & 3;          // 2 x 4 wave grid
    // XCD-bijective swizzle over 256 blocks
    int bi = blockIdx.x;
    int xcd = bi & 7, bj = bi >> 3;
    int m0 = ((xcd << 3) + (bj >> 2)) << 8;
    int n0 = (bj & 3) << 8;

    f32x4 acc[8][4];
#pragma unroll
    for (int i = 0; i < 8; i++)
#pragma unroll
        for (int j = 0; j < 4; j++) acc[i][j] = f32x4{0.f, 0.f, 0.f, 0.f};

    int frow = lane & 15;
    int sw = ((lane >> 4) ^ ((frow >> 1) & 3)) * 8;   // read-side chunk swizzle

    // prologue: stage K-step 0 fully into buf0
    stage_part<MODE, 0>(lds, Ahi, Alo, Xhi, Xlo, m0, n0, 0, tid);
    stage_part<MODE, 1>(lds, Ahi, Alo, Xhi, Xlo, m0, n0, 0, tid);
    stage_part<MODE, 2>(lds, Ahi, Alo, Xhi, Xlo, m0, n0, 0, tid);
    stage_part<MODE, 3>(lds, Ahi, Alo, Xhi, Xlo, m0, n0, 0, tid);

    int cur = 0;
    for (int ks = 0; ks < 32; ++ks) {
        unsigned short* rb = lds + cur * BUFS;
        unsigned short* wb = lds + (cur ^ 1) * BUFS;
        const bool pf = (ks < 31);
        const int k1 = (ks + 1) * 32;

        // ---- guard: wait prior step's loads; keep part0 of next in flight ----
        if (pf) {
            stage_part<MODE, 0>(wb, Ahi, Alo, Xhi, Xlo, m0, n0, k1, tid);
            SCHED0;
            asm volatile("s_waitcnt vmcnt(2)" ::: "memory");
        } else {
            asm volatile("s_waitcnt vmcnt(0)" ::: "memory");
        }
        SCHED0; ASM_BAR; SCHED0;

        // ---- phase 0: B frags + A01, stage part1, MFMA mi 0-1 ----
        short8 bh[4], bl[4];
#pragma unroll
        for (int j = 0; j < 4; j++) {
            int br = wn * 64 + j * 16 + frow;
            bh[j] = *(const short8*)&rb[BHI + br * 32 + sw];
            bl[j] = *(const short8*)&rb[BLO + br * 32 + sw];
        }
        {
            int ar0 = wm * 128 + 0 * 16 + frow, ar1 = wm * 128 + 1 * 16 + frow;
            short8 a0h = *(const short8*)&rb[AHI + ar0 * 32 + sw];
            short8 a1h = *(const short8*)&rb[AHI + ar1 * 32 + sw];
            short8 a0l, a1l;
            if constexpr (MODE == 0) {
                a0l = *(const short8*)&rb[ALO + ar0 * 32 + sw];
                a1l = *(const short8*)&rb[ALO + ar1 * 32 + sw];
            }
            if (pf) stage_part<MODE, 1>(wb, Ahi, Alo, Xhi, Xlo, m0, n0, k1, tid);
            SCHED0; ASM_BAR; SCHED0;
            asm volatile("s_waitcnt lgkmcnt(0)" ::: "memory"); SCHED0;
            __builtin_amdgcn_s_setprio(1);
            if constexpr (MODE == 0) { mfma_mi3(a0h, a0l, bh, bl, acc[0]); mfma_mi3(a1h, a1l, bh, bl, acc[1]); }
            else                     { mfma_mi2(a0h, bh, bl, acc[0]);      mfma_mi2(a1h, bh, bl, acc[1]); }
            __builtin_amdgcn_s_setprio(0);
            SCHED0; ASM_BAR; SCHED0;
        }
        // ---- phases 1..3: A-frag pairs, stage parts 2,3, MFMA ----
#pragma unroll
        for (int ph = 1; ph < 4; ph++) {
            int mia = 2 * ph, mib = 2 * ph + 1;
            int ara = wm * 128 + mia * 16 + frow, arb = wm * 128 + mib * 16 + frow;
            short8 aah = *(const short8*)&rb[AHI + ara * 32 + sw];
            short8 abh = *(const short8*)&rb[AHI + arb * 32 + sw];
            short8 aal, abl;
            if constexpr (MODE == 0) {
                aal = *(const short8*)&rb[ALO + ara * 32 + sw];
                abl = *(const short8*)&rb[ALO + arb * 32 + sw];
            }
            if (pf) {
                if (ph == 1) stage_part<MODE, 2>(wb, Ahi, Alo, Xhi, Xlo, m0, n0, k1, tid);
                if (ph == 2) stage_part<MODE, 3>(wb, Ahi, Alo, Xhi, Xlo, m0, n0, k1, tid);
            }
            SCHED0; ASM_BAR; SCHED0;
            asm volatile("s_waitcnt lgkmcnt(0)" ::: "memory"); SCHED0;
            __builtin_amdgcn_s_setprio(1);
            if constexpr (MODE == 0) { mfma_mi3(aah, aal, bh, bl, acc[mia]); mfma_mi3(abh, abl, bh, bl, acc[mib]); }
            else                     { mfma_mi2(aah, bh, bl, acc[mia]);      mfma_mi2(abh, bh, bl, acc[mib]); }
            __builtin_amdgcn_s_setprio(0);
            SCHED0; ASM_BAR; SCHED0;
        }
        cur ^= 1;
    }

    int crow = (lane >> 4) * 4, ccol = lane & 15;
    if constexpr (MODE == 0) {
        unsigned long long best[4] = {~0ULL, ~0ULL, ~0ULL, ~0ULL};
#pragma unroll
        for (int mi = 0; mi < 8; mi++)
#pragma unroll
            for (int r = 0; r < 4; r++) {
                int gm = m0 + wm * 128 + mi * 16 + crow + r;
                float pcx = 0.f, pcq = 0.f;
#pragma unroll
                for (int jj = 0; jj < 4; jj++) {
                    int gn = n0 + wn * 64 + jj * 16 + ccol;
                    size_t idx = (size_t)gm * A_DIM + gn;
                    float c = bf2f(Ahi[idx]) + bf2f(Alo[idx]);
                    float q = qt[idx];
                    float xc = acc[mi][jj][r];
                    pcx += c * xc;
                    pcq += c * q;
                    unsigned long long key =
                        ((unsigned long long)fkey(xc - q) << 32) | (unsigned int)gm;
                    if (key < best[jj]) best[jj] = key;
                }
                for (int mm = 1; mm < 16; mm <<= 1) {
                    pcx += __shfl_xor(pcx, mm, 16);
                    pcq += __shfl_xor(pcq, mm, 16);
                }
                if (ccol == 0) {
                    atomicAdd(&cxc[gm], pcx);
                    atomicAdd(&cq[gm], pcq);
                }
            }
#pragma unroll
        for (int jj = 0; jj < 4; jj++) {
            int gn = n0 + wn * 64 + jj * 16 + ccol;
            unsigned long long o = __shfl_xor(best[jj], 16);
            if (o < best[jj]) best[jj] = o;
            o = __shfl_xor(best[jj], 32);
            if (o < best[jj]) best[jj] = o;
            if ((lane >> 4) == 0) atomicMin(&keys[gn], best[jj]);
        }
    } else if constexpr (MODE == 1) {
#pragma unroll
        for (int mi = 0; mi < 8; mi++)
#pragma unroll
            for (int r = 0; r < 4; r++) {
                int gm = m0 + wm * 128 + mi * 16 + crow + r;
#pragma unroll
                for (int jj = 0; jj < 4; jj++) {
                    int gn = n0 + wn * 64 + jj * 16 + ccol;
                    size_t idx = (size_t)gm * A_DIM + gn;
                    G[idx] = acc[mi][jj][r] - qt[idx];
                }
            }
    } else {
        float part = 0.f;
#pragma unroll
        for (int mi = 0; mi < 8; mi++)
#pragma unroll
            for (int r = 0; r < 4; r++) {
                int gm = m0 + wm * 128 + mi * 16 + crow + r;
#pragma unroll
                for (int jj = 0; jj < 4; jj++) {
                    int gn = n0 + wn * 64 + jj * 16 + ccol;
                    size_t idx = (size_t)gm * A_DIM + gn;
                    float d = bf2f(Ahi[idx]) + bf2f(Alo[idx]);
                    part += acc[mi][jj][r] * d;
                }
            }
        part = wave_sum(part);
        if (lane == 0) red[w] = part;
        __syncthreads();
        if (tid == 0) {
            float tot = red[0] + red[1] + red[2] + red[3] +
                        red[4] + red[5] + red[6] + red[7];
            atomicAdd(scal3, tot);
        }
    }
}

// ---------------- setup kernels ----------------

__global__ __launch_bounds__(256) void ynorm_kernel(const float* __restrict__ y,
                                                    float* __restrict__ ynorm) {
    __shared__ float red[16];
    int b = blockIdx.x;
    const float* row = y + (size_t)b * D_DIM;
    float s = 0.f;
    for (int i = threadIdx.x; i < D_DIM; i += 256) s += fabsf(row[i]);
    float tot = block_reduce_sum(s, red);
    if (threadIdx.x == 0) ynorm[b] = tot;
}

__global__ __launch_bounds__(256) void yn_split_kernel(const float* __restrict__ y,
                                                       const float* __restrict__ ynorm,
                                                       unsigned short* __restrict__ Ynh,
                                                       unsigned short* __restrict__ Ynl) {
    int b = blockIdx.x;
    float inv = 1.f / ynorm[b];
    const float* row = y + (size_t)b * D_DIM;
    unsigned short* oh = Ynh + (size_t)b * D_DIM;
    unsigned short* ol = Ynl + (size_t)b * D_DIM;
    for (int i = threadIdx.x; i < D_DIM; i += 256) {
        unsigned short h, l;
        split2(row[i] * inv, h, l);
        oh[i] = h; ol[i] = l;
    }
}

__global__ __launch_bounds__(256) void anorm_kernel(const float* __restrict__ atoms,
                                                    float* __restrict__ an,
                                                    float* __restrict__ anrm,
                                                    unsigned short* __restrict__ Anh,
                                                    unsigned short* __restrict__ Anl) {
    __shared__ float red[16];
    int a = blockIdx.x;
    const float* row = atoms + (size_t)a * D_DIM;
    float s = 0.f;
    for (int i = threadIdx.x; i < D_DIM; i += 256) s += fabsf(row[i]);
    float tot = block_reduce_sum(s, red);
    float inv = 1.f / tot;
    for (int i = threadIdx.x; i < D_DIM; i += 256) {
        float v = row[i] * inv;
        an[(size_t)a * D_DIM + i] = v;
        unsigned short h, l;
        split2(v, h, l);
        Anh[(size_t)a * D_DIM + i] = h;
        Anl[(size_t)a * D_DIM + i] = l;
    }
    if (threadIdx.x == 0) anrm[a] = tot;
}

__global__ __launch_bounds__(256) void atrans_split_kernel(const float* __restrict__ atoms,
                                                           const float* __restrict__ anrm,
                                                           unsigned short* __restrict__ AnTh,
                                                           unsigned short* __restrict__ AnTl) {
    int n = blockIdx.x;
    for (int k = threadIdx.x; k < A_DIM; k += 256) {
        float v = atoms[(size_t)k * D_DIM + n] / anrm[k];
        unsigned short h, l;
        split2(v, h, l);
        AnTh[(size_t)n * A_DIM + k] = h;
        AnTl[(size_t)n * A_DIM + k] = l;
    }
}

__global__ __launch_bounds__(256) void split_kernel(const float* __restrict__ src,
                                                    unsigned short* __restrict__ hi,
                                                    unsigned short* __restrict__ lo,
                                                    int n4) {
    int i = blockIdx.x * 256 + threadIdx.x;
    if (i < n4) {
        float4 v = ((const float4*)src)[i];
        ushort4 h, l;
        split2(v.x, h.x, l.x);
        split2(v.y, h.y, l.y);
        split2(v.z, h.z, l.z);
        split2(v.w, h.w, l.w);
        ((ushort4*)hi)[i] = h;
        ((ushort4*)lo)[i] = l;
    }
}

__global__ __launch_bounds__(256) void fill_pair_kernel(unsigned short* __restrict__ Chi,
                                                        unsigned short* __restrict__ Clo,
                                                        size_t n4) {
    size_t i = (size_t)blockIdx.x * 256 + threadIdx.x;
    if (i < n4) {
        unsigned short h, l;
        split2(1.f / A_DIM, h, l);
        ((ushort4*)Chi)[i] = make_ushort4(h, h, h, h);
        ((ushort4*)Clo)[i] = make_ushort4(l, l, l, l);
    }
}

// fp32 vector GEMM, B transposed, setup only: X = an @ an^T
__global__ __launch_bounds__(256) void gemm_xt(const float* __restrict__ Aop,
                                               float* __restrict__ Cout) {
    const int LDT = 132;
    const int N = A_DIM, K = D_DIM;
    __shared__ float As[16 * LDT];
    __shared__ float Bs[16 * LDT];
    int m0 = blockIdx.y * 128, n0 = blockIdx.x * 128;
    int tid = threadIdx.x;
    int tx = tid & 15, ty = tid >> 4;
    float acc[8][8];
#pragma unroll
    for (int i = 0; i < 8; i++)
#pragma unroll
        for (int j = 0; j < 8; j++) acc[i][j] = 0.f;
    for (int k0 = 0; k0 < K; k0 += 16) {
#pragma unroll
        for (int s = 0; s < 2; s++) {
            int idx = tid + s * 256;
            int row = idx >> 2, kq = (idx & 3) * 4;
            float4 v = *(const float4*)(Aop + (size_t)(m0 + row) * K + k0 + kq);
            As[(kq + 0) * LDT + row] = v.x;
            As[(kq + 1) * LDT + row] = v.y;
            As[(kq + 2) * LDT + row] = v.z;
            As[(kq + 3) * LDT + row] = v.w;
        }
#pragma unroll
        for (int s = 0; s < 2; s++) {
            int idx = tid + s * 256;
            int row = idx >> 2, kq = (idx & 3) * 4;
            float4 v = *(const float4*)(Aop + (size_t)(n0 + row) * K + k0 + kq);
            Bs[(kq + 0) * LDT + row] = v.x;
            Bs[(kq + 1) * LDT + row] = v.y;
            Bs[(kq + 2) * LDT + row] = v.z;
            Bs[(kq + 3) * LDT + row] = v.w;
        }
        __syncthreads();
#pragma unroll
        for (int kk = 0; kk < 16; kk++) {
            float a[8], b[8];
            *(float4*)(a)     = *(const float4*)(As + kk * LDT + ty * 8);
            *(float4*)(a + 4) = *(const float4*)(As + kk * LDT + ty * 8 + 4);
            *(float4*)(b)     = *(const float4*)(Bs + kk * LDT + tx * 8);
            *(float4*)(b + 4) = *(const float4*)(Bs + kk * LDT + tx * 8 + 4);
#pragma unroll
            for (int i = 0; i < 8; i++)
#pragma unroll
                for (int j = 0; j < 8; j++) acc[i][j] = fmaf(a[i], b[j], acc[i][j]);
        }
        __syncthreads();
    }
#pragma unroll
    for (int i = 0; i < 8; i++) {
        int row = m0 + ty * 8 + i;
#pragma unroll
        for (int j = 0; j < 8; j += 4) {
            int col = n0 + tx * 8 + j;
            float4 v = make_float4(acc[i][j], acc[i][j + 1], acc[i][j + 2], acc[i][j + 3]);
            *(float4*)(Cout + (size_t)row * N + col) = v;
        }
    }
}

// qt = Yn @ An^T  (bf16x2 pair-pair MFMA, K=768), swizzled 1D grid of 1024
__global__ __launch_bounds__(256) void qt_mfma(const unsigned short* __restrict__ Ynh,
                                               const unsigned short* __restrict__ Ynl,
                                               const unsigned short* __restrict__ Anh,
                                               const unsigned short* __restrict__ Anl,
                                               float* __restrict__ qt) {
    __shared__ unsigned short lds[16384];
    int tid = threadIdx.x;
    int w = tid >> 6, lane = tid & 63;
    int wm = w >> 1, wn = w & 1;
    int m0, n0;
    swz(blockIdx.x, m0, n0);

    f32x4 acc[4][4];
#pragma unroll
    for (int i = 0; i < 4; i++)
#pragma unroll
        for (int j = 0; j < 4; j++) acc[i][j] = f32x4{0.f, 0.f, 0.f, 0.f};

    const unsigned short* gsrc;
    if (w == 0) gsrc = Ynh + (size_t)m0 * D_DIM;
    else if (w == 1) gsrc = Ynl + (size_t)m0 * D_DIM;
    else if (w == 2) gsrc = Anh + (size_t)n0 * D_DIM;
    else gsrc = Anl + (size_t)n0 * D_DIM;
    unsigned short* ltile = lds + w * 4096;
    for (int k0 = 0; k0 < D_DIM; k0 += 32) {
        stage_tile8(gsrc, D_DIM, k0, ltile, lane);
        __syncthreads();
        mfma_k32(lds, wm, wn, lane, acc);
        __syncthreads();
    }

    int crow = (lane >> 4) * 4, ccol = lane & 15;
#pragma unroll
    for (int i = 0; i < 4; i++) {
        int gm = m0 + wm * 64 + i * 16 + crow;
#pragma unroll
        for (int j = 0; j < 4; j++) {
            int gn = n0 + wn * 64 + j * 16 + ccol;
#pragma unroll
            for (int r = 0; r < 4; r++)
                qt[(size_t)(gm + r) * A_DIM + gn] = acc[i][j][r];
        }
    }
}

// ---------------- nondiff per-iteration kernels ----------------

__global__ __launch_bounds__(256) void init_kernel(unsigned long long* __restrict__ keys,
                                                   float* __restrict__ num_amg,
                                                   float* __restrict__ cxc,
                                                   float* __restrict__ cq,
                                                   float* __restrict__ scal) {
    int i = blockIdx.x * 256 + threadIdx.x;
    num_amg[i] = 0.f;
    cxc[i] = 0.f;
    cq[i] = 0.f;
    if (i < A_DIM) keys[i] = ~0ULL;
    if (i < 4) scal[i] = 0.f;
}

__global__ __launch_bounds__(256) void stats_kernel(const float* __restrict__ Xf,
                                                    const unsigned long long* __restrict__ keys,
                                                    const unsigned short* __restrict__ Chi,
                                                    const unsigned short* __restrict__ Clo,
                                                    const float* __restrict__ qt,
                                                    const float* __restrict__ cxc,
                                                    int* __restrict__ bstar,
                                                    float* __restrict__ num_amg,
                                                    float* __restrict__ scal) {
    __shared__ float red[16];
    int a = blockIdx.x;
    int ba = (int)(unsigned int)(keys[a] & 0xFFFFFFFFULL);
    const float* xr = Xf + (size_t)a * A_DIM;
    const unsigned short* ch = Chi + (size_t)ba * A_DIM;
    const unsigned short* cl = Clo + (size_t)ba * A_DIM;
    float ps = 0.f, xs = 0.f;
    for (int i = threadIdx.x; i < A_DIM; i += 256) {
        float xv = xr[i];
        if ((int)(unsigned int)(keys[i] & 0xFFFFFFFFULL) == ba) ps += xv;
        xs += xv * (bf2f(ch[i]) + bf2f(cl[i]));
    }
    float s1p = (threadIdx.x < 16) ? cxc[(a << 4) + threadIdx.x] : 0.f;
    block_reduce_sum3(ps, xs, s1p, red);
    if (threadIdx.x == 0) {
        bstar[a] = ba;
        atomicAdd(&scal[0], ps);
        atomicAdd(&scal[2], xs);
        atomicAdd(&scal[1], s1p);
        atomicAdd(&num_amg[ba], xs - qt[(size_t)ba * A_DIM + a]);
    }
}

__global__ __launch_bounds__(256) void ndupdate_kernel(unsigned short* __restrict__ Chi,
                                                       unsigned short* __restrict__ Clo,
                                                       const int* __restrict__ bstar,
                                                       float* __restrict__ cxc,
                                                       float* __restrict__ cq,
                                                       float* __restrict__ num_amg,
                                                       const float* __restrict__ scal,
                                                       unsigned long long* __restrict__ keys) {
    int b = blockIdx.x;
    float den = scal[0] + scal[1] - 2.f * scal[2] + EPS_C;
    float lam = fminf(fmaxf((cxc[b] - cq[b] - num_amg[b]) / den, 0.f), 1.f);
    float om = 1.f - lam;
    int i = threadIdx.x;
    ushort4* h4 = (ushort4*)(Chi + (size_t)b * A_DIM);
    ushort4* l4 = (ushort4*)(Clo + (size_t)b * A_DIM);
    ushort4 h = h4[i], l = l4[i];
    int4 bs = ((const int4*)bstar)[i];
    float c0 = om * (bf2f(h.x) + bf2f(l.x)) + ((bs.x == b) ? lam : 0.f);
    float c1 = om * (bf2f(h.y) + bf2f(l.y)) + ((bs.y == b) ? lam : 0.f);
    float c2 = om * (bf2f(h.z) + bf2f(l.z)) + ((bs.z == b) ? lam : 0.f);
    float c3 = om * (bf2f(h.w) + bf2f(l.w)) + ((bs.w == b) ? lam : 0.f);
    split2(c0, h.x, l.x);
    split2(c1, h.y, l.y);
    split2(c2, h.z, l.z);
    split2(c3, h.w, l.w);
    h4[i] = h; l4[i] = l;
    __syncthreads();  // drains all reads above before the resets below
    if (i == 0) {
        cxc[b] = 0.f;
        cq[b] = 0.f;
        num_amg[b] = 0.f;
        if (b < A_DIM) keys[b] = ~0ULL;
    }
}

// ---------------- diff-phase small kernels ----------------

__global__ __launch_bounds__(256) void softmax_kernel(float* __restrict__ G,
                                                      unsigned short* __restrict__ Chi,
                                                      unsigned short* __restrict__ Clo,
                                                      float* __restrict__ num_cg,
                                                      float* __restrict__ scal3) {
    __shared__ float red[16];
    int b = blockIdx.x;
    int i = threadIdx.x;
    if (b == 0 && i == 0) *scal3 = 0.f;  // reset before the dot dispatch
    float4* g4 = (float4*)(G + (size_t)b * A_DIM);
    ushort4* h4 = (ushort4*)(Chi + (size_t)b * A_DIM);
    ushort4* l4 = (ushort4*)(Clo + (size_t)b * A_DIM);
    float4 g = g4[i];
    ushort4 h = h4[i], l = l4[i];
    float c0 = bf2f(h.x) + bf2f(l.x);
    float c1 = bf2f(h.y) + bf2f(l.y);
    float c2 = bf2f(h.z) + bf2f(l.z);
    float c3 = bf2f(h.w) + bf2f(l.w);
    float4 t = make_float4(-TEMP_C * g.x, -TEMP_C * g.y, -TEMP_C * g.z, -TEMP_C * g.w);
    float m = fmaxf(fmaxf(t.x, t.y), fmaxf(t.z, t.w));
    float M = block_reduce_max(m, red);
    float4 e = make_float4(expf(t.x - M), expf(t.y - M), expf(t.z - M), expf(t.w - M));
    float S = block_reduce_sum(e.x + e.y + e.z + e.w, red);
    float inv = 1.f / S;
    float4 sm = make_float4(e.x * inv, e.y * inv, e.z * inv, e.w * inv);
    float np = (c0 - sm.x) * g.x + (c1 - sm.y) * g.y + (c2 - sm.z) * g.z + (c3 - sm.w) * g.w;
    g4[i] = sm;
    split2(sm.x - c0, h.x, l.x);
    split2(sm.y - c1, h.y, l.y);
    split2(sm.z - c2, h.z, l.z);
    split2(sm.w - c3, h.w, l.w);
    h4[i] = h; l4[i] = l;
    float nt = block_reduce_sum(np, red);
    if (i == 0) num_cg[b] = nt;
}

__global__ __launch_bounds__(256) void dupdate_kernel(const float* __restrict__ G,
                                                      unsigned short* __restrict__ Chi,
                                                      unsigned short* __restrict__ Clo,
                                                      const float* __restrict__ num_cg,
                                                      const float* __restrict__ scal3) {
    int b = blockIdx.x;
    float den = *scal3 + EPS_C;
    float lam = fminf(fmaxf(num_cg[b] / den, 0.f), 1.f);
    float om = 1.f - lam;
    int i = threadIdx.x;
    const float4* g4 = (const float4*)(G + (size_t)b * A_DIM);
    ushort4* h4 = (ushort4*)(Chi + (size_t)b * A_DIM);
    ushort4* l4 = (ushort4*)(Clo + (size_t)b * A_DIM);
    float4 sm = g4[i];
    ushort4 h = h4[i], l = l4[i];
    float c0 = sm.x - om * (bf2f(h.x) + bf2f(l.x));
    float c1 = sm.y - om * (bf2f(h.y) + bf2f(l.y));
    float c2 = sm.z - om * (bf2f(h.z) + bf2f(l.z));
    float c3 = sm.w - om * (bf2f(h.w) + bf2f(l.w));
    split2(c0, h.x, l.x);
    split2(c1, h.y, l.y);
    split2(c2, h.z, l.z);
    split2(c3, h.w, l.w);
    h4[i] = h; l4[i] = l;
}

// recon: out[b, n] = (c_b . anT[:,n]) * ynorm[b]
__global__ __launch_bounds__(256) void mfma_recon(const unsigned short* __restrict__ Chi,
                                                  const unsigned short* __restrict__ Clo,
                                                  const unsigned short* __restrict__ AnTh,
                                                  const unsigned short* __restrict__ AnTl,
                                                  const float* __restrict__ ynorm,
                                                  float* __restrict__ out) {
    __shared__ unsigned short lds[16384];
    int tid = threadIdx.x;
    int w = tid >> 6, lane = tid & 63;
    int wm = w >> 1, wn = w & 1;
    int m0 = blockIdx.y * 128, n0 = blockIdx.x * 128;

    f32x4 acc[4][4];
#pragma unroll
    for (int i = 0; i < 4; i++)
#pragma unroll
        for (int j = 0; j < 4; j++) acc[i][j] = f32x4{0.f, 0.f, 0.f, 0.f};

    const unsigned short* gsrc;
    if (w == 0) gsrc = Chi + (size_t)m0 * A_DIM;
    else if (w == 1) gsrc = Clo + (size_t)m0 * A_DIM;
    else if (w == 2) gsrc = AnTh + (size_t)n0 * A_DIM;
    else gsrc = AnTl + (size_t)n0 * A_DIM;
    unsigned short* ltile = lds + w * 4096;
    for (int k0 = 0; k0 < A_DIM; k0 += 32) {
        stage_tile8(gsrc, A_DIM, k0, ltile, lane);
        __syncthreads();
        mfma_k32(lds, wm, wn, lane, acc);
        __syncthreads();
    }

    int crow = (lane >> 4) * 4, ccol = lane & 15;
#pragma unroll
    for (int i = 0; i < 4; i++) {
        int gm = m0 + wm * 64 + i * 16 + crow;
#pragma unroll
        for (int j = 0; j < 4; j++) {
            int gn = n0 + wn * 64 + j * 16 + ccol;
#pragma unroll
            for (int r = 0; r < 4; r++)
                out[(size_t)(gm + r) * D_DIM + gn] = acc[i][j][r] * ynorm[gm + r];
        }
    }
}

// ---------------- host launch ----------------

extern "C" void kernel_launch(void* const* d_in, const int* in_sizes, int n_in,
                              void* d_out, int out_size, void* d_ws, size_t ws_size,
                              hipStream_t stream) {
    const float* y = (const float*)d_in[0];      // [B, 768]
    const float* atoms = (const float*)d_in[1];  // [A, 768]
    float* out = (float*)d_out;                  // [B, 768]

    char* ws = (char*)d_ws;
    size_t off = 0;
    auto alloc = [&](size_t bytes) -> void* {
        void* p = ws + off;
        off += (bytes + 255) & ~(size_t)255;
        return p;
    };
    const size_t BA = (size_t)B_DIM * A_DIM;
    unsigned short* Chi = (unsigned short*)alloc(BA * 2);            // 32 MiB
    unsigned short* Clo = (unsigned short*)alloc(BA * 2);            // 32 MiB
    float* Greg = (float*)alloc(BA * 4);                             // 64 MiB (aliased)
    float* qt = (float*)alloc(BA * 4);                               // 64 MiB
    unsigned short* Xhi = (unsigned short*)alloc((size_t)A_DIM * A_DIM * 2);  // 2 MiB
    unsigned short* Xlo = (unsigned short*)alloc((size_t)A_DIM * A_DIM * 2);  // 2 MiB
    float* ynorm = (float*)alloc(B_DIM * 4);
    float* anrm  = (float*)alloc(A_DIM * 4);
    float* cxc   = (float*)alloc(B_DIM * 4);
    float* cq    = (float*)alloc(B_DIM * 4);
    float* num_amg = (float*)alloc(B_DIM * 4);
    float* num_cg  = (float*)alloc(B_DIM * 4);
    unsigned long long* keys = (unsigned long long*)alloc(A_DIM * 8);
    int* bstar = (int*)alloc(A_DIM * 4);
    float* scal = (float*)alloc(256);
    (void)ws_size; (void)in_sizes; (void)n_in; (void)out_size;

    // Greg aliases (floats):
    float* Xf = Greg;                                         // 4 MiB, live thru nondiff
    float* an = Greg + (size_t)A_DIM * A_DIM;                 // 3 MiB, setup only
    unsigned short* Anh = (unsigned short*)(an + (size_t)A_DIM * D_DIM);          // 1.5 MiB
    unsigned short* Anl = Anh + (size_t)A_DIM * D_DIM;                            // 1.5 MiB
    unsigned short* Ynh = Anl + (size_t)A_DIM * D_DIM;                            // 24 MiB
    unsigned short* Ynl = Ynh + (size_t)B_DIM * D_DIM;                            // 24 MiB
    float* G = Greg;                                          // diff phase (clobbers all)
    unsigned short* AnTh = (unsigned short*)Greg;             // post-diff recon
    unsigned short* AnTl = (unsigned short*)Greg + (size_t)D_DIM * A_DIM;

    // ---- setup ----
    ynorm_kernel<<<B_DIM, 256, 0, stream>>>(y, ynorm);
    yn_split_kernel<<<B_DIM, 256, 0, stream>>>(y, ynorm, Ynh, Ynl);
    anorm_kernel<<<A_DIM, 256, 0, stream>>>(atoms, an, anrm, Anh, Anl);
    gemm_xt<<<dim3(A_DIM / 128, A_DIM / 128), 256, 0, stream>>>(an, Xf);
    split_kernel<<<A_DIM * A_DIM / 4 / 256, 256, 0, stream>>>(Xf, Xhi, Xlo, A_DIM * A_DIM / 4);
    qt_mfma<<<1024, 256, 0, stream>>>(Ynh, Ynl, Anh, Anl, qt);
    fill_pair_kernel<<<(int)(BA / 4 / 256), 256, 0, stream>>>(Chi, Clo, BA / 4);
    init_kernel<<<B_DIM / 256, 256, 0, stream>>>(keys, num_amg, cxc, cq, scal);

    // ---- 30 nondiff steps ----
    for (int it = 0; it < 30; it++) {
        gemm256<0><<<256, 512, 0, stream>>>(Chi, Clo, Xhi, Xlo, qt,
                                            keys, cxc, cq, scal, nullptr, nullptr);
        stats_kernel<<<A_DIM, 256, 0, stream>>>(Xf, keys, Chi, Clo, qt, cxc,
                                                bstar, num_amg, scal);
        ndupdate_kernel<<<B_DIM, 256, 0, stream>>>(Chi, Clo, bstar, cxc, cq,
                                                   num_amg, scal, keys);
    }

    // ---- 10 diff steps (G clobbers Xf/setup region) ----
    for (int it = 0; it < 10; it++) {
        gemm256<1><<<256, 512, 0, stream>>>(Chi, nullptr, Xhi, Xlo, qt,
                                            nullptr, nullptr, nullptr, nullptr, G, nullptr);
        softmax_kernel<<<B_DIM, 256, 0, stream>>>(G, Chi, Clo, num_cg, &scal[3]);
        gemm256<2><<<256, 512, 0, stream>>>(Chi, Clo, Xhi, Xlo, nullptr,
                                            nullptr, nullptr, nullptr, nullptr, nullptr,
                                            &scal[3]);
        dupdate_kernel<<<B_DIM, 256, 0, stream>>>(G, Chi, Clo, num_cg, &scal[3]);
    }

    // ---- recon ----
    atrans_split_kernel<<<D_DIM, 256, 0, stream>>>(atoms, anrm, AnTh, AnTl);
    mfma_recon<<<dim3(D_DIM / 128, B_DIM / 128), 256, 0, stream>>>(Chi, Clo, AnTh, AnTl,
                                                                   ynorm, out);
}

// Round 6
// 6432.399 us; speedup vs baseline: 1.2546x; 1.1741x over previous
//
#include <hip/hip_runtime.h>
#include <hip/hip_bf16.h>
#include <math.h>

// Problem constants
#define A_DIM 1024      // NB_ATOMS
#define D_DIM 768       // 3*16*16
#define B_DIM 16384     // BATCH
#define TEMP_C 100.0f
#define EPS_C 1e-8f

// Round 12: nondiff XC-recurrence (work deletion).
//   XC = X@c tracked across iterations: XC' = (1-lam_b) XC + lam_b * T_b,
//   T_b = sum_{a: bstar[a]=b} Xf[a,:]  (exact fp32; c's split-rounding drift
//   ~1e-8/iter). Refresh XC with the real fused GEMM at t=0,8,16,24.
//   Non-refresh iters: grad_stream (streaming argmin/cxc/cq over XC - qt,
//   ~192 MB) replaces the 103-GF GEMM. ndupdate applies the recurrence
//   (bstar match-scan + row AXPY). XC lives in Greg (dead during nondiff);
//   Xf moved to its own 4 MiB alloc. Diff phase & GEMM schedule unchanged
//   from round 11 (verified absmax 4.88e-4).

typedef __attribute__((ext_vector_type(8))) short short8;
typedef __attribute__((ext_vector_type(4))) float f32x4;
#define MFMA16(a, b, c) __builtin_amdgcn_mfma_f32_16x16x32_bf16(a, b, c, 0, 0, 0)

typedef __attribute__((address_space(3))) unsigned char lds_byte;
typedef __attribute__((address_space(1))) const unsigned char g_byte;
__device__ __forceinline__ void async_copy16(const void* gptr, void* lptr) {
    __builtin_amdgcn_global_load_lds((g_byte*)gptr, (lds_byte*)lptr, 16, 0, 0);
}

#define SCHED0 __builtin_amdgcn_sched_barrier(0)
#define ASM_BAR asm volatile("s_barrier" ::: "memory")

// XCD-slab swizzle for 1024-block GEMM grids (qt_mfma only)
__device__ __forceinline__ void swz(int i, int& m0, int& n0) {
    int xcd = i & 7, j = i >> 3;
    m0 = ((xcd << 4) + (j >> 3)) << 7;
    n0 = (j & 7) << 7;
}

// ---------------- reductions (wave shuffle + tiny LDS combine) ----------------

__device__ __forceinline__ float wave_sum(float v) {
#pragma unroll
    for (int m = 1; m < 64; m <<= 1) v += __shfl_xor(v, m);
    return v;
}
__device__ __forceinline__ float wave_max(float v) {
#pragma unroll
    for (int m = 1; m < 64; m <<= 1) v = fmaxf(v, __shfl_xor(v, m));
    return v;
}

__device__ __forceinline__ float block_reduce_sum(float v, float* red) {
    int t = threadIdx.x;
    v = wave_sum(v);
    if ((t & 63) == 0) red[t >> 6] = v;
    __syncthreads();
    float r = red[0] + red[1] + red[2] + red[3];
    __syncthreads();
    return r;
}

__device__ __forceinline__ float block_reduce_max(float v, float* red) {
    int t = threadIdx.x;
    v = wave_max(v);
    if ((t & 63) == 0) red[t >> 6] = v;
    __syncthreads();
    float r = fmaxf(fmaxf(red[0], red[1]), fmaxf(red[2], red[3]));
    __syncthreads();
    return r;
}

__device__ __forceinline__ void block_reduce_sum3(float& a, float& b, float& c, float* red) {
    int t = threadIdx.x;
    a = wave_sum(a);
    b = wave_sum(b);
    c = wave_sum(c);
    if ((t & 63) == 0) {
        int w = t >> 6;
        red[w] = a; red[4 + w] = b; red[8 + w] = c;
    }
    __syncthreads();
    a = red[0] + red[1] + red[2] + red[3];
    b = red[4] + red[5] + red[6] + red[7];
    c = red[8] + red[9] + red[10] + red[11];
    __syncthreads();
}

// ---------------- small helpers ----------------

__device__ __forceinline__ unsigned int fkey(float v) {
    unsigned int u = __float_as_uint(v);
    return u ^ ((u & 0x80000000u) ? 0xFFFFFFFFu : 0x80000000u);
}

__device__ __forceinline__ unsigned short f2bf(float x) {
    unsigned int u = __float_as_uint(x);
    return (unsigned short)((u + 0x7FFFu + ((u >> 16) & 1u)) >> 16);
}
__device__ __forceinline__ float bf2f(unsigned short h) {
    return __uint_as_float(((unsigned int)h) << 16);
}
__device__ __forceinline__ void split2(float x, unsigned short& hi, unsigned short& lo) {
    hi = f2bf(x);
    lo = f2bf(x - bf2f(hi));
}

// ---------------- 128^2 MFMA building blocks (qt_mfma / mfma_recon) ----------------

__device__ __forceinline__ void stage_tile8(const unsigned short* gsrc, int stride, int k0,
                                            unsigned short* ltile, int lane) {
    int srow = lane >> 2;
    int scol = (lane & 3) * 8;
#pragma unroll
    for (int s = 0; s < 8; s++) {
        const unsigned short* src = gsrc + (size_t)(s * 16 + srow) * stride + k0 + scol;
        async_copy16(src, ltile + s * 512);
    }
}

// 3-product (pair x pair) K=32 step
__device__ __forceinline__ void mfma_k32(const unsigned short* lds, int wm, int wn, int lane,
                                         f32x4 acc[4][4]) {
    int frow = lane & 15, fk = (lane >> 4) * 8;
    short8 ah[4], al[4], bh[4], bl[4];
#pragma unroll
    for (int t = 0; t < 4; t++) {
        int ar = (wm * 64 + t * 16 + frow) * 32 + fk;
        ah[t] = *(const short8*)&lds[ar];
        al[t] = *(const short8*)&lds[4096 + ar];
        int br = (wn * 64 + t * 16 + frow) * 32 + fk;
        bh[t] = *(const short8*)&lds[8192 + br];
        bl[t] = *(const short8*)&lds[12288 + br];
    }
#pragma unroll
    for (int i = 0; i < 4; i++)
#pragma unroll
        for (int j = 0; j < 4; j++) {
            acc[i][j] = MFMA16(ah[i], bh[j], acc[i][j]);
            acc[i][j] = MFMA16(ah[i], bl[j], acc[i][j]);
            acc[i][j] = MFMA16(al[i], bh[j], acc[i][j]);
        }
}

// ---------------- 256^2 phase-split pipelined GEMM core ----------------
// MODE 0: A = pair (Chi,Clo), 3 products, nondiff epilogue (argmin/cxc/cq) + XC write
// MODE 1: A = single hi, 2 products, epilogue G = acc - qt
// MODE 2: A = single hi, 2 products, epilogue scal3 += sum(acc * (Ahi+Alo pair))

template <int MODE, int PART>
__device__ __forceinline__ void stage_part(unsigned short* buf,
                                           const unsigned short* Ahi,
                                           const unsigned short* Alo,
                                           const unsigned short* Xhi,
                                           const unsigned short* Xlo,
                                           int m0, int n0, int k0, int t) {
    constexpr int AHI = 0;
    constexpr int ALO = 8192;
    constexpr int BHI = (MODE == 0) ? 16384 : 8192;
    constexpr int BLO = BHI + 8192;
    int r = t >> 2;
    int cg = (t & 3) ^ ((t >> 3) & 3);    // pre-swizzled source chunk
    size_t col = (size_t)k0 + cg * 8;
    if constexpr (MODE == 0) {
        if constexpr (PART == 0) {
            async_copy16(Ahi + (size_t)(m0 + r) * A_DIM + col,       buf + AHI + t * 8);
            async_copy16(Ahi + (size_t)(m0 + 128 + r) * A_DIM + col, buf + AHI + 4096 + t * 8);
        } else if constexpr (PART == 1) {
            async_copy16(Alo + (size_t)(m0 + r) * A_DIM + col,       buf + ALO + t * 8);
            async_copy16(Alo + (size_t)(m0 + 128 + r) * A_DIM + col, buf + ALO + 4096 + t * 8);
        } else if constexpr (PART == 2) {
            async_copy16(Xhi + (size_t)(n0 + r) * A_DIM + col,       buf + BHI + t * 8);
            async_copy16(Xhi + (size_t)(n0 + 128 + r) * A_DIM + col, buf + BHI + 4096 + t * 8);
        } else {
            async_copy16(Xlo + (size_t)(n0 + r) * A_DIM + col,       buf + BLO + t * 8);
            async_copy16(Xlo + (size_t)(n0 + 128 + r) * A_DIM + col, buf + BLO + 4096 + t * 8);
        }
    } else {
        if constexpr (PART == 0) {
            async_copy16(Ahi + (size_t)(m0 + r) * A_DIM + col,       buf + AHI + t * 8);
            async_copy16(Ahi + (size_t)(m0 + 128 + r) * A_DIM + col, buf + AHI + 4096 + t * 8);
        } else if constexpr (PART == 1) {
            async_copy16(Xhi + (size_t)(n0 + r) * A_DIM + col,       buf + BHI + t * 8);
            async_copy16(Xhi + (size_t)(n0 + 128 + r) * A_DIM + col, buf + BHI + 4096 + t * 8);
        } else if constexpr (PART == 2) {
            async_copy16(Xlo + (size_t)(n0 + r) * A_DIM + col,       buf + BLO + t * 8);
            async_copy16(Xlo + (size_t)(n0 + 128 + r) * A_DIM + col, buf + BLO + 4096 + t * 8);
        }
    }
}

__device__ __forceinline__ void mfma_mi3(short8 ah, short8 al,
                                         const short8 bh[4], const short8 bl[4],
                                         f32x4* accRow) {
#pragma unroll
    for (int j = 0; j < 4; j++) {
        accRow[j] = MFMA16(ah, bh[j], accRow[j]);
        accRow[j] = MFMA16(ah, bl[j], accRow[j]);
        accRow[j] = MFMA16(al, bh[j], accRow[j]);
    }
}
__device__ __forceinline__ void mfma_mi2(short8 ah,
                                         const short8 bh[4], const short8 bl[4],
                                         f32x4* accRow) {
#pragma unroll
    for (int j = 0; j < 4; j++) {
        accRow[j] = MFMA16(ah, bh[j], accRow[j]);
        accRow[j] = MFMA16(ah, bl[j], accRow[j]);
    }
}

template <int MODE>
__global__ __launch_bounds__(512, 2) void gemm256(const unsigned short* __restrict__ Ahi,
                                                  const unsigned short* __restrict__ Alo,
                                                  const unsigned short* __restrict__ Xhi,
                                                  const unsigned short* __restrict__ Xlo,
                                                  const float* __restrict__ qt,
                                                  unsigned long long* __restrict__ keys,
                                                  float* __restrict__ cxc,
                                                  float* __restrict__ cq,
                                                  float* __restrict__ scal,
                                                  float* __restrict__ G,
                                                  float* __restrict__ scal3,
                                                  float* __restrict__ XC) {
    constexpr int BUFS = (MODE == 0) ? 32768 : 24576;   // shorts per buffer
    constexpr int AHI = 0;
    constexpr int ALO = 8192;
    constexpr int BHI = (MODE == 0) ? 16384 : 8192;
    constexpr int BLO = BHI + 8192;
    __shared__ unsigned short lds[2 * BUFS];
    __shared__ float red[8];
    int tid = threadIdx.x;
    if (MODE == 0 && blockIdx.x == 0 && tid < 4) scal[tid] = 0.f;
    int w = tid >> 6, lane = tid & 63;
    int wm = w >> 2, wn = w & 3;          // 2 x 4 wave grid
    int bi = blockIdx.x;
    int xcd = bi & 7, bj = bi >> 3;
    int m0 = ((xcd << 3) + (bj >> 2)) << 8;
    int n0 = (bj & 3) << 8;

    f32x4 acc[8][4];
#pragma unroll
    for (int i = 0; i < 8; i++)
#pragma unroll
        for (int j = 0; j < 4; j++) acc[i][j] = f32x4{0.f, 0.f, 0.f, 0.f};

    int frow = lane & 15;
    int sw = ((lane >> 4) ^ ((frow >> 1) & 3)) * 8;   // read-side chunk swizzle

    stage_part<MODE, 0>(lds, Ahi, Alo, Xhi, Xlo, m0, n0, 0, tid);
    stage_part<MODE, 1>(lds, Ahi, Alo, Xhi, Xlo, m0, n0, 0, tid);
    stage_part<MODE, 2>(lds, Ahi, Alo, Xhi, Xlo, m0, n0, 0, tid);
    stage_part<MODE, 3>(lds, Ahi, Alo, Xhi, Xlo, m0, n0, 0, tid);

    int cur = 0;
    for (int ks = 0; ks < 32; ++ks) {
        unsigned short* rb = lds + cur * BUFS;
        unsigned short* wb = lds + (cur ^ 1) * BUFS;
        const bool pf = (ks < 31);
        const int k1 = (ks + 1) * 32;

        if (pf) {
            stage_part<MODE, 0>(wb, Ahi, Alo, Xhi, Xlo, m0, n0, k1, tid);
            SCHED0;
            asm volatile("s_waitcnt vmcnt(2)" ::: "memory");
        } else {
            asm volatile("s_waitcnt vmcnt(0)" ::: "memory");
        }
        SCHED0; ASM_BAR; SCHED0;

        short8 bh[4], bl[4];
#pragma unroll
        for (int j = 0; j < 4; j++) {
            int br = wn * 64 + j * 16 + frow;
            bh[j] = *(const short8*)&rb[BHI + br * 32 + sw];
            bl[j] = *(const short8*)&rb[BLO + br * 32 + sw];
        }
        {
            int ar0 = wm * 128 + 0 * 16 + frow, ar1 = wm * 128 + 1 * 16 + frow;
            short8 a0h = *(const short8*)&rb[AHI + ar0 * 32 + sw];
            short8 a1h = *(const short8*)&rb[AHI + ar1 * 32 + sw];
            short8 a0l, a1l;
            if constexpr (MODE == 0) {
                a0l = *(const short8*)&rb[ALO + ar0 * 32 + sw];
                a1l = *(const short8*)&rb[ALO + ar1 * 32 + sw];
            }
            if (pf) stage_part<MODE, 1>(wb, Ahi, Alo, Xhi, Xlo, m0, n0, k1, tid);
            SCHED0; ASM_BAR; SCHED0;
            asm volatile("s_waitcnt lgkmcnt(0)" ::: "memory"); SCHED0;
            __builtin_amdgcn_s_setprio(1);
            if constexpr (MODE == 0) { mfma_mi3(a0h, a0l, bh, bl, acc[0]); mfma_mi3(a1h, a1l, bh, bl, acc[1]); }
            else                     { mfma_mi2(a0h, bh, bl, acc[0]);      mfma_mi2(a1h, bh, bl, acc[1]); }
            __builtin_amdgcn_s_setprio(0);
            SCHED0; ASM_BAR; SCHED0;
        }
#pragma unroll
        for (int ph = 1; ph < 4; ph++) {
            int mia = 2 * ph, mib = 2 * ph + 1;
            int ara = wm * 128 + mia * 16 + frow, arb = wm * 128 + mib * 16 + frow;
            short8 aah = *(const short8*)&rb[AHI + ara * 32 + sw];
            short8 abh = *(const short8*)&rb[AHI + arb * 32 + sw];
            short8 aal, abl;
            if constexpr (MODE == 0) {
                aal = *(const short8*)&rb[ALO + ara * 32 + sw];
                abl = *(const short8*)&rb[ALO + arb * 32 + sw];
            }
            if (pf) {
                if (ph == 1) stage_part<MODE, 2>(wb, Ahi, Alo, Xhi, Xlo, m0, n0, k1, tid);
                if (ph == 2) stage_part<MODE, 3>(wb, Ahi, Alo, Xhi, Xlo, m0, n0, k1, tid);
            }
            SCHED0; ASM_BAR; SCHED0;
            asm volatile("s_waitcnt lgkmcnt(0)" ::: "memory"); SCHED0;
            __builtin_amdgcn_s_setprio(1);
            if constexpr (MODE == 0) { mfma_mi3(aah, aal, bh, bl, acc[mia]); mfma_mi3(abh, abl, bh, bl, acc[mib]); }
            else                     { mfma_mi2(aah, bh, bl, acc[mia]);      mfma_mi2(abh, bh, bl, acc[mib]); }
            __builtin_amdgcn_s_setprio(0);
            SCHED0; ASM_BAR; SCHED0;
        }
        cur ^= 1;
    }

    int crow = (lane >> 4) * 4, ccol = lane & 15;
    if constexpr (MODE == 0) {
        unsigned long long best[4] = {~0ULL, ~0ULL, ~0ULL, ~0ULL};
#pragma unroll
        for (int mi = 0; mi < 8; mi++)
#pragma unroll
            for (int r = 0; r < 4; r++) {
                int gm = m0 + wm * 128 + mi * 16 + crow + r;
                float pcx = 0.f, pcq = 0.f;
#pragma unroll
                for (int jj = 0; jj < 4; jj++) {
                    int gn = n0 + wn * 64 + jj * 16 + ccol;
                    size_t idx = (size_t)gm * A_DIM + gn;
                    float c = bf2f(Ahi[idx]) + bf2f(Alo[idx]);
                    float q = qt[idx];
                    float xc = acc[mi][jj][r];
                    XC[idx] = xc;               // refresh the tracked X@c
                    pcx += c * xc;
                    pcq += c * q;
                    unsigned long long key =
                        ((unsigned long long)fkey(xc - q) << 32) | (unsigned int)gm;
                    if (key < best[jj]) best[jj] = key;
                }
                for (int mm = 1; mm < 16; mm <<= 1) {
                    pcx += __shfl_xor(pcx, mm, 16);
                    pcq += __shfl_xor(pcq, mm, 16);
                }
                if (ccol == 0) {
                    atomicAdd(&cxc[gm], pcx);
                    atomicAdd(&cq[gm], pcq);
                }
            }
#pragma unroll
        for (int jj = 0; jj < 4; jj++) {
            int gn = n0 + wn * 64 + jj * 16 + ccol;
            unsigned long long o = __shfl_xor(best[jj], 16);
            if (o < best[jj]) best[jj] = o;
            o = __shfl_xor(best[jj], 32);
            if (o < best[jj]) best[jj] = o;
            if ((lane >> 4) == 0) atomicMin(&keys[gn], best[jj]);
        }
    } else if constexpr (MODE == 1) {
#pragma unroll
        for (int mi = 0; mi < 8; mi++)
#pragma unroll
            for (int r = 0; r < 4; r++) {
                int gm = m0 + wm * 128 + mi * 16 + crow + r;
#pragma unroll
                for (int jj = 0; jj < 4; jj++) {
                    int gn = n0 + wn * 64 + jj * 16 + ccol;
                    size_t idx = (size_t)gm * A_DIM + gn;
                    G[idx] = acc[mi][jj][r] - qt[idx];
                }
            }
    } else {
        float part = 0.f;
#pragma unroll
        for (int mi = 0; mi < 8; mi++)
#pragma unroll
            for (int r = 0; r < 4; r++) {
                int gm = m0 + wm * 128 + mi * 16 + crow + r;
#pragma unroll
                for (int jj = 0; jj < 4; jj++) {
                    int gn = n0 + wn * 64 + jj * 16 + ccol;
                    size_t idx = (size_t)gm * A_DIM + gn;
                    float d = bf2f(Ahi[idx]) + bf2f(Alo[idx]);
                    part += acc[mi][jj][r] * d;
                }
            }
        part = wave_sum(part);
        if (lane == 0) red[w] = part;
        __syncthreads();
        if (tid == 0) {
            float tot = red[0] + red[1] + red[2] + red[3] +
                        red[4] + red[5] + red[6] + red[7];
            atomicAdd(scal3, tot);
        }
    }
}

// ---------------- streaming argmin/cxc/cq over XC - qt (non-refresh iters) ----------------
// Block = 64 batch rows x 1024 atoms; wave w handles rows b0+w+4k (full row).
__global__ __launch_bounds__(256) void grad_stream(const float* __restrict__ XC,
                                                   const float* __restrict__ qt,
                                                   const unsigned short* __restrict__ Chi,
                                                   const unsigned short* __restrict__ Clo,
                                                   unsigned long long* __restrict__ keys,
                                                   float* __restrict__ cxc,
                                                   float* __restrict__ cq,
                                                   float* __restrict__ scal) {
    __shared__ unsigned long long lkeys[4][1024];   // 32 KiB
    int tid = threadIdx.x;
    if (blockIdx.x == 0 && tid < 4) scal[tid] = 0.f;
    int w = tid >> 6, lane = tid & 63;
    int b0 = blockIdx.x * 64;

    unsigned long long best[16];
#pragma unroll
    for (int i = 0; i < 16; i++) best[i] = ~0ULL;

    for (int rr = 0; rr < 16; ++rr) {
        int b = b0 + w + rr * 4;
        const float* xcr = XC + (size_t)b * A_DIM;
        const float* qr  = qt + (size_t)b * A_DIM;
        const unsigned short* hr = Chi + (size_t)b * A_DIM;
        const unsigned short* lr = Clo + (size_t)b * A_DIM;
        float dx = 0.f, dq = 0.f;
#pragma unroll
        for (int ch = 0; ch < 4; ++ch) {
            int col = ch * 256 + lane * 4;
            float4 xv = *(const float4*)(xcr + col);
            float4 qv = *(const float4*)(qr + col);
            ushort4 hv = *(const ushort4*)(hr + col);
            ushort4 lv = *(const ushort4*)(lr + col);
            float c0 = bf2f(hv.x) + bf2f(lv.x);
            float c1 = bf2f(hv.y) + bf2f(lv.y);
            float c2 = bf2f(hv.z) + bf2f(lv.z);
            float c3 = bf2f(hv.w) + bf2f(lv.w);
            dx += c0 * xv.x + c1 * xv.y + c2 * xv.z + c3 * xv.w;
            dq += c0 * qv.x + c1 * qv.y + c2 * qv.z + c3 * qv.w;
            float g[4] = {xv.x - qv.x, xv.y - qv.y, xv.z - qv.z, xv.w - qv.w};
#pragma unroll
            for (int j = 0; j < 4; ++j) {
                unsigned long long key =
                    ((unsigned long long)fkey(g[j]) << 32) | (unsigned int)b;
                if (key < best[ch * 4 + j]) best[ch * 4 + j] = key;
            }
        }
        dx = wave_sum(dx);
        dq = wave_sum(dq);
        if (lane == 0) { cxc[b] = dx; cq[b] = dq; }   // exclusive row owner
    }
#pragma unroll
    for (int ch = 0; ch < 4; ++ch)
#pragma unroll
        for (int j = 0; j < 4; ++j)
            lkeys[w][ch * 256 + lane * 4 + j] = best[ch * 4 + j];
    __syncthreads();
    for (int i = tid; i < 1024; i += 256) {
        unsigned long long v = lkeys[0][i];
        if (lkeys[1][i] < v) v = lkeys[1][i];
        if (lkeys[2][i] < v) v = lkeys[2][i];
        if (lkeys[3][i] < v) v = lkeys[3][i];
        atomicMin(&keys[i], v);
    }
}

// ---------------- setup kernels ----------------

__global__ __launch_bounds__(256) void ynorm_kernel(const float* __restrict__ y,
                                                    float* __restrict__ ynorm) {
    __shared__ float red[16];
    int b = blockIdx.x;
    const float* row = y + (size_t)b * D_DIM;
    float s = 0.f;
    for (int i = threadIdx.x; i < D_DIM; i += 256) s += fabsf(row[i]);
    float tot = block_reduce_sum(s, red);
    if (threadIdx.x == 0) ynorm[b] = tot;
}

__global__ __launch_bounds__(256) void yn_split_kernel(const float* __restrict__ y,
                                                       const float* __restrict__ ynorm,
                                                       unsigned short* __restrict__ Ynh,
                                                       unsigned short* __restrict__ Ynl) {
    int b = blockIdx.x;
    float inv = 1.f / ynorm[b];
    const float* row = y + (size_t)b * D_DIM;
    unsigned short* oh = Ynh + (size_t)b * D_DIM;
    unsigned short* ol = Ynl + (size_t)b * D_DIM;
    for (int i = threadIdx.x; i < D_DIM; i += 256) {
        unsigned short h, l;
        split2(row[i] * inv, h, l);
        oh[i] = h; ol[i] = l;
    }
}

__global__ __launch_bounds__(256) void anorm_kernel(const float* __restrict__ atoms,
                                                    float* __restrict__ an,
                                                    float* __restrict__ anrm,
                                                    unsigned short* __restrict__ Anh,
                                                    unsigned short* __restrict__ Anl) {
    __shared__ float red[16];
    int a = blockIdx.x;
    const float* row = atoms + (size_t)a * D_DIM;
    float s = 0.f;
    for (int i = threadIdx.x; i < D_DIM; i += 256) s += fabsf(row[i]);
    float tot = block_reduce_sum(s, red);
    float inv = 1.f / tot;
    for (int i = threadIdx.x; i < D_DIM; i += 256) {
        float v = row[i] * inv;
        an[(size_t)a * D_DIM + i] = v;
        unsigned short h, l;
        split2(v, h, l);
        Anh[(size_t)a * D_DIM + i] = h;
        Anl[(size_t)a * D_DIM + i] = l;
    }
    if (threadIdx.x == 0) anrm[a] = tot;
}

__global__ __launch_bounds__(256) void atrans_split_kernel(const float* __restrict__ atoms,
                                                           const float* __restrict__ anrm,
                                                           unsigned short* __restrict__ AnTh,
                                                           unsigned short* __restrict__ AnTl) {
    int n = blockIdx.x;
    for (int k = threadIdx.x; k < A_DIM; k += 256) {
        float v = atoms[(size_t)k * D_DIM + n] / anrm[k];
        unsigned short h, l;
        split2(v, h, l);
        AnTh[(size_t)n * A_DIM + k] = h;
        AnTl[(size_t)n * A_DIM + k] = l;
    }
}

__global__ __launch_bounds__(256) void split_kernel(const float* __restrict__ src,
                                                    unsigned short* __restrict__ hi,
                                                    unsigned short* __restrict__ lo,
                                                    int n4) {
    int i = blockIdx.x * 256 + threadIdx.x;
    if (i < n4) {
        float4 v = ((const float4*)src)[i];
        ushort4 h, l;
        split2(v.x, h.x, l.x);
        split2(v.y, h.y, l.y);
        split2(v.z, h.z, l.z);
        split2(v.w, h.w, l.w);
        ((ushort4*)hi)[i] = h;
        ((ushort4*)lo)[i] = l;
    }
}

__global__ __launch_bounds__(256) void fill_pair_kernel(unsigned short* __restrict__ Chi,
                                                        unsigned short* __restrict__ Clo,
                                                        size_t n4) {
    size_t i = (size_t)blockIdx.x * 256 + threadIdx.x;
    if (i < n4) {
        unsigned short h, l;
        split2(1.f / A_DIM, h, l);
        ((ushort4*)Chi)[i] = make_ushort4(h, h, h, h);
        ((ushort4*)Clo)[i] = make_ushort4(l, l, l, l);
    }
}

// fp32 vector GEMM, B transposed, setup only: X = an @ an^T
__global__ __launch_bounds__(256) void gemm_xt(const float* __restrict__ Aop,
                                               float* __restrict__ Cout) {
    const int LDT = 132;
    const int N = A_DIM, K = D_DIM;
    __shared__ float As[16 * LDT];
    __shared__ float Bs[16 * LDT];
    int m0 = blockIdx.y * 128, n0 = blockIdx.x * 128;
    int tid = threadIdx.x;
    int tx = tid & 15, ty = tid >> 4;
    float acc[8][8];
#pragma unroll
    for (int i = 0; i < 8; i++)
#pragma unroll
        for (int j = 0; j < 8; j++) acc[i][j] = 0.f;
    for (int k0 = 0; k0 < K; k0 += 16) {
#pragma unroll
        for (int s = 0; s < 2; s++) {
            int idx = tid + s * 256;
            int row = idx >> 2, kq = (idx & 3) * 4;
            float4 v = *(const float4*)(Aop + (size_t)(m0 + row) * K + k0 + kq);
            As[(kq + 0) * LDT + row] = v.x;
            As[(kq + 1) * LDT + row] = v.y;
            As[(kq + 2) * LDT + row] = v.z;
            As[(kq + 3) * LDT + row] = v.w;
        }
#pragma unroll
        for (int s = 0; s < 2; s++) {
            int idx = tid + s * 256;
            int row = idx >> 2, kq = (idx & 3) * 4;
            float4 v = *(const float4*)(Aop + (size_t)(n0 + row) * K + k0 + kq);
            Bs[(kq + 0) * LDT + row] = v.x;
            Bs[(kq + 1) * LDT + row] = v.y;
            Bs[(kq + 2) * LDT + row] = v.z;
            Bs[(kq + 3) * LDT + row] = v.w;
        }
        __syncthreads();
#pragma unroll
        for (int kk = 0; kk < 16; kk++) {
            float a[8], b[8];
            *(float4*)(a)     = *(const float4*)(As + kk * LDT + ty * 8);
            *(float4*)(a + 4) = *(const float4*)(As + kk * LDT + ty * 8 + 4);
            *(float4*)(b)     = *(const float4*)(Bs + kk * LDT + tx * 8);
            *(float4*)(b + 4) = *(const float4*)(Bs + kk * LDT + tx * 8 + 4);
#pragma unroll
            for (int i = 0; i < 8; i++)
#pragma unroll
                for (int j = 0; j < 8; j++) acc[i][j] = fmaf(a[i], b[j], acc[i][j]);
        }
        __syncthreads();
    }
#pragma unroll
    for (int i = 0; i < 8; i++) {
        int row = m0 + ty * 8 + i;
#pragma unroll
        for (int j = 0; j < 8; j += 4) {
            int col = n0 + tx * 8 + j;
            float4 v = make_float4(acc[i][j], acc[i][j + 1], acc[i][j + 2], acc[i][j + 3]);
            *(float4*)(Cout + (size_t)row * N + col) = v;
        }
    }
}

// qt = Yn @ An^T  (bf16x2 pair-pair MFMA, K=768), swizzled 1D grid of 1024
__global__ __launch_bounds__(256) void qt_mfma(const unsigned short* __restrict__ Ynh,
                                               const unsigned short* __restrict__ Ynl,
                                               const unsigned short* __restrict__ Anh,
                                               const unsigned short* __restrict__ Anl,
                                               float* __restrict__ qt) {
    __shared__ unsigned short lds[16384];
    int tid = threadIdx.x;
    int w = tid >> 6, lane = tid & 63;
    int wm = w >> 1, wn = w & 1;
    int m0, n0;
    swz(blockIdx.x, m0, n0);

    f32x4 acc[4][4];
#pragma unroll
    for (int i = 0; i < 4; i++)
#pragma unroll
        for (int j = 0; j < 4; j++) acc[i][j] = f32x4{0.f, 0.f, 0.f, 0.f};

    const unsigned short* gsrc;
    if (w == 0) gsrc = Ynh + (size_t)m0 * D_DIM;
    else if (w == 1) gsrc = Ynl + (size_t)m0 * D_DIM;
    else if (w == 2) gsrc = Anh + (size_t)n0 * D_DIM;
    else gsrc = Anl + (size_t)n0 * D_DIM;
    unsigned short* ltile = lds + w * 4096;
    for (int k0 = 0; k0 < D_DIM; k0 += 32) {
        stage_tile8(gsrc, D_DIM, k0, ltile, lane);
        __syncthreads();
        mfma_k32(lds, wm, wn, lane, acc);
        __syncthreads();
    }

    int crow = (lane >> 4) * 4, ccol = lane & 15;
#pragma unroll
    for (int i = 0; i < 4; i++) {
        int gm = m0 + wm * 64 + i * 16 + crow;
#pragma unroll
        for (int j = 0; j < 4; j++) {
            int gn = n0 + wn * 64 + j * 16 + ccol;
#pragma unroll
            for (int r = 0; r < 4; r++)
                qt[(size_t)(gm + r) * A_DIM + gn] = acc[i][j][r];
        }
    }
}

// ---------------- nondiff per-iteration kernels ----------------

__global__ __launch_bounds__(256) void init_kernel(unsigned long long* __restrict__ keys,
                                                   float* __restrict__ num_amg,
                                                   float* __restrict__ cxc,
                                                   float* __restrict__ cq,
                                                   float* __restrict__ scal) {
    int i = blockIdx.x * 256 + threadIdx.x;
    num_amg[i] = 0.f;
    cxc[i] = 0.f;
    cq[i] = 0.f;
    if (i < A_DIM) keys[i] = ~0ULL;
    if (i < 4) scal[i] = 0.f;
}

__global__ __launch_bounds__(256) void stats_kernel(const float* __restrict__ Xf,
                                                    const unsigned long long* __restrict__ keys,
                                                    const unsigned short* __restrict__ Chi,
                                                    const unsigned short* __restrict__ Clo,
                                                    const float* __restrict__ qt,
                                                    const float* __restrict__ cxc,
                                                    int* __restrict__ bstar,
                                                    float* __restrict__ num_amg,
                                                    float* __restrict__ scal) {
    __shared__ float red[16];
    int a = blockIdx.x;
    int ba = (int)(unsigned int)(keys[a] & 0xFFFFFFFFULL);
    const float* xr = Xf + (size_t)a * A_DIM;
    const unsigned short* ch = Chi + (size_t)ba * A_DIM;
    const unsigned short* cl = Clo + (size_t)ba * A_DIM;
    float ps = 0.f, xs = 0.f;
    for (int i = threadIdx.x; i < A_DIM; i += 256) {
        float xv = xr[i];
        if ((int)(unsigned int)(keys[i] & 0xFFFFFFFFULL) == ba) ps += xv;
        xs += xv * (bf2f(ch[i]) + bf2f(cl[i]));
    }
    float s1p = (threadIdx.x < 16) ? cxc[(a << 4) + threadIdx.x] : 0.f;
    block_reduce_sum3(ps, xs, s1p, red);
    if (threadIdx.x == 0) {
        bstar[a] = ba;
        atomicAdd(&scal[0], ps);
        atomicAdd(&scal[2], xs);
        atomicAdd(&scal[1], s1p);
        atomicAdd(&num_amg[ba], xs - qt[(size_t)ba * A_DIM + a]);
    }
}

// nondiff update: c' = (1-lam)c + lam*am (splits refreshed) AND the XC
// recurrence XC[b,:] = (1-lam_b) XC[b,:] + lam_b * sum_{a: bstar[a]=b} Xf[a,:].
// Tail resets per-iteration accumulators (block-owned, kernel-boundary ordered).
__global__ __launch_bounds__(256) void ndupdate_kernel(unsigned short* __restrict__ Chi,
                                                       unsigned short* __restrict__ Clo,
                                                       const int* __restrict__ bstar,
                                                       float* __restrict__ cxc,
                                                       float* __restrict__ cq,
                                                       float* __restrict__ num_amg,
                                                       const float* __restrict__ scal,
                                                       unsigned long long* __restrict__ keys,
                                                       float* __restrict__ XC,
                                                       const float* __restrict__ Xf) {
    __shared__ int mlist[1024];
    __shared__ int mcount;
    int b = blockIdx.x;
    int i = threadIdx.x;
    if (i == 0) mcount = 0;
    float den = scal[0] + scal[1] - 2.f * scal[2] + EPS_C;
    float lam = fminf(fmaxf((cxc[b] - cq[b] - num_amg[b]) / den, 0.f), 1.f);
    float om = 1.f - lam;
    ushort4* h4 = (ushort4*)(Chi + (size_t)b * A_DIM);
    ushort4* l4 = (ushort4*)(Clo + (size_t)b * A_DIM);
    ushort4 h = h4[i], l = l4[i];
    int4 bs = ((const int4*)bstar)[i];
    float c0 = om * (bf2f(h.x) + bf2f(l.x)) + ((bs.x == b) ? lam : 0.f);
    float c1 = om * (bf2f(h.y) + bf2f(l.y)) + ((bs.y == b) ? lam : 0.f);
    float c2 = om * (bf2f(h.z) + bf2f(l.z)) + ((bs.z == b) ? lam : 0.f);
    float c3 = om * (bf2f(h.w) + bf2f(l.w)) + ((bs.w == b) ? lam : 0.f);
    split2(c0, h.x, l.x);
    split2(c1, h.y, l.y);
    split2(c2, h.z, l.z);
    split2(c3, h.w, l.w);
    h4[i] = h; l4[i] = l;
    __syncthreads();              // mcount visible; c reads drained
    for (int a = i; a < A_DIM; a += 256)
        if (bstar[a] == b) { int p = atomicAdd(&mcount, 1); mlist[p] = a; }
    __syncthreads();
    float4 xv = *(float4*)(XC + (size_t)b * A_DIM + i * 4);
    xv.x *= om; xv.y *= om; xv.z *= om; xv.w *= om;
    int mc = mcount;
    for (int m = 0; m < mc; m++) {
        float4 av = *(const float4*)(Xf + (size_t)mlist[m] * A_DIM + i * 4);
        xv.x += lam * av.x; xv.y += lam * av.y;
        xv.z += lam * av.z; xv.w += lam * av.w;
    }
    *(float4*)(XC + (size_t)b * A_DIM + i * 4) = xv;
    __syncthreads();              // drain all reads before the resets below
    if (i == 0) {
        cxc[b] = 0.f;
        cq[b] = 0.f;
        num_amg[b] = 0.f;
        if (b < A_DIM) keys[b] = ~0ULL;
    }
}

// ---------------- diff-phase small kernels ----------------

__global__ __launch_bounds__(256) void softmax_kernel(float* __restrict__ G,
                                                      unsigned short* __restrict__ Chi,
                                                      unsigned short* __restrict__ Clo,
                                                      float* __restrict__ num_cg,
                                                      float* __restrict__ scal3) {
    __shared__ float red[16];
    int b = blockIdx.x;
    int i = threadIdx.x;
    if (b == 0 && i == 0) *scal3 = 0.f;  // reset before the dot dispatch
    float4* g4 = (float4*)(G + (size_t)b * A_DIM);
    ushort4* h4 = (ushort4*)(Chi + (size_t)b * A_DIM);
    ushort4* l4 = (ushort4*)(Clo + (size_t)b * A_DIM);
    float4 g = g4[i];
    ushort4 h = h4[i], l = l4[i];
    float c0 = bf2f(h.x) + bf2f(l.x);
    float c1 = bf2f(h.y) + bf2f(l.y);
    float c2 = bf2f(h.z) + bf2f(l.z);
    float c3 = bf2f(h.w) + bf2f(l.w);
    float4 t = make_float4(-TEMP_C * g.x, -TEMP_C * g.y, -TEMP_C * g.z, -TEMP_C * g.w);
    float m = fmaxf(fmaxf(t.x, t.y), fmaxf(t.z, t.w));
    float M = block_reduce_max(m, red);
    float4 e = make_float4(expf(t.x - M), expf(t.y - M), expf(t.z - M), expf(t.w - M));
    float S = block_reduce_sum(e.x + e.y + e.z + e.w, red);
    float inv = 1.f / S;
    float4 sm = make_float4(e.x * inv, e.y * inv, e.z * inv, e.w * inv);
    float np = (c0 - sm.x) * g.x + (c1 - sm.y) * g.y + (c2 - sm.z) * g.z + (c3 - sm.w) * g.w;
    g4[i] = sm;
    split2(sm.x - c0, h.x, l.x);
    split2(sm.y - c1, h.y, l.y);
    split2(sm.z - c2, h.z, l.z);
    split2(sm.w - c3, h.w, l.w);
    h4[i] = h; l4[i] = l;
    float nt = block_reduce_sum(np, red);
    if (i == 0) num_cg[b] = nt;
}

__global__ __launch_bounds__(256) void dupdate_kernel(const float* __restrict__ G,
                                                      unsigned short* __restrict__ Chi,
                                                      unsigned short* __restrict__ Clo,
                                                      const float* __restrict__ num_cg,
                                                      const float* __restrict__ scal3) {
    int b = blockIdx.x;
    float den = *scal3 + EPS_C;
    float lam = fminf(fmaxf(num_cg[b] / den, 0.f), 1.f);
    float om = 1.f - lam;
    int i = threadIdx.x;
    const float4* g4 = (const float4*)(G + (size_t)b * A_DIM);
    ushort4* h4 = (ushort4*)(Chi + (size_t)b * A_DIM);
    ushort4* l4 = (ushort4*)(Clo + (size_t)b * A_DIM);
    float4 sm = g4[i];
    ushort4 h = h4[i], l = l4[i];
    float c0 = sm.x - om * (bf2f(h.x) + bf2f(l.x));
    float c1 = sm.y - om * (bf2f(h.y) + bf2f(l.y));
    float c2 = sm.z - om * (bf2f(h.z) + bf2f(l.z));
    float c3 = sm.w - om * (bf2f(h.w) + bf2f(l.w));
    split2(c0, h.x, l.x);
    split2(c1, h.y, l.y);
    split2(c2, h.z, l.z);
    split2(c3, h.w, l.w);
    h4[i] = h; l4[i] = l;
}

// recon: out[b, n] = (c_b . anT[:,n]) * ynorm[b]
__global__ __launch_bounds__(256) void mfma_recon(const unsigned short* __restrict__ Chi,
                                                  const unsigned short* __restrict__ Clo,
                                                  const unsigned short* __restrict__ AnTh,
                                                  const unsigned short* __restrict__ AnTl,
                                                  const float* __restrict__ ynorm,
                                                  float* __restrict__ out) {
    __shared__ unsigned short lds[16384];
    int tid = threadIdx.x;
    int w = tid >> 6, lane = tid & 63;
    int wm = w >> 1, wn = w & 1;
    int m0 = blockIdx.y * 128, n0 = blockIdx.x * 128;

    f32x4 acc[4][4];
#pragma unroll
    for (int i = 0; i < 4; i++)
#pragma unroll
        for (int j = 0; j < 4; j++) acc[i][j] = f32x4{0.f, 0.f, 0.f, 0.f};

    const unsigned short* gsrc;
    if (w == 0) gsrc = Chi + (size_t)m0 * A_DIM;
    else if (w == 1) gsrc = Clo + (size_t)m0 * A_DIM;
    else if (w == 2) gsrc = AnTh + (size_t)n0 * A_DIM;
    else gsrc = AnTl + (size_t)n0 * A_DIM;
    unsigned short* ltile = lds + w * 4096;
    for (int k0 = 0; k0 < A_DIM; k0 += 32) {
        stage_tile8(gsrc, A_DIM, k0, ltile, lane);
        __syncthreads();
        mfma_k32(lds, wm, wn, lane, acc);
        __syncthreads();
    }

    int crow = (lane >> 4) * 4, ccol = lane & 15;
#pragma unroll
    for (int i = 0; i < 4; i++) {
        int gm = m0 + wm * 64 + i * 16 + crow;
#pragma unroll
        for (int j = 0; j < 4; j++) {
            int gn = n0 + wn * 64 + j * 16 + ccol;
#pragma unroll
            for (int r = 0; r < 4; r++)
                out[(size_t)(gm + r) * D_DIM + gn] = acc[i][j][r] * ynorm[gm + r];
        }
    }
}

// ---------------- host launch ----------------

extern "C" void kernel_launch(void* const* d_in, const int* in_sizes, int n_in,
                              void* d_out, int out_size, void* d_ws, size_t ws_size,
                              hipStream_t stream) {
    const float* y = (const float*)d_in[0];      // [B, 768]
    const float* atoms = (const float*)d_in[1];  // [A, 768]
    float* out = (float*)d_out;                  // [B, 768]

    char* ws = (char*)d_ws;
    size_t off = 0;
    auto alloc = [&](size_t bytes) -> void* {
        void* p = ws + off;
        off += (bytes + 255) & ~(size_t)255;
        return p;
    };
    const size_t BA = (size_t)B_DIM * A_DIM;
    unsigned short* Chi = (unsigned short*)alloc(BA * 2);            // 32 MiB
    unsigned short* Clo = (unsigned short*)alloc(BA * 2);            // 32 MiB
    float* Greg = (float*)alloc(BA * 4);                             // 64 MiB (aliased)
    float* qt = (float*)alloc(BA * 4);                               // 64 MiB
    unsigned short* Xhi = (unsigned short*)alloc((size_t)A_DIM * A_DIM * 2);  // 2 MiB
    unsigned short* Xlo = (unsigned short*)alloc((size_t)A_DIM * A_DIM * 2);  // 2 MiB
    float* Xf = (float*)alloc((size_t)A_DIM * A_DIM * 4);            // 4 MiB (own alloc)
    float* ynorm = (float*)alloc(B_DIM * 4);
    float* anrm  = (float*)alloc(A_DIM * 4);
    float* cxc   = (float*)alloc(B_DIM * 4);
    float* cq    = (float*)alloc(B_DIM * 4);
    float* num_amg = (float*)alloc(B_DIM * 4);
    float* num_cg  = (float*)alloc(B_DIM * 4);
    unsigned long long* keys = (unsigned long long*)alloc(A_DIM * 8);
    int* bstar = (int*)alloc(A_DIM * 4);
    float* scal = (float*)alloc(256);
    (void)ws_size; (void)in_sizes; (void)n_in; (void)out_size;

    // Greg aliases:
    //   setup:   an fp32 | Anh | Anl | Ynh | Ynl        (54 MiB, dead after qt_mfma)
    //   nondiff: XC fp32 [B,A] (64 MiB, first written by refresh iter 0)
    //   diff:    G fp32 (clobbers XC)
    //   post:    AnT splits
    float* an = Greg;                                                 // 3 MiB
    unsigned short* Anh = (unsigned short*)(an + (size_t)A_DIM * D_DIM);          // 1.5 MiB
    unsigned short* Anl = Anh + (size_t)A_DIM * D_DIM;                            // 1.5 MiB
    unsigned short* Ynh = Anl + (size_t)A_DIM * D_DIM;                            // 24 MiB
    unsigned short* Ynl = Ynh + (size_t)B_DIM * D_DIM;                            // 24 MiB
    float* XC = Greg;                                                 // nondiff phase
    float* G = Greg;                                                  // diff phase
    unsigned short* AnTh = (unsigned short*)Greg;                     // post-diff recon
    unsigned short* AnTl = (unsigned short*)Greg + (size_t)D_DIM * A_DIM;

    // ---- setup ----
    ynorm_kernel<<<B_DIM, 256, 0, stream>>>(y, ynorm);
    yn_split_kernel<<<B_DIM, 256, 0, stream>>>(y, ynorm, Ynh, Ynl);
    anorm_kernel<<<A_DIM, 256, 0, stream>>>(atoms, an, anrm, Anh, Anl);
    gemm_xt<<<dim3(A_DIM / 128, A_DIM / 128), 256, 0, stream>>>(an, Xf);
    split_kernel<<<A_DIM * A_DIM / 4 / 256, 256, 0, stream>>>(Xf, Xhi, Xlo, A_DIM * A_DIM / 4);
    qt_mfma<<<1024, 256, 0, stream>>>(Ynh, Ynl, Anh, Anl, qt);
    fill_pair_kernel<<<(int)(BA / 4 / 256), 256, 0, stream>>>(Chi, Clo, BA / 4);
    init_kernel<<<B_DIM / 256, 256, 0, stream>>>(keys, num_amg, cxc, cq, scal);

    // ---- 30 nondiff steps: GEMM refresh every 8th, streaming argmin otherwise ----
    for (int it = 0; it < 30; it++) {
        if ((it & 7) == 0)
            gemm256<0><<<256, 512, 0, stream>>>(Chi, Clo, Xhi, Xlo, qt,
                                                keys, cxc, cq, scal, nullptr, nullptr, XC);
        else
            grad_stream<<<256, 256, 0, stream>>>(XC, qt, Chi, Clo, keys, cxc, cq, scal);
        stats_kernel<<<A_DIM, 256, 0, stream>>>(Xf, keys, Chi, Clo, qt, cxc,
                                                bstar, num_amg, scal);
        ndupdate_kernel<<<B_DIM, 256, 0, stream>>>(Chi, Clo, bstar, cxc, cq,
                                                   num_amg, scal, keys, XC, Xf);
    }

    // ---- 10 diff steps (G clobbers XC) ----
    for (int it = 0; it < 10; it++) {
        gemm256<1><<<256, 512, 0, stream>>>(Chi, nullptr, Xhi, Xlo, qt,
                                            nullptr, nullptr, nullptr, nullptr, G, nullptr,
                                            nullptr);
        softmax_kernel<<<B_DIM, 256, 0, stream>>>(G, Chi, Clo, num_cg, &scal[3]);
        gemm256<2><<<256, 512, 0, stream>>>(Chi, Clo, Xhi, Xlo, nullptr,
                                            nullptr, nullptr, nullptr, nullptr, nullptr,
                                            &scal[3], nullptr);
        dupdate_kernel<<<B_DIM, 256, 0, stream>>>(G, Chi, Clo, num_cg, &scal[3]);
    }

    // ---- recon ----
    atrans_split_kernel<<<D_DIM, 256, 0, stream>>>(atoms, anrm, AnTh, AnTl);
    mfma_recon<<<dim3(D_DIM / 128, B_DIM / 128), 256, 0, stream>>>(Chi, Clo, AnTh, AnTl,
                                                                   ynorm, out);
}

// Round 7
// 6144.927 us; speedup vs baseline: 1.3133x; 1.0468x over previous
//
#include <hip/hip_runtime.h>
#include <hip/hip_bf16.h>
#include <math.h>

// Problem constants
#define A_DIM 1024      // NB_ATOMS
#define D_DIM 768       // 3*16*16
#define B_DIM 16384     // BATCH
#define TEMP_C 100.0f
#define EPS_C 1e-8f

// Round 13: diff-phase R-tracking (second work deletion).
//   R = X@c - qt (the grad) tracked across diff iters: R' = R + lam_b * Xd,
//   Xd = X@d. Kills the per-iter MODE-1 GEMM (grad is R); the one remaining
//   GEMM per iter is gemm256<3>: Xd = X@(d-pair) (3-product, MORE accurate
//   than the verified d-hi MODE 2), epilogue fuses denom = sum(d*Xd) and
//   materializes Xd into qt's buffer (qt dead after rinit folds it into R).
//   dupdate recomputes sm from R (bitwise-identical reduction sequence to
//   softmax_kernel), applies the unchanged c' = sm - (1-lam)*d, advances R.
//   Nondiff phase (XC recurrence, refresh-8) unchanged from round 12
//   (verified absmax 4.88e-4). ynorm/yn_split merged (one y pass).
//   Workspace unchanged (~200 MiB; R reuses Greg, Xd reuses qt).

typedef __attribute__((ext_vector_type(8))) short short8;
typedef __attribute__((ext_vector_type(4))) float f32x4;
#define MFMA16(a, b, c) __builtin_amdgcn_mfma_f32_16x16x32_bf16(a, b, c, 0, 0, 0)

typedef __attribute__((address_space(3))) unsigned char lds_byte;
typedef __attribute__((address_space(1))) const unsigned char g_byte;
__device__ __forceinline__ void async_copy16(const void* gptr, void* lptr) {
    __builtin_amdgcn_global_load_lds((g_byte*)gptr, (lds_byte*)lptr, 16, 0, 0);
}

#define SCHED0 __builtin_amdgcn_sched_barrier(0)
#define ASM_BAR asm volatile("s_barrier" ::: "memory")

// XCD-slab swizzle for 1024-block GEMM grids (qt_mfma only)
__device__ __forceinline__ void swz(int i, int& m0, int& n0) {
    int xcd = i & 7, j = i >> 3;
    m0 = ((xcd << 4) + (j >> 3)) << 7;
    n0 = (j & 7) << 7;
}

// ---------------- reductions (wave shuffle + tiny LDS combine) ----------------

__device__ __forceinline__ float wave_sum(float v) {
#pragma unroll
    for (int m = 1; m < 64; m <<= 1) v += __shfl_xor(v, m);
    return v;
}
__device__ __forceinline__ float wave_max(float v) {
#pragma unroll
    for (int m = 1; m < 64; m <<= 1) v = fmaxf(v, __shfl_xor(v, m));
    return v;
}

__device__ __forceinline__ float block_reduce_sum(float v, float* red) {
    int t = threadIdx.x;
    v = wave_sum(v);
    if ((t & 63) == 0) red[t >> 6] = v;
    __syncthreads();
    float r = red[0] + red[1] + red[2] + red[3];
    __syncthreads();
    return r;
}

__device__ __forceinline__ float block_reduce_max(float v, float* red) {
    int t = threadIdx.x;
    v = wave_max(v);
    if ((t & 63) == 0) red[t >> 6] = v;
    __syncthreads();
    float r = fmaxf(fmaxf(red[0], red[1]), fmaxf(red[2], red[3]));
    __syncthreads();
    return r;
}

__device__ __forceinline__ void block_reduce_sum3(float& a, float& b, float& c, float* red) {
    int t = threadIdx.x;
    a = wave_sum(a);
    b = wave_sum(b);
    c = wave_sum(c);
    if ((t & 63) == 0) {
        int w = t >> 6;
        red[w] = a; red[4 + w] = b; red[8 + w] = c;
    }
    __syncthreads();
    a = red[0] + red[1] + red[2] + red[3];
    b = red[4] + red[5] + red[6] + red[7];
    c = red[8] + red[9] + red[10] + red[11];
    __syncthreads();
}

// ---------------- small helpers ----------------

__device__ __forceinline__ unsigned int fkey(float v) {
    unsigned int u = __float_as_uint(v);
    return u ^ ((u & 0x80000000u) ? 0xFFFFFFFFu : 0x80000000u);
}

__device__ __forceinline__ unsigned short f2bf(float x) {
    unsigned int u = __float_as_uint(x);
    return (unsigned short)((u + 0x7FFFu + ((u >> 16) & 1u)) >> 16);
}
__device__ __forceinline__ float bf2f(unsigned short h) {
    return __uint_as_float(((unsigned int)h) << 16);
}
__device__ __forceinline__ void split2(float x, unsigned short& hi, unsigned short& lo) {
    hi = f2bf(x);
    lo = f2bf(x - bf2f(hi));
}

// ---------------- 128^2 MFMA building blocks (qt_mfma / mfma_recon) ----------------

__device__ __forceinline__ void stage_tile8(const unsigned short* gsrc, int stride, int k0,
                                            unsigned short* ltile, int lane) {
    int srow = lane >> 2;
    int scol = (lane & 3) * 8;
#pragma unroll
    for (int s = 0; s < 8; s++) {
        const unsigned short* src = gsrc + (size_t)(s * 16 + srow) * stride + k0 + scol;
        async_copy16(src, ltile + s * 512);
    }
}

// 3-product (pair x pair) K=32 step
__device__ __forceinline__ void mfma_k32(const unsigned short* lds, int wm, int wn, int lane,
                                         f32x4 acc[4][4]) {
    int frow = lane & 15, fk = (lane >> 4) * 8;
    short8 ah[4], al[4], bh[4], bl[4];
#pragma unroll
    for (int t = 0; t < 4; t++) {
        int ar = (wm * 64 + t * 16 + frow) * 32 + fk;
        ah[t] = *(const short8*)&lds[ar];
        al[t] = *(const short8*)&lds[4096 + ar];
        int br = (wn * 64 + t * 16 + frow) * 32 + fk;
        bh[t] = *(const short8*)&lds[8192 + br];
        bl[t] = *(const short8*)&lds[12288 + br];
    }
#pragma unroll
    for (int i = 0; i < 4; i++)
#pragma unroll
        for (int j = 0; j < 4; j++) {
            acc[i][j] = MFMA16(ah[i], bh[j], acc[i][j]);
            acc[i][j] = MFMA16(ah[i], bl[j], acc[i][j]);
            acc[i][j] = MFMA16(al[i], bh[j], acc[i][j]);
        }
}

// ---------------- 256^2 phase-split pipelined GEMM core (pair-A, 3-product) ----------------
// MODE 0: A = (Chi,Clo), nondiff epilogue (argmin/cxc/cq) + XC refresh write
// MODE 3: A = (d-hi,d-lo), epilogue Xd write + scal3 += sum(d * Xd)

template <int PART>
__device__ __forceinline__ void stage_part(unsigned short* buf,
                                           const unsigned short* Ahi,
                                           const unsigned short* Alo,
                                           const unsigned short* Xhi,
                                           const unsigned short* Xlo,
                                           int m0, int n0, int k0, int t) {
    constexpr int AHI = 0;
    constexpr int ALO = 8192;
    constexpr int BHI = 16384;
    constexpr int BLO = 24576;
    int r = t >> 2;
    int cg = (t & 3) ^ ((t >> 3) & 3);    // pre-swizzled source chunk
    size_t col = (size_t)k0 + cg * 8;
    if constexpr (PART == 0) {
        async_copy16(Ahi + (size_t)(m0 + r) * A_DIM + col,       buf + AHI + t * 8);
        async_copy16(Ahi + (size_t)(m0 + 128 + r) * A_DIM + col, buf + AHI + 4096 + t * 8);
    } else if constexpr (PART == 1) {
        async_copy16(Alo + (size_t)(m0 + r) * A_DIM + col,       buf + ALO + t * 8);
        async_copy16(Alo + (size_t)(m0 + 128 + r) * A_DIM + col, buf + ALO + 4096 + t * 8);
    } else if constexpr (PART == 2) {
        async_copy16(Xhi + (size_t)(n0 + r) * A_DIM + col,       buf + BHI + t * 8);
        async_copy16(Xhi + (size_t)(n0 + 128 + r) * A_DIM + col, buf + BHI + 4096 + t * 8);
    } else {
        async_copy16(Xlo + (size_t)(n0 + r) * A_DIM + col,       buf + BLO + t * 8);
        async_copy16(Xlo + (size_t)(n0 + 128 + r) * A_DIM + col, buf + BLO + 4096 + t * 8);
    }
}

__device__ __forceinline__ void mfma_mi3(short8 ah, short8 al,
                                         const short8 bh[4], const short8 bl[4],
                                         f32x4* accRow) {
#pragma unroll
    for (int j = 0; j < 4; j++) {
        accRow[j] = MFMA16(ah, bh[j], accRow[j]);
        accRow[j] = MFMA16(ah, bl[j], accRow[j]);
        accRow[j] = MFMA16(al, bh[j], accRow[j]);
    }
}

template <int MODE>
__global__ __launch_bounds__(512, 2) void gemm256(const unsigned short* __restrict__ Ahi,
                                                  const unsigned short* __restrict__ Alo,
                                                  const unsigned short* __restrict__ Xhi,
                                                  const unsigned short* __restrict__ Xlo,
                                                  const float* __restrict__ qt,
                                                  unsigned long long* __restrict__ keys,
                                                  float* __restrict__ cxc,
                                                  float* __restrict__ cq,
                                                  float* __restrict__ scal,
                                                  float* __restrict__ G,
                                                  float* __restrict__ scal3,
                                                  float* __restrict__ XC) {
    constexpr int BUFS = 32768;   // shorts per buffer (128 KiB total LDS)
    constexpr int AHI = 0;
    constexpr int ALO = 8192;
    constexpr int BHI = 16384;
    constexpr int BLO = 24576;
    __shared__ unsigned short lds[2 * BUFS];
    __shared__ float red[8];
    int tid = threadIdx.x;
    if (MODE == 0 && blockIdx.x == 0 && tid < 4) scal[tid] = 0.f;
    int w = tid >> 6, lane = tid & 63;
    int wm = w >> 2, wn = w & 3;          // 2 x 4 wave grid
    int bi = blockIdx.x;
    int xcd = bi & 7, bj = bi >> 3;
    int m0 = ((xcd << 3) + (bj >> 2)) << 8;
    int n0 = (bj & 3) << 8;

    f32x4 acc[8][4];
#pragma unroll
    for (int i = 0; i < 8; i++)
#pragma unroll
        for (int j = 0; j < 4; j++) acc[i][j] = f32x4{0.f, 0.f, 0.f, 0.f};

    int frow = lane & 15;
    int sw = ((lane >> 4) ^ ((frow >> 1) & 3)) * 8;   // read-side chunk swizzle

    stage_part<0>(lds, Ahi, Alo, Xhi, Xlo, m0, n0, 0, tid);
    stage_part<1>(lds, Ahi, Alo, Xhi, Xlo, m0, n0, 0, tid);
    stage_part<2>(lds, Ahi, Alo, Xhi, Xlo, m0, n0, 0, tid);
    stage_part<3>(lds, Ahi, Alo, Xhi, Xlo, m0, n0, 0, tid);

    int cur = 0;
    for (int ks = 0; ks < 32; ++ks) {
        unsigned short* rb = lds + cur * BUFS;
        unsigned short* wb = lds + (cur ^ 1) * BUFS;
        const bool pf = (ks < 31);
        const int k1 = (ks + 1) * 32;

        if (pf) {
            stage_part<0>(wb, Ahi, Alo, Xhi, Xlo, m0, n0, k1, tid);
            SCHED0;
            asm volatile("s_waitcnt vmcnt(2)" ::: "memory");
        } else {
            asm volatile("s_waitcnt vmcnt(0)" ::: "memory");
        }
        SCHED0; ASM_BAR; SCHED0;

        short8 bh[4], bl[4];
#pragma unroll
        for (int j = 0; j < 4; j++) {
            int br = wn * 64 + j * 16 + frow;
            bh[j] = *(const short8*)&rb[BHI + br * 32 + sw];
            bl[j] = *(const short8*)&rb[BLO + br * 32 + sw];
        }
        {
            int ar0 = wm * 128 + 0 * 16 + frow, ar1 = wm * 128 + 1 * 16 + frow;
            short8 a0h = *(const short8*)&rb[AHI + ar0 * 32 + sw];
            short8 a1h = *(const short8*)&rb[AHI + ar1 * 32 + sw];
            short8 a0l = *(const short8*)&rb[ALO + ar0 * 32 + sw];
            short8 a1l = *(const short8*)&rb[ALO + ar1 * 32 + sw];
            if (pf) stage_part<1>(wb, Ahi, Alo, Xhi, Xlo, m0, n0, k1, tid);
            SCHED0; ASM_BAR; SCHED0;
            asm volatile("s_waitcnt lgkmcnt(0)" ::: "memory"); SCHED0;
            __builtin_amdgcn_s_setprio(1);
            mfma_mi3(a0h, a0l, bh, bl, acc[0]);
            mfma_mi3(a1h, a1l, bh, bl, acc[1]);
            __builtin_amdgcn_s_setprio(0);
            SCHED0; ASM_BAR; SCHED0;
        }
#pragma unroll
        for (int ph = 1; ph < 4; ph++) {
            int mia = 2 * ph, mib = 2 * ph + 1;
            int ara = wm * 128 + mia * 16 + frow, arb = wm * 128 + mib * 16 + frow;
            short8 aah = *(const short8*)&rb[AHI + ara * 32 + sw];
            short8 abh = *(const short8*)&rb[AHI + arb * 32 + sw];
            short8 aal = *(const short8*)&rb[ALO + ara * 32 + sw];
            short8 abl = *(const short8*)&rb[ALO + arb * 32 + sw];
            if (pf) {
                if (ph == 1) stage_part<2>(wb, Ahi, Alo, Xhi, Xlo, m0, n0, k1, tid);
                if (ph == 2) stage_part<3>(wb, Ahi, Alo, Xhi, Xlo, m0, n0, k1, tid);
            }
            SCHED0; ASM_BAR; SCHED0;
            asm volatile("s_waitcnt lgkmcnt(0)" ::: "memory"); SCHED0;
            __builtin_amdgcn_s_setprio(1);
            mfma_mi3(aah, aal, bh, bl, acc[mia]);
            mfma_mi3(abh, abl, bh, bl, acc[mib]);
            __builtin_amdgcn_s_setprio(0);
            SCHED0; ASM_BAR; SCHED0;
        }
        cur ^= 1;
    }

    int crow = (lane >> 4) * 4, ccol = lane & 15;
    if constexpr (MODE == 0) {
        unsigned long long best[4] = {~0ULL, ~0ULL, ~0ULL, ~0ULL};
#pragma unroll
        for (int mi = 0; mi < 8; mi++)
#pragma unroll
            for (int r = 0; r < 4; r++) {
                int gm = m0 + wm * 128 + mi * 16 + crow + r;
                float pcx = 0.f, pcq = 0.f;
#pragma unroll
                for (int jj = 0; jj < 4; jj++) {
                    int gn = n0 + wn * 64 + jj * 16 + ccol;
                    size_t idx = (size_t)gm * A_DIM + gn;
                    float c = bf2f(Ahi[idx]) + bf2f(Alo[idx]);
                    float q = qt[idx];
                    float xc = acc[mi][jj][r];
                    XC[idx] = xc;               // refresh the tracked X@c
                    pcx += c * xc;
                    pcq += c * q;
                    unsigned long long key =
                        ((unsigned long long)fkey(xc - q) << 32) | (unsigned int)gm;
                    if (key < best[jj]) best[jj] = key;
                }
                for (int mm = 1; mm < 16; mm <<= 1) {
                    pcx += __shfl_xor(pcx, mm, 16);
                    pcq += __shfl_xor(pcq, mm, 16);
                }
                if (ccol == 0) {
                    atomicAdd(&cxc[gm], pcx);
                    atomicAdd(&cq[gm], pcq);
                }
            }
#pragma unroll
        for (int jj = 0; jj < 4; jj++) {
            int gn = n0 + wn * 64 + jj * 16 + ccol;
            unsigned long long o = __shfl_xor(best[jj], 16);
            if (o < best[jj]) best[jj] = o;
            o = __shfl_xor(best[jj], 32);
            if (o < best[jj]) best[jj] = o;
            if ((lane >> 4) == 0) atomicMin(&keys[gn], best[jj]);
        }
    } else {
        // MODE 3: Xd = acc -> G; denom partial = sum(d * Xd) -> scal3
        float part = 0.f;
#pragma unroll
        for (int mi = 0; mi < 8; mi++)
#pragma unroll
            for (int r = 0; r < 4; r++) {
                int gm = m0 + wm * 128 + mi * 16 + crow + r;
#pragma unroll
                for (int jj = 0; jj < 4; jj++) {
                    int gn = n0 + wn * 64 + jj * 16 + ccol;
                    size_t idx = (size_t)gm * A_DIM + gn;
                    float d = bf2f(Ahi[idx]) + bf2f(Alo[idx]);
                    float xd = acc[mi][jj][r];
                    G[idx] = xd;
                    part += xd * d;
                }
            }
        part = wave_sum(part);
        if (lane == 0) red[w] = part;
        __syncthreads();
        if (tid == 0) {
            float tot = red[0] + red[1] + red[2] + red[3] +
                        red[4] + red[5] + red[6] + red[7];
            atomicAdd(scal3, tot);
        }
    }
}

// ---------------- streaming argmin/cxc/cq over XC - qt (non-refresh iters) ----------------
__global__ __launch_bounds__(256) void grad_stream(const float* __restrict__ XC,
                                                   const float* __restrict__ qt,
                                                   const unsigned short* __restrict__ Chi,
                                                   const unsigned short* __restrict__ Clo,
                                                   unsigned long long* __restrict__ keys,
                                                   float* __restrict__ cxc,
                                                   float* __restrict__ cq,
                                                   float* __restrict__ scal) {
    __shared__ unsigned long long lkeys[4][1024];   // 32 KiB
    int tid = threadIdx.x;
    if (blockIdx.x == 0 && tid < 4) scal[tid] = 0.f;
    int w = tid >> 6, lane = tid & 63;
    int b0 = blockIdx.x * 64;

    unsigned long long best[16];
#pragma unroll
    for (int i = 0; i < 16; i++) best[i] = ~0ULL;

    for (int rr = 0; rr < 16; ++rr) {
        int b = b0 + w + rr * 4;
        const float* xcr = XC + (size_t)b * A_DIM;
        const float* qr  = qt + (size_t)b * A_DIM;
        const unsigned short* hr = Chi + (size_t)b * A_DIM;
        const unsigned short* lr = Clo + (size_t)b * A_DIM;
        float dx = 0.f, dq = 0.f;
#pragma unroll
        for (int ch = 0; ch < 4; ++ch) {
            int col = ch * 256 + lane * 4;
            float4 xv = *(const float4*)(xcr + col);
            float4 qv = *(const float4*)(qr + col);
            ushort4 hv = *(const ushort4*)(hr + col);
            ushort4 lv = *(const ushort4*)(lr + col);
            float c0 = bf2f(hv.x) + bf2f(lv.x);
            float c1 = bf2f(hv.y) + bf2f(lv.y);
            float c2 = bf2f(hv.z) + bf2f(lv.z);
            float c3 = bf2f(hv.w) + bf2f(lv.w);
            dx += c0 * xv.x + c1 * xv.y + c2 * xv.z + c3 * xv.w;
            dq += c0 * qv.x + c1 * qv.y + c2 * qv.z + c3 * qv.w;
            float g[4] = {xv.x - qv.x, xv.y - qv.y, xv.z - qv.z, xv.w - qv.w};
#pragma unroll
            for (int j = 0; j < 4; ++j) {
                unsigned long long key =
                    ((unsigned long long)fkey(g[j]) << 32) | (unsigned int)b;
                if (key < best[ch * 4 + j]) best[ch * 4 + j] = key;
            }
        }
        dx = wave_sum(dx);
        dq = wave_sum(dq);
        if (lane == 0) { cxc[b] = dx; cq[b] = dq; }   // exclusive row owner
    }
#pragma unroll
    for (int ch = 0; ch < 4; ++ch)
#pragma unroll
        for (int j = 0; j < 4; ++j)
            lkeys[w][ch * 256 + lane * 4 + j] = best[ch * 4 + j];
    __syncthreads();
    for (int i = tid; i < 1024; i += 256) {
        unsigned long long v = lkeys[0][i];
        if (lkeys[1][i] < v) v = lkeys[1][i];
        if (lkeys[2][i] < v) v = lkeys[2][i];
        if (lkeys[3][i] < v) v = lkeys[3][i];
        atomicMin(&keys[i], v);
    }
}

// ---------------- setup kernels ----------------

// merged: ynorm + split(y/ynorm) in one y pass
__global__ __launch_bounds__(256) void ynorm_split_kernel(const float* __restrict__ y,
                                                          float* __restrict__ ynorm,
                                                          unsigned short* __restrict__ Ynh,
                                                          unsigned short* __restrict__ Ynl) {
    __shared__ float red[16];
    int b = blockIdx.x;
    const float* row = y + (size_t)b * D_DIM;
    float s = 0.f;
    for (int i = threadIdx.x; i < D_DIM; i += 256) s += fabsf(row[i]);
    float tot = block_reduce_sum(s, red);
    float inv = 1.f / tot;
    unsigned short* oh = Ynh + (size_t)b * D_DIM;
    unsigned short* ol = Ynl + (size_t)b * D_DIM;
    for (int i = threadIdx.x; i < D_DIM; i += 256) {
        unsigned short h, l;
        split2(row[i] * inv, h, l);
        oh[i] = h; ol[i] = l;
    }
    if (threadIdx.x == 0) ynorm[b] = tot;
}

__global__ __launch_bounds__(256) void anorm_kernel(const float* __restrict__ atoms,
                                                    float* __restrict__ an,
                                                    float* __restrict__ anrm,
                                                    unsigned short* __restrict__ Anh,
                                                    unsigned short* __restrict__ Anl) {
    __shared__ float red[16];
    int a = blockIdx.x;
    const float* row = atoms + (size_t)a * D_DIM;
    float s = 0.f;
    for (int i = threadIdx.x; i < D_DIM; i += 256) s += fabsf(row[i]);
    float tot = block_reduce_sum(s, red);
    float inv = 1.f / tot;
    for (int i = threadIdx.x; i < D_DIM; i += 256) {
        float v = row[i] * inv;
        an[(size_t)a * D_DIM + i] = v;
        unsigned short h, l;
        split2(v, h, l);
        Anh[(size_t)a * D_DIM + i] = h;
        Anl[(size_t)a * D_DIM + i] = l;
    }
    if (threadIdx.x == 0) anrm[a] = tot;
}

__global__ __launch_bounds__(256) void atrans_split_kernel(const float* __restrict__ atoms,
                                                           const float* __restrict__ anrm,
                                                           unsigned short* __restrict__ AnTh,
                                                           unsigned short* __restrict__ AnTl) {
    int n = blockIdx.x;
    for (int k = threadIdx.x; k < A_DIM; k += 256) {
        float v = atoms[(size_t)k * D_DIM + n] / anrm[k];
        unsigned short h, l;
        split2(v, h, l);
        AnTh[(size_t)n * A_DIM + k] = h;
        AnTl[(size_t)n * A_DIM + k] = l;
    }
}

__global__ __launch_bounds__(256) void split_kernel(const float* __restrict__ src,
                                                    unsigned short* __restrict__ hi,
                                                    unsigned short* __restrict__ lo,
                                                    int n4) {
    int i = blockIdx.x * 256 + threadIdx.x;
    if (i < n4) {
        float4 v = ((const float4*)src)[i];
        ushort4 h, l;
        split2(v.x, h.x, l.x);
        split2(v.y, h.y, l.y);
        split2(v.z, h.z, l.z);
        split2(v.w, h.w, l.w);
        ((ushort4*)hi)[i] = h;
        ((ushort4*)lo)[i] = l;
    }
}

__global__ __launch_bounds__(256) void fill_pair_kernel(unsigned short* __restrict__ Chi,
                                                        unsigned short* __restrict__ Clo,
                                                        size_t n4) {
    size_t i = (size_t)blockIdx.x * 256 + threadIdx.x;
    if (i < n4) {
        unsigned short h, l;
        split2(1.f / A_DIM, h, l);
        ((ushort4*)Chi)[i] = make_ushort4(h, h, h, h);
        ((ushort4*)Clo)[i] = make_ushort4(l, l, l, l);
    }
}

// fp32 vector GEMM, B transposed, setup only: X = an @ an^T
__global__ __launch_bounds__(256) void gemm_xt(const float* __restrict__ Aop,
                                               float* __restrict__ Cout) {
    const int LDT = 132;
    const int N = A_DIM, K = D_DIM;
    __shared__ float As[16 * LDT];
    __shared__ float Bs[16 * LDT];
    int m0 = blockIdx.y * 128, n0 = blockIdx.x * 128;
    int tid = threadIdx.x;
    int tx = tid & 15, ty = tid >> 4;
    float acc[8][8];
#pragma unroll
    for (int i = 0; i < 8; i++)
#pragma unroll
        for (int j = 0; j < 8; j++) acc[i][j] = 0.f;
    for (int k0 = 0; k0 < K; k0 += 16) {
#pragma unroll
        for (int s = 0; s < 2; s++) {
            int idx = tid + s * 256;
            int row = idx >> 2, kq = (idx & 3) * 4;
            float4 v = *(const float4*)(Aop + (size_t)(m0 + row) * K + k0 + kq);
            As[(kq + 0) * LDT + row] = v.x;
            As[(kq + 1) * LDT + row] = v.y;
            As[(kq + 2) * LDT + row] = v.z;
            As[(kq + 3) * LDT + row] = v.w;
        }
#pragma unroll
        for (int s = 0; s < 2; s++) {
            int idx = tid + s * 256;
            int row = idx >> 2, kq = (idx & 3) * 4;
            float4 v = *(const float4*)(Aop + (size_t)(n0 + row) * K + k0 + kq);
            Bs[(kq + 0) * LDT + row] = v.x;
            Bs[(kq + 1) * LDT + row] = v.y;
            Bs[(kq + 2) * LDT + row] = v.z;
            Bs[(kq + 3) * LDT + row] = v.w;
        }
        __syncthreads();
#pragma unroll
        for (int kk = 0; kk < 16; kk++) {
            float a[8], b[8];
            *(float4*)(a)     = *(const float4*)(As + kk * LDT + ty * 8);
            *(float4*)(a + 4) = *(const float4*)(As + kk * LDT + ty * 8 + 4);
            *(float4*)(b)     = *(const float4*)(Bs + kk * LDT + tx * 8);
            *(float4*)(b + 4) = *(const float4*)(Bs + kk * LDT + tx * 8 + 4);
#pragma unroll
            for (int i = 0; i < 8; i++)
#pragma unroll
                for (int j = 0; j < 8; j++) acc[i][j] = fmaf(a[i], b[j], acc[i][j]);
        }
        __syncthreads();
    }
#pragma unroll
    for (int i = 0; i < 8; i++) {
        int row = m0 + ty * 8 + i;
#pragma unroll
        for (int j = 0; j < 8; j += 4) {
            int col = n0 + tx * 8 + j;
            float4 v = make_float4(acc[i][j], acc[i][j + 1], acc[i][j + 2], acc[i][j + 3]);
            *(float4*)(Cout + (size_t)row * N + col) = v;
        }
    }
}

// qt = Yn @ An^T  (bf16x2 pair-pair MFMA, K=768), swizzled 1D grid of 1024
__global__ __launch_bounds__(256) void qt_mfma(const unsigned short* __restrict__ Ynh,
                                               const unsigned short* __restrict__ Ynl,
                                               const unsigned short* __restrict__ Anh,
                                               const unsigned short* __restrict__ Anl,
                                               float* __restrict__ qt) {
    __shared__ unsigned short lds[16384];
    int tid = threadIdx.x;
    int w = tid >> 6, lane = tid & 63;
    int wm = w >> 1, wn = w & 1;
    int m0, n0;
    swz(blockIdx.x, m0, n0);

    f32x4 acc[4][4];
#pragma unroll
    for (int i = 0; i < 4; i++)
#pragma unroll
        for (int j = 0; j < 4; j++) acc[i][j] = f32x4{0.f, 0.f, 0.f, 0.f};

    const unsigned short* gsrc;
    if (w == 0) gsrc = Ynh + (size_t)m0 * D_DIM;
    else if (w == 1) gsrc = Ynl + (size_t)m0 * D_DIM;
    else if (w == 2) gsrc = Anh + (size_t)n0 * D_DIM;
    else gsrc = Anl + (size_t)n0 * D_DIM;
    unsigned short* ltile = lds + w * 4096;
    for (int k0 = 0; k0 < D_DIM; k0 += 32) {
        stage_tile8(gsrc, D_DIM, k0, ltile, lane);
        __syncthreads();
        mfma_k32(lds, wm, wn, lane, acc);
        __syncthreads();
    }

    int crow = (lane >> 4) * 4, ccol = lane & 15;
#pragma unroll
    for (int i = 0; i < 4; i++) {
        int gm = m0 + wm * 64 + i * 16 + crow;
#pragma unroll
        for (int j = 0; j < 4; j++) {
            int gn = n0 + wn * 64 + j * 16 + ccol;
#pragma unroll
            for (int r = 0; r < 4; r++)
                qt[(size_t)(gm + r) * A_DIM + gn] = acc[i][j][r];
        }
    }
}

// ---------------- nondiff per-iteration kernels ----------------

__global__ __launch_bounds__(256) void init_kernel(unsigned long long* __restrict__ keys,
                                                   float* __restrict__ num_amg,
                                                   float* __restrict__ cxc,
                                                   float* __restrict__ cq,
                                                   float* __restrict__ scal) {
    int i = blockIdx.x * 256 + threadIdx.x;
    num_amg[i] = 0.f;
    cxc[i] = 0.f;
    cq[i] = 0.f;
    if (i < A_DIM) keys[i] = ~0ULL;
    if (i < 4) scal[i] = 0.f;
}

__global__ __launch_bounds__(256) void stats_kernel(const float* __restrict__ Xf,
                                                    const unsigned long long* __restrict__ keys,
                                                    const unsigned short* __restrict__ Chi,
                                                    const unsigned short* __restrict__ Clo,
                                                    const float* __restrict__ qt,
                                                    const float* __restrict__ cxc,
                                                    int* __restrict__ bstar,
                                                    float* __restrict__ num_amg,
                                                    float* __restrict__ scal) {
    __shared__ float red[16];
    int a = blockIdx.x;
    int ba = (int)(unsigned int)(keys[a] & 0xFFFFFFFFULL);
    const float* xr = Xf + (size_t)a * A_DIM;
    const unsigned short* ch = Chi + (size_t)ba * A_DIM;
    const unsigned short* cl = Clo + (size_t)ba * A_DIM;
    float ps = 0.f, xs = 0.f;
    for (int i = threadIdx.x; i < A_DIM; i += 256) {
        float xv = xr[i];
        if ((int)(unsigned int)(keys[i] & 0xFFFFFFFFULL) == ba) ps += xv;
        xs += xv * (bf2f(ch[i]) + bf2f(cl[i]));
    }
    float s1p = (threadIdx.x < 16) ? cxc[(a << 4) + threadIdx.x] : 0.f;
    block_reduce_sum3(ps, xs, s1p, red);
    if (threadIdx.x == 0) {
        bstar[a] = ba;
        atomicAdd(&scal[0], ps);
        atomicAdd(&scal[2], xs);
        atomicAdd(&scal[1], s1p);
        atomicAdd(&num_amg[ba], xs - qt[(size_t)ba * A_DIM + a]);
    }
}

// nondiff update: c' = (1-lam)c + lam*am (splits refreshed) AND the XC
// recurrence XC[b,:] = (1-lam_b) XC[b,:] + lam_b * sum_{a: bstar[a]=b} Xf[a,:].
__global__ __launch_bounds__(256) void ndupdate_kernel(unsigned short* __restrict__ Chi,
                                                       unsigned short* __restrict__ Clo,
                                                       const int* __restrict__ bstar,
                                                       float* __restrict__ cxc,
                                                       float* __restrict__ cq,
                                                       float* __restrict__ num_amg,
                                                       const float* __restrict__ scal,
                                                       unsigned long long* __restrict__ keys,
                                                       float* __restrict__ XC,
                                                       const float* __restrict__ Xf) {
    __shared__ int mlist[1024];
    __shared__ int mcount;
    int b = blockIdx.x;
    int i = threadIdx.x;
    if (i == 0) mcount = 0;
    float den = scal[0] + scal[1] - 2.f * scal[2] + EPS_C;
    float lam = fminf(fmaxf((cxc[b] - cq[b] - num_amg[b]) / den, 0.f), 1.f);
    float om = 1.f - lam;
    ushort4* h4 = (ushort4*)(Chi + (size_t)b * A_DIM);
    ushort4* l4 = (ushort4*)(Clo + (size_t)b * A_DIM);
    ushort4 h = h4[i], l = l4[i];
    int4 bs = ((const int4*)bstar)[i];
    float c0 = om * (bf2f(h.x) + bf2f(l.x)) + ((bs.x == b) ? lam : 0.f);
    float c1 = om * (bf2f(h.y) + bf2f(l.y)) + ((bs.y == b) ? lam : 0.f);
    float c2 = om * (bf2f(h.z) + bf2f(l.z)) + ((bs.z == b) ? lam : 0.f);
    float c3 = om * (bf2f(h.w) + bf2f(l.w)) + ((bs.w == b) ? lam : 0.f);
    split2(c0, h.x, l.x);
    split2(c1, h.y, l.y);
    split2(c2, h.z, l.z);
    split2(c3, h.w, l.w);
    h4[i] = h; l4[i] = l;
    __syncthreads();              // mcount visible; c reads drained
    for (int a = i; a < A_DIM; a += 256)
        if (bstar[a] == b) { int p = atomicAdd(&mcount, 1); mlist[p] = a; }
    __syncthreads();
    float4 xv = *(float4*)(XC + (size_t)b * A_DIM + i * 4);
    xv.x *= om; xv.y *= om; xv.z *= om; xv.w *= om;
    int mc = mcount;
    for (int m = 0; m < mc; m++) {
        float4 av = *(const float4*)(Xf + (size_t)mlist[m] * A_DIM + i * 4);
        xv.x += lam * av.x; xv.y += lam * av.y;
        xv.z += lam * av.z; xv.w += lam * av.w;
    }
    *(float4*)(XC + (size_t)b * A_DIM + i * 4) = xv;
    __syncthreads();              // drain all reads before the resets below
    if (i == 0) {
        cxc[b] = 0.f;
        cq[b] = 0.f;
        num_amg[b] = 0.f;
        if (b < A_DIM) keys[b] = ~0ULL;
    }
}

// ---------------- diff-phase kernels ----------------

// R = XC - qt (in place in Greg), once at diff entry; qt becomes the Xd buffer.
__global__ __launch_bounds__(256) void rinit_kernel(float* __restrict__ XC,
                                                    const float* __restrict__ qt) {
    size_t i = (size_t)blockIdx.x * 256 + threadIdx.x;
    float4 x = ((const float4*)XC)[i];
    float4 q = ((const float4*)qt)[i];
    x.x -= q.x; x.y -= q.y; x.z -= q.z; x.w -= q.w;
    ((float4*)XC)[i] = x;
}

// softmax over grad = R; writes d = sm - c into Chi/Clo; num_cg[b] = -sum d*grad
__global__ __launch_bounds__(256) void softmax_kernel(const float* __restrict__ R,
                                                      unsigned short* __restrict__ Chi,
                                                      unsigned short* __restrict__ Clo,
                                                      float* __restrict__ num_cg,
                                                      float* __restrict__ scal3) {
    __shared__ float red[16];
    int b = blockIdx.x;
    int i = threadIdx.x;
    if (b == 0 && i == 0) *scal3 = 0.f;  // reset before the dot dispatch
    const float4* g4 = (const float4*)(R + (size_t)b * A_DIM);
    ushort4* h4 = (ushort4*)(Chi + (size_t)b * A_DIM);
    ushort4* l4 = (ushort4*)(Clo + (size_t)b * A_DIM);
    float4 g = g4[i];
    ushort4 h = h4[i], l = l4[i];
    float c0 = bf2f(h.x) + bf2f(l.x);
    float c1 = bf2f(h.y) + bf2f(l.y);
    float c2 = bf2f(h.z) + bf2f(l.z);
    float c3 = bf2f(h.w) + bf2f(l.w);
    float4 t = make_float4(-TEMP_C * g.x, -TEMP_C * g.y, -TEMP_C * g.z, -TEMP_C * g.w);
    float m = fmaxf(fmaxf(t.x, t.y), fmaxf(t.z, t.w));
    float M = block_reduce_max(m, red);
    float4 e = make_float4(expf(t.x - M), expf(t.y - M), expf(t.z - M), expf(t.w - M));
    float S = block_reduce_sum(e.x + e.y + e.z + e.w, red);
    float inv = 1.f / S;
    float4 sm = make_float4(e.x * inv, e.y * inv, e.z * inv, e.w * inv);
    float np = (c0 - sm.x) * g.x + (c1 - sm.y) * g.y + (c2 - sm.z) * g.z + (c3 - sm.w) * g.w;
    split2(sm.x - c0, h.x, l.x);
    split2(sm.y - c1, h.y, l.y);
    split2(sm.z - c2, h.z, l.z);
    split2(sm.w - c3, h.w, l.w);
    h4[i] = h; l4[i] = l;
    float nt = block_reduce_sum(np, red);
    if (i == 0) num_cg[b] = nt;
}

// dupdate: recompute sm from R (bitwise-identical sequence to softmax_kernel),
// c' = sm - (1-lam)*d (unchanged formula), then R += lam * Xd.
__global__ __launch_bounds__(256) void dupdate_kernel(float* __restrict__ R,
                                                      const float* __restrict__ Xd,
                                                      unsigned short* __restrict__ Chi,
                                                      unsigned short* __restrict__ Clo,
                                                      const float* __restrict__ num_cg,
                                                      const float* __restrict__ scal3) {
    __shared__ float red[16];
    int b = blockIdx.x;
    int i = threadIdx.x;
    float4* r4 = (float4*)(R + (size_t)b * A_DIM);
    float4 g = r4[i];
    float4 t = make_float4(-TEMP_C * g.x, -TEMP_C * g.y, -TEMP_C * g.z, -TEMP_C * g.w);
    float m = fmaxf(fmaxf(t.x, t.y), fmaxf(t.z, t.w));
    float M = block_reduce_max(m, red);
    float4 e = make_float4(expf(t.x - M), expf(t.y - M), expf(t.z - M), expf(t.w - M));
    float S = block_reduce_sum(e.x + e.y + e.z + e.w, red);
    float inv = 1.f / S;
    float4 sm = make_float4(e.x * inv, e.y * inv, e.z * inv, e.w * inv);
    float den = *scal3 + EPS_C;
    float lam = fminf(fmaxf(num_cg[b] / den, 0.f), 1.f);
    float om = 1.f - lam;
    ushort4* h4 = (ushort4*)(Chi + (size_t)b * A_DIM);
    ushort4* l4 = (ushort4*)(Clo + (size_t)b * A_DIM);
    ushort4 h = h4[i], l = l4[i];          // d
    float c0 = sm.x - om * (bf2f(h.x) + bf2f(l.x));
    float c1 = sm.y - om * (bf2f(h.y) + bf2f(l.y));
    float c2 = sm.z - om * (bf2f(h.z) + bf2f(l.z));
    float c3 = sm.w - om * (bf2f(h.w) + bf2f(l.w));
    split2(c0, h.x, l.x);
    split2(c1, h.y, l.y);
    split2(c2, h.z, l.z);
    split2(c3, h.w, l.w);
    h4[i] = h; l4[i] = l;
    float4 xd = ((const float4*)(Xd + (size_t)b * A_DIM))[i];
    g.x += lam * xd.x; g.y += lam * xd.y;
    g.z += lam * xd.z; g.w += lam * xd.w;
    r4[i] = g;
}

// recon: out[b, n] = (c_b . anT[:,n]) * ynorm[b]
__global__ __launch_bounds__(256) void mfma_recon(const unsigned short* __restrict__ Chi,
                                                  const unsigned short* __restrict__ Clo,
                                                  const unsigned short* __restrict__ AnTh,
                                                  const unsigned short* __restrict__ AnTl,
                                                  const float* __restrict__ ynorm,
                                                  float* __restrict__ out) {
    __shared__ unsigned short lds[16384];
    int tid = threadIdx.x;
    int w = tid >> 6, lane = tid & 63;
    int wm = w >> 1, wn = w & 1;
    int m0 = blockIdx.y * 128, n0 = blockIdx.x * 128;

    f32x4 acc[4][4];
#pragma unroll
    for (int i = 0; i < 4; i++)
#pragma unroll
        for (int j = 0; j < 4; j++) acc[i][j] = f32x4{0.f, 0.f, 0.f, 0.f};

    const unsigned short* gsrc;
    if (w == 0) gsrc = Chi + (size_t)m0 * A_DIM;
    else if (w == 1) gsrc = Clo + (size_t)m0 * A_DIM;
    else if (w == 2) gsrc = AnTh + (size_t)n0 * A_DIM;
    else gsrc = AnTl + (size_t)n0 * A_DIM;
    unsigned short* ltile = lds + w * 4096;
    for (int k0 = 0; k0 < A_DIM; k0 += 32) {
        stage_tile8(gsrc, A_DIM, k0, ltile, lane);
        __syncthreads();
        mfma_k32(lds, wm, wn, lane, acc);
        __syncthreads();
    }

    int crow = (lane >> 4) * 4, ccol = lane & 15;
#pragma unroll
    for (int i = 0; i < 4; i++) {
        int gm = m0 + wm * 64 + i * 16 + crow;
#pragma unroll
        for (int j = 0; j < 4; j++) {
            int gn = n0 + wn * 64 + j * 16 + ccol;
#pragma unroll
            for (int r = 0; r < 4; r++)
                out[(size_t)(gm + r) * D_DIM + gn] = acc[i][j][r] * ynorm[gm + r];
        }
    }
}

// ---------------- host launch ----------------

extern "C" void kernel_launch(void* const* d_in, const int* in_sizes, int n_in,
                              void* d_out, int out_size, void* d_ws, size_t ws_size,
                              hipStream_t stream) {
    const float* y = (const float*)d_in[0];      // [B, 768]
    const float* atoms = (const float*)d_in[1];  // [A, 768]
    float* out = (float*)d_out;                  // [B, 768]

    char* ws = (char*)d_ws;
    size_t off = 0;
    auto alloc = [&](size_t bytes) -> void* {
        void* p = ws + off;
        off += (bytes + 255) & ~(size_t)255;
        return p;
    };
    const size_t BA = (size_t)B_DIM * A_DIM;
    unsigned short* Chi = (unsigned short*)alloc(BA * 2);            // 32 MiB
    unsigned short* Clo = (unsigned short*)alloc(BA * 2);            // 32 MiB
    float* Greg = (float*)alloc(BA * 4);                             // 64 MiB (aliased)
    float* qt = (float*)alloc(BA * 4);                               // 64 MiB (-> Xd in diff)
    unsigned short* Xhi = (unsigned short*)alloc((size_t)A_DIM * A_DIM * 2);  // 2 MiB
    unsigned short* Xlo = (unsigned short*)alloc((size_t)A_DIM * A_DIM * 2);  // 2 MiB
    float* Xf = (float*)alloc((size_t)A_DIM * A_DIM * 4);            // 4 MiB (own alloc)
    float* ynorm = (float*)alloc(B_DIM * 4);
    float* anrm  = (float*)alloc(A_DIM * 4);
    float* cxc   = (float*)alloc(B_DIM * 4);
    float* cq    = (float*)alloc(B_DIM * 4);
    float* num_amg = (float*)alloc(B_DIM * 4);
    float* num_cg  = (float*)alloc(B_DIM * 4);
    unsigned long long* keys = (unsigned long long*)alloc(A_DIM * 8);
    int* bstar = (int*)alloc(A_DIM * 4);
    float* scal = (float*)alloc(256);
    (void)ws_size; (void)in_sizes; (void)n_in; (void)out_size;

    // Greg aliases:
    //   setup:   an fp32 | Anh | Anl | Ynh | Ynl        (54 MiB, dead after qt_mfma)
    //   nondiff: XC fp32 [B,A] (64 MiB)
    //   diff:    R = XC - qt (in place); Xd lives in qt's buffer
    //   post:    AnT splits
    float* an = Greg;                                                 // 3 MiB
    unsigned short* Anh = (unsigned short*)(an + (size_t)A_DIM * D_DIM);          // 1.5 MiB
    unsigned short* Anl = Anh + (size_t)A_DIM * D_DIM;                            // 1.5 MiB
    unsigned short* Ynh = Anl + (size_t)A_DIM * D_DIM;                            // 24 MiB
    unsigned short* Ynl = Ynh + (size_t)B_DIM * D_DIM;                            // 24 MiB
    float* XC = Greg;                                                 // nondiff phase
    float* R  = Greg;                                                 // diff phase (= XC - qt)
    float* Xd = qt;                                                   // diff phase
    unsigned short* AnTh = (unsigned short*)Greg;                     // post-diff recon
    unsigned short* AnTl = (unsigned short*)Greg + (size_t)D_DIM * A_DIM;

    // ---- setup ----
    ynorm_split_kernel<<<B_DIM, 256, 0, stream>>>(y, ynorm, Ynh, Ynl);
    anorm_kernel<<<A_DIM, 256, 0, stream>>>(atoms, an, anrm, Anh, Anl);
    gemm_xt<<<dim3(A_DIM / 128, A_DIM / 128), 256, 0, stream>>>(an, Xf);
    split_kernel<<<A_DIM * A_DIM / 4 / 256, 256, 0, stream>>>(Xf, Xhi, Xlo, A_DIM * A_DIM / 4);
    qt_mfma<<<1024, 256, 0, stream>>>(Ynh, Ynl, Anh, Anl, qt);
    fill_pair_kernel<<<(int)(BA / 4 / 256), 256, 0, stream>>>(Chi, Clo, BA / 4);
    init_kernel<<<B_DIM / 256, 256, 0, stream>>>(keys, num_amg, cxc, cq, scal);

    // ---- 30 nondiff steps: GEMM refresh every 8th, streaming argmin otherwise ----
    for (int it = 0; it < 30; it++) {
        if ((it & 7) == 0)
            gemm256<0><<<256, 512, 0, stream>>>(Chi, Clo, Xhi, Xlo, qt,
                                                keys, cxc, cq, scal, nullptr, nullptr, XC);
        else
            grad_stream<<<256, 256, 0, stream>>>(XC, qt, Chi, Clo, keys, cxc, cq, scal);
        stats_kernel<<<A_DIM, 256, 0, stream>>>(Xf, keys, Chi, Clo, qt, cxc,
                                                bstar, num_amg, scal);
        ndupdate_kernel<<<B_DIM, 256, 0, stream>>>(Chi, Clo, bstar, cxc, cq,
                                                   num_amg, scal, keys, XC, Xf);
    }

    // ---- 10 diff steps: R-tracking, one GEMM per iter ----
    rinit_kernel<<<(int)(BA / 4 / 256), 256, 0, stream>>>(XC, qt);   // R = XC - qt
    for (int it = 0; it < 10; it++) {
        softmax_kernel<<<B_DIM, 256, 0, stream>>>(R, Chi, Clo, num_cg, &scal[3]);
        gemm256<3><<<256, 512, 0, stream>>>(Chi, Clo, Xhi, Xlo, nullptr,
                                            nullptr, nullptr, nullptr, nullptr,
                                            Xd, &scal[3], nullptr);
        dupdate_kernel<<<B_DIM, 256, 0, stream>>>(R, Xd, Chi, Clo, num_cg, &scal[3]);
    }

    // ---- recon ----
    atrans_split_kernel<<<D_DIM, 256, 0, stream>>>(atoms, anrm, AnTh, AnTl);
    mfma_recon<<<dim3(D_DIM / 128, B_DIM / 128), 256, 0, stream>>>(Chi, Clo, AnTh, AnTl,
                                                                   ynorm, out);
}

// Round 9
// 5600.244 us; speedup vs baseline: 1.4411x; 1.0973x over previous
//
#include <hip/hip_runtime.h>
#include <hip/hip_bf16.h>
#include <math.h>

// Problem constants
#define A_DIM 1024      // NB_ATOMS
#define D_DIM 768       // 3*16*16
#define B_DIM 16384     // BATCH
#define TEMP_C 100.0f
#define EPS_C 1e-8f

// Round 14 (RE-SUBMIT after broker timeout; full choreography re-audited):
//  NONDIFF: fgrad = ndupdate(t-1) + grad_stream(t) in ONE pass over c/XC/qt.
//   - keys double-buffered K0/K1: fgrad(t) reads K[(t-1)&1] (ballot match
//     masks per wave-row), atomicMins argmin into K[t&1]; stats(t) resets
//     K[(t+1)&1]. scal double-banked (stats adds bank t&1; fgrad reads other).
//   - cxc/cq: row-owned read-old -> write-new (no atomics outside refresh).
//   - refresh boundaries (7/15/23): thin ndupdate_c (c only; refresh GEMM
//     rewrites XC exactly). iter 29: ndupdate_full (c + XC for diff's rinit).
//  DIFF: dupdate_fused computes sm_t (lam, c_{t+1}), advances R, then computes
//   sm_{t+1}+d_{t+1}+num_{t+1} in the same pass (softmax runs once at entry).
//   scal3 double-buffered in scal[3]/scal[7].
//  gemm256<0/3>, qt_mfma, recon, setup unchanged from round 13 (absmax 4.88e-4).

typedef __attribute__((ext_vector_type(8))) short short8;
typedef __attribute__((ext_vector_type(4))) float f32x4;
#define MFMA16(a, b, c) __builtin_amdgcn_mfma_f32_16x16x32_bf16(a, b, c, 0, 0, 0)

typedef __attribute__((address_space(3))) unsigned char lds_byte;
typedef __attribute__((address_space(1))) const unsigned char g_byte;
__device__ __forceinline__ void async_copy16(const void* gptr, void* lptr) {
    __builtin_amdgcn_global_load_lds((g_byte*)gptr, (lds_byte*)lptr, 16, 0, 0);
}

#define SCHED0 __builtin_amdgcn_sched_barrier(0)
#define ASM_BAR asm volatile("s_barrier" ::: "memory")

// XCD-slab swizzle for 1024-block GEMM grids (qt_mfma only)
__device__ __forceinline__ void swz(int i, int& m0, int& n0) {
    int xcd = i & 7, j = i >> 3;
    m0 = ((xcd << 4) + (j >> 3)) << 7;
    n0 = (j & 7) << 7;
}

// ---------------- reductions ----------------

__device__ __forceinline__ float wave_sum(float v) {
#pragma unroll
    for (int m = 1; m < 64; m <<= 1) v += __shfl_xor(v, m);
    return v;
}
__device__ __forceinline__ float wave_max(float v) {
#pragma unroll
    for (int m = 1; m < 64; m <<= 1) v = fmaxf(v, __shfl_xor(v, m));
    return v;
}

__device__ __forceinline__ float block_reduce_sum(float v, float* red) {
    int t = threadIdx.x;
    v = wave_sum(v);
    if ((t & 63) == 0) red[t >> 6] = v;
    __syncthreads();
    float r = red[0] + red[1] + red[2] + red[3];
    __syncthreads();
    return r;
}

__device__ __forceinline__ float block_reduce_max(float v, float* red) {
    int t = threadIdx.x;
    v = wave_max(v);
    if ((t & 63) == 0) red[t >> 6] = v;
    __syncthreads();
    float r = fmaxf(fmaxf(red[0], red[1]), fmaxf(red[2], red[3]));
    __syncthreads();
    return r;
}

__device__ __forceinline__ void block_reduce_sum3(float& a, float& b, float& c, float* red) {
    int t = threadIdx.x;
    a = wave_sum(a);
    b = wave_sum(b);
    c = wave_sum(c);
    if ((t & 63) == 0) {
        int w = t >> 6;
        red[w] = a; red[4 + w] = b; red[8 + w] = c;
    }
    __syncthreads();
    a = red[0] + red[1] + red[2] + red[3];
    b = red[4] + red[5] + red[6] + red[7];
    c = red[8] + red[9] + red[10] + red[11];
    __syncthreads();
}

// ---------------- small helpers ----------------

__device__ __forceinline__ unsigned int fkey(float v) {
    unsigned int u = __float_as_uint(v);
    return u ^ ((u & 0x80000000u) ? 0xFFFFFFFFu : 0x80000000u);
}

__device__ __forceinline__ unsigned short f2bf(float x) {
    unsigned int u = __float_as_uint(x);
    return (unsigned short)((u + 0x7FFFu + ((u >> 16) & 1u)) >> 16);
}
__device__ __forceinline__ float bf2f(unsigned short h) {
    return __uint_as_float(((unsigned int)h) << 16);
}
__device__ __forceinline__ void split2(float x, unsigned short& hi, unsigned short& lo) {
    hi = f2bf(x);
    lo = f2bf(x - bf2f(hi));
}
__device__ __forceinline__ float clamp01(float x) {
    return fminf(fmaxf(x, 0.f), 1.f);
}

// ---------------- 128^2 MFMA building blocks (qt_mfma / mfma_recon) ----------------

__device__ __forceinline__ void stage_tile8(const unsigned short* gsrc, int stride, int k0,
                                            unsigned short* ltile, int lane) {
    int srow = lane >> 2;
    int scol = (lane & 3) * 8;
#pragma unroll
    for (int s = 0; s < 8; s++) {
        const unsigned short* src = gsrc + (size_t)(s * 16 + srow) * stride + k0 + scol;
        async_copy16(src, ltile + s * 512);
    }
}

// 3-product (pair x pair) K=32 step
__device__ __forceinline__ void mfma_k32(const unsigned short* lds, int wm, int wn, int lane,
                                         f32x4 acc[4][4]) {
    int frow = lane & 15, fk = (lane >> 4) * 8;
    short8 ah[4], al[4], bh[4], bl[4];
#pragma unroll
    for (int t = 0; t < 4; t++) {
        int ar = (wm * 64 + t * 16 + frow) * 32 + fk;
        ah[t] = *(const short8*)&lds[ar];
        al[t] = *(const short8*)&lds[4096 + ar];
        int br = (wn * 64 + t * 16 + frow) * 32 + fk;
        bh[t] = *(const short8*)&lds[8192 + br];
        bl[t] = *(const short8*)&lds[12288 + br];
    }
#pragma unroll
    for (int i = 0; i < 4; i++)
#pragma unroll
        for (int j = 0; j < 4; j++) {
            acc[i][j] = MFMA16(ah[i], bh[j], acc[i][j]);
            acc[i][j] = MFMA16(ah[i], bl[j], acc[i][j]);
            acc[i][j] = MFMA16(al[i], bh[j], acc[i][j]);
        }
}

// ---------------- 256^2 phase-split pipelined GEMM core (pair-A, 3-product) ----------------
// MODE 0: A = (Chi,Clo), nondiff epilogue (argmin/cxc/cq) + XC refresh write
// MODE 3: A = (d-hi,d-lo), epilogue Xd write + scal3 += sum(d * Xd)

template <int PART>
__device__ __forceinline__ void stage_part(unsigned short* buf,
                                           const unsigned short* Ahi,
                                           const unsigned short* Alo,
                                           const unsigned short* Xhi,
                                           const unsigned short* Xlo,
                                           int m0, int n0, int k0, int t) {
    constexpr int AHI = 0;
    constexpr int ALO = 8192;
    constexpr int BHI = 16384;
    constexpr int BLO = 24576;
    int r = t >> 2;
    int cg = (t & 3) ^ ((t >> 3) & 3);    // pre-swizzled source chunk
    size_t col = (size_t)k0 + cg * 8;
    if constexpr (PART == 0) {
        async_copy16(Ahi + (size_t)(m0 + r) * A_DIM + col,       buf + AHI + t * 8);
        async_copy16(Ahi + (size_t)(m0 + 128 + r) * A_DIM + col, buf + AHI + 4096 + t * 8);
    } else if constexpr (PART == 1) {
        async_copy16(Alo + (size_t)(m0 + r) * A_DIM + col,       buf + ALO + t * 8);
        async_copy16(Alo + (size_t)(m0 + 128 + r) * A_DIM + col, buf + ALO + 4096 + t * 8);
    } else if constexpr (PART == 2) {
        async_copy16(Xhi + (size_t)(n0 + r) * A_DIM + col,       buf + BHI + t * 8);
        async_copy16(Xhi + (size_t)(n0 + 128 + r) * A_DIM + col, buf + BHI + 4096 + t * 8);
    } else {
        async_copy16(Xlo + (size_t)(n0 + r) * A_DIM + col,       buf + BLO + t * 8);
        async_copy16(Xlo + (size_t)(n0 + 128 + r) * A_DIM + col, buf + BLO + 4096 + t * 8);
    }
}

__device__ __forceinline__ void mfma_mi3(short8 ah, short8 al,
                                         const short8 bh[4], const short8 bl[4],
                                         f32x4* accRow) {
#pragma unroll
    for (int j = 0; j < 4; j++) {
        accRow[j] = MFMA16(ah, bh[j], accRow[j]);
        accRow[j] = MFMA16(ah, bl[j], accRow[j]);
        accRow[j] = MFMA16(al, bh[j], accRow[j]);
    }
}

template <int MODE>
__global__ __launch_bounds__(512, 2) void gemm256(const unsigned short* __restrict__ Ahi,
                                                  const unsigned short* __restrict__ Alo,
                                                  const unsigned short* __restrict__ Xhi,
                                                  const unsigned short* __restrict__ Xlo,
                                                  const float* __restrict__ qt,
                                                  unsigned long long* __restrict__ keys,
                                                  float* __restrict__ cxc,
                                                  float* __restrict__ cq,
                                                  float* __restrict__ scal,
                                                  float* __restrict__ G,
                                                  float* __restrict__ scal3,
                                                  float* __restrict__ XC) {
    constexpr int BUFS = 32768;   // shorts per buffer (128 KiB total LDS)
    constexpr int AHI = 0;
    constexpr int ALO = 8192;
    constexpr int BHI = 16384;
    constexpr int BLO = 24576;
    __shared__ unsigned short lds[2 * BUFS];
    __shared__ float red[8];
    int tid = threadIdx.x;
    if (MODE == 0 && blockIdx.x == 0 && tid < 4) scal[tid] = 0.f;
    int w = tid >> 6, lane = tid & 63;
    int wm = w >> 2, wn = w & 3;          // 2 x 4 wave grid
    int bi = blockIdx.x;
    int xcd = bi & 7, bj = bi >> 3;
    int m0 = ((xcd << 3) + (bj >> 2)) << 8;
    int n0 = (bj & 3) << 8;

    f32x4 acc[8][4];
#pragma unroll
    for (int i = 0; i < 8; i++)
#pragma unroll
        for (int j = 0; j < 4; j++) acc[i][j] = f32x4{0.f, 0.f, 0.f, 0.f};

    int frow = lane & 15;
    int sw = ((lane >> 4) ^ ((frow >> 1) & 3)) * 8;   // read-side chunk swizzle

    stage_part<0>(lds, Ahi, Alo, Xhi, Xlo, m0, n0, 0, tid);
    stage_part<1>(lds, Ahi, Alo, Xhi, Xlo, m0, n0, 0, tid);
    stage_part<2>(lds, Ahi, Alo, Xhi, Xlo, m0, n0, 0, tid);
    stage_part<3>(lds, Ahi, Alo, Xhi, Xlo, m0, n0, 0, tid);

    int cur = 0;
    for (int ks = 0; ks < 32; ++ks) {
        unsigned short* rb = lds + cur * BUFS;
        unsigned short* wb = lds + (cur ^ 1) * BUFS;
        const bool pf = (ks < 31);
        const int k1 = (ks + 1) * 32;

        if (pf) {
            stage_part<0>(wb, Ahi, Alo, Xhi, Xlo, m0, n0, k1, tid);
            SCHED0;
            asm volatile("s_waitcnt vmcnt(2)" ::: "memory");
        } else {
            asm volatile("s_waitcnt vmcnt(0)" ::: "memory");
        }
        SCHED0; ASM_BAR; SCHED0;

        short8 bh[4], bl[4];
#pragma unroll
        for (int j = 0; j < 4; j++) {
            int br = wn * 64 + j * 16 + frow;
            bh[j] = *(const short8*)&rb[BHI + br * 32 + sw];
            bl[j] = *(const short8*)&rb[BLO + br * 32 + sw];
        }
        {
            int ar0 = wm * 128 + 0 * 16 + frow, ar1 = wm * 128 + 1 * 16 + frow;
            short8 a0h = *(const short8*)&rb[AHI + ar0 * 32 + sw];
            short8 a1h = *(const short8*)&rb[AHI + ar1 * 32 + sw];
            short8 a0l = *(const short8*)&rb[ALO + ar0 * 32 + sw];
            short8 a1l = *(const short8*)&rb[ALO + ar1 * 32 + sw];
            if (pf) stage_part<1>(wb, Ahi, Alo, Xhi, Xlo, m0, n0, k1, tid);
            SCHED0; ASM_BAR; SCHED0;
            asm volatile("s_waitcnt lgkmcnt(0)" ::: "memory"); SCHED0;
            __builtin_amdgcn_s_setprio(1);
            mfma_mi3(a0h, a0l, bh, bl, acc[0]);
            mfma_mi3(a1h, a1l, bh, bl, acc[1]);
            __builtin_amdgcn_s_setprio(0);
            SCHED0; ASM_BAR; SCHED0;
        }
#pragma unroll
        for (int ph = 1; ph < 4; ph++) {
            int mia = 2 * ph, mib = 2 * ph + 1;
            int ara = wm * 128 + mia * 16 + frow, arb = wm * 128 + mib * 16 + frow;
            short8 aah = *(const short8*)&rb[AHI + ara * 32 + sw];
            short8 abh = *(const short8*)&rb[AHI + arb * 32 + sw];
            short8 aal = *(const short8*)&rb[ALO + ara * 32 + sw];
            short8 abl = *(const short8*)&rb[ALO + arb * 32 + sw];
            if (pf) {
                if (ph == 1) stage_part<2>(wb, Ahi, Alo, Xhi, Xlo, m0, n0, k1, tid);
                if (ph == 2) stage_part<3>(wb, Ahi, Alo, Xhi, Xlo, m0, n0, k1, tid);
            }
            SCHED0; ASM_BAR; SCHED0;
            asm volatile("s_waitcnt lgkmcnt(0)" ::: "memory"); SCHED0;
            __builtin_amdgcn_s_setprio(1);
            mfma_mi3(aah, aal, bh, bl, acc[mia]);
            mfma_mi3(abh, abl, bh, bl, acc[mib]);
            __builtin_amdgcn_s_setprio(0);
            SCHED0; ASM_BAR; SCHED0;
        }
        cur ^= 1;
    }

    int crow = (lane >> 4) * 4, ccol = lane & 15;
    if constexpr (MODE == 0) {
        unsigned long long best[4] = {~0ULL, ~0ULL, ~0ULL, ~0ULL};
#pragma unroll
        for (int mi = 0; mi < 8; mi++)
#pragma unroll
            for (int r = 0; r < 4; r++) {
                int gm = m0 + wm * 128 + mi * 16 + crow + r;
                float pcx = 0.f, pcq = 0.f;
#pragma unroll
                for (int jj = 0; jj < 4; jj++) {
                    int gn = n0 + wn * 64 + jj * 16 + ccol;
                    size_t idx = (size_t)gm * A_DIM + gn;
                    float c = bf2f(Ahi[idx]) + bf2f(Alo[idx]);
                    float q = qt[idx];
                    float xc = acc[mi][jj][r];
                    XC[idx] = xc;               // refresh the tracked X@c
                    pcx += c * xc;
                    pcq += c * q;
                    unsigned long long key =
                        ((unsigned long long)fkey(xc - q) << 32) | (unsigned int)gm;
                    if (key < best[jj]) best[jj] = key;
                }
                for (int mm = 1; mm < 16; mm <<= 1) {
                    pcx += __shfl_xor(pcx, mm, 16);
                    pcq += __shfl_xor(pcq, mm, 16);
                }
                if (ccol == 0) {
                    atomicAdd(&cxc[gm], pcx);
                    atomicAdd(&cq[gm], pcq);
                }
            }
#pragma unroll
        for (int jj = 0; jj < 4; jj++) {
            int gn = n0 + wn * 64 + jj * 16 + ccol;
            unsigned long long o = __shfl_xor(best[jj], 16);
            if (o < best[jj]) best[jj] = o;
            o = __shfl_xor(best[jj], 32);
            if (o < best[jj]) best[jj] = o;
            if ((lane >> 4) == 0) atomicMin(&keys[gn], best[jj]);
        }
    } else {
        // MODE 3: Xd = acc -> G; denom partial = sum(d * Xd) -> scal3
        float part = 0.f;
#pragma unroll
        for (int mi = 0; mi < 8; mi++)
#pragma unroll
            for (int r = 0; r < 4; r++) {
                int gm = m0 + wm * 128 + mi * 16 + crow + r;
#pragma unroll
                for (int jj = 0; jj < 4; jj++) {
                    int gn = n0 + wn * 64 + jj * 16 + ccol;
                    size_t idx = (size_t)gm * A_DIM + gn;
                    float d = bf2f(Ahi[idx]) + bf2f(Alo[idx]);
                    float xd = acc[mi][jj][r];
                    G[idx] = xd;
                    part += xd * d;
                }
            }
        part = wave_sum(part);
        if (lane == 0) red[w] = part;
        __syncthreads();
        if (tid == 0) {
            float tot = red[0] + red[1] + red[2] + red[3] +
                        red[4] + red[5] + red[6] + red[7];
            atomicAdd(scal3, tot);
        }
    }
}

// ---------------- nondiff fused stream: update(t-1) + grad/argmin(t) ----------------
// 256 blocks x 256 thr; wave w owns rows b0+w+4*rr. Applies c/XC update from
// iter t-1 (Kprev ballot masks, scalars), then computes grad, argmin->Kcur,
// cxc[b]=c.Xc, cq[b]=c.q (direct row-owned writes), num_amg[b]=0.
__global__ __launch_bounds__(256) void fgrad(const float* __restrict__ qt,
                                             unsigned short* __restrict__ Chi,
                                             unsigned short* __restrict__ Clo,
                                             float* __restrict__ XC,
                                             const float* __restrict__ Xf,
                                             const unsigned long long* __restrict__ Kprev,
                                             unsigned long long* __restrict__ Kcur,
                                             float* __restrict__ cxc,
                                             float* __restrict__ cq,
                                             float* __restrict__ num_amg,
                                             const float* __restrict__ scalPrev,
                                             float* __restrict__ scalCur) {
    __shared__ unsigned long long lkeys[4][1024];   // 32 KiB
    int tid = threadIdx.x;
    if (blockIdx.x == 0 && tid < 4) scalCur[tid] = 0.f;   // other blocks read scalPrev only
    int w = tid >> 6, lane = tid & 63;
    int b0 = blockIdx.x * 64;
    float den = scalPrev[0] + scalPrev[1] - 2.f * scalPrev[2] + EPS_C;

    unsigned int klow[16];
#pragma unroll
    for (int s = 0; s < 16; s++) klow[s] = (unsigned int)Kprev[lane + s * 64];

    unsigned long long best[16];
#pragma unroll
    for (int i = 0; i < 16; i++) best[i] = ~0ULL;

    for (int rr = 0; rr < 16; ++rr) {
        int b = b0 + w + rr * 4;
        float lam = clamp01((cxc[b] - cq[b] - num_amg[b]) / den);
        float om = 1.f - lam;
        unsigned long long mask[16];
#pragma unroll
        for (int s = 0; s < 16; s++) mask[s] = __ballot(klow[s] == (unsigned int)b);

        unsigned short* hr = Chi + (size_t)b * A_DIM;
        unsigned short* lr = Clo + (size_t)b * A_DIM;
        float* xcr = XC + (size_t)b * A_DIM;
        const float* qr = qt + (size_t)b * A_DIM;
        float dx = 0.f, dq = 0.f;
#pragma unroll
        for (int ch = 0; ch < 4; ++ch) {
            int col = ch * 256 + lane * 4;
            ushort4 hv = *(const ushort4*)(hr + col);
            ushort4 lv = *(const ushort4*)(lr + col);
            float4 xv = *(const float4*)(xcr + col);
            float4 qv = *(const float4*)(qr + col);
            // indicator bits for this lane's 4 cols (all in one 64-block)
            int sel = lane >> 4;
            unsigned long long mw =
                (sel == 0) ? mask[ch * 4 + 0] :
                (sel == 1) ? mask[ch * 4 + 1] :
                (sel == 2) ? mask[ch * 4 + 2] : mask[ch * 4 + 3];
            unsigned int ind4 = (unsigned int)((mw >> ((lane & 15) * 4)) & 0xFULL);
            float c0 = om * (bf2f(hv.x) + bf2f(lv.x)) + ((ind4 & 1u) ? lam : 0.f);
            float c1 = om * (bf2f(hv.y) + bf2f(lv.y)) + ((ind4 & 2u) ? lam : 0.f);
            float c2 = om * (bf2f(hv.z) + bf2f(lv.z)) + ((ind4 & 4u) ? lam : 0.f);
            float c3 = om * (bf2f(hv.w) + bf2f(lv.w)) + ((ind4 & 8u) ? lam : 0.f);
            // XC recurrence: om*XC + lam * sum_{matched a} Xf[a, cols]
            xv.x *= om; xv.y *= om; xv.z *= om; xv.w *= om;
#pragma unroll
            for (int s = 0; s < 16; s++) {
                unsigned long long m = mask[s];
                while (m) {   // wave-uniform (mask/lam uniform per row)
                    int a = __ffsll(m) - 1 + s * 64;
                    m &= m - 1;
                    float4 av = *(const float4*)(Xf + (size_t)a * A_DIM + col);
                    xv.x += lam * av.x; xv.y += lam * av.y;
                    xv.z += lam * av.z; xv.w += lam * av.w;
                }
            }
            // store updated c (split) and XC
            split2(c0, hv.x, lv.x);
            split2(c1, hv.y, lv.y);
            split2(c2, hv.z, lv.z);
            split2(c3, hv.w, lv.w);
            *(ushort4*)(hr + col) = hv;
            *(ushort4*)(lr + col) = lv;
            *(float4*)(xcr + col) = xv;
            // grads / dots / argmin
            float g0 = xv.x - qv.x, g1 = xv.y - qv.y, g2 = xv.z - qv.z, g3 = xv.w - qv.w;
            dx += c0 * xv.x + c1 * xv.y + c2 * xv.z + c3 * xv.w;
            dq += c0 * qv.x + c1 * qv.y + c2 * qv.z + c3 * qv.w;
            unsigned long long k0 = ((unsigned long long)fkey(g0) << 32) | (unsigned int)b;
            unsigned long long k1 = ((unsigned long long)fkey(g1) << 32) | (unsigned int)b;
            unsigned long long k2 = ((unsigned long long)fkey(g2) << 32) | (unsigned int)b;
            unsigned long long k3 = ((unsigned long long)fkey(g3) << 32) | (unsigned int)b;
            if (k0 < best[ch * 4 + 0]) best[ch * 4 + 0] = k0;
            if (k1 < best[ch * 4 + 1]) best[ch * 4 + 1] = k1;
            if (k2 < best[ch * 4 + 2]) best[ch * 4 + 2] = k2;
            if (k3 < best[ch * 4 + 3]) best[ch * 4 + 3] = k3;
        }
        dx = wave_sum(dx);
        dq = wave_sum(dq);
        if (lane == 0) {
            cxc[b] = dx;          // row-owned overwrite (old value already consumed)
            cq[b] = dq;
            num_amg[b] = 0.f;     // reset for this iteration's stats atomics
        }
    }
#pragma unroll
    for (int ch = 0; ch < 4; ++ch)
#pragma unroll
        for (int j = 0; j < 4; ++j)
            lkeys[w][ch * 256 + lane * 4 + j] = best[ch * 4 + j];
    __syncthreads();
    for (int i = tid; i < 1024; i += 256) {
        unsigned long long v = lkeys[0][i];
        if (lkeys[1][i] < v) v = lkeys[1][i];
        if (lkeys[2][i] < v) v = lkeys[2][i];
        if (lkeys[3][i] < v) v = lkeys[3][i];
        atomicMin(&Kcur[i], v);
    }
}

// ---------------- setup kernels ----------------

__global__ __launch_bounds__(256) void ynorm_split_kernel(const float* __restrict__ y,
                                                          float* __restrict__ ynorm,
                                                          unsigned short* __restrict__ Ynh,
                                                          unsigned short* __restrict__ Ynl) {
    __shared__ float red[16];
    int b = blockIdx.x;
    const float* row = y + (size_t)b * D_DIM;
    float s = 0.f;
    for (int i = threadIdx.x; i < D_DIM; i += 256) s += fabsf(row[i]);
    float tot = block_reduce_sum(s, red);
    float inv = 1.f / tot;
    unsigned short* oh = Ynh + (size_t)b * D_DIM;
    unsigned short* ol = Ynl + (size_t)b * D_DIM;
    for (int i = threadIdx.x; i < D_DIM; i += 256) {
        unsigned short h, l;
        split2(row[i] * inv, h, l);
        oh[i] = h; ol[i] = l;
    }
    if (threadIdx.x == 0) ynorm[b] = tot;
}

__global__ __launch_bounds__(256) void anorm_kernel(const float* __restrict__ atoms,
                                                    float* __restrict__ an,
                                                    float* __restrict__ anrm,
                                                    unsigned short* __restrict__ Anh,
                                                    unsigned short* __restrict__ Anl) {
    __shared__ float red[16];
    int a = blockIdx.x;
    const float* row = atoms + (size_t)a * D_DIM;
    float s = 0.f;
    for (int i = threadIdx.x; i < D_DIM; i += 256) s += fabsf(row[i]);
    float tot = block_reduce_sum(s, red);
    float inv = 1.f / tot;
    for (int i = threadIdx.x; i < D_DIM; i += 256) {
        float v = row[i] * inv;
        an[(size_t)a * D_DIM + i] = v;
        unsigned short h, l;
        split2(v, h, l);
        Anh[(size_t)a * D_DIM + i] = h;
        Anl[(size_t)a * D_DIM + i] = l;
    }
    if (threadIdx.x == 0) anrm[a] = tot;
}

__global__ __launch_bounds__(256) void atrans_split_kernel(const float* __restrict__ atoms,
                                                           const float* __restrict__ anrm,
                                                           unsigned short* __restrict__ AnTh,
                                                           unsigned short* __restrict__ AnTl) {
    int n = blockIdx.x;
    for (int k = threadIdx.x; k < A_DIM; k += 256) {
        float v = atoms[(size_t)k * D_DIM + n] / anrm[k];
        unsigned short h, l;
        split2(v, h, l);
        AnTh[(size_t)n * A_DIM + k] = h;
        AnTl[(size_t)n * A_DIM + k] = l;
    }
}

__global__ __launch_bounds__(256) void split_kernel(const float* __restrict__ src,
                                                    unsigned short* __restrict__ hi,
                                                    unsigned short* __restrict__ lo,
                                                    int n4) {
    int i = blockIdx.x * 256 + threadIdx.x;
    if (i < n4) {
        float4 v = ((const float4*)src)[i];
        ushort4 h, l;
        split2(v.x, h.x, l.x);
        split2(v.y, h.y, l.y);
        split2(v.z, h.z, l.z);
        split2(v.w, h.w, l.w);
        ((ushort4*)hi)[i] = h;
        ((ushort4*)lo)[i] = l;
    }
}

__global__ __launch_bounds__(256) void fill_pair_kernel(unsigned short* __restrict__ Chi,
                                                        unsigned short* __restrict__ Clo,
                                                        size_t n4) {
    size_t i = (size_t)blockIdx.x * 256 + threadIdx.x;
    if (i < n4) {
        unsigned short h, l;
        split2(1.f / A_DIM, h, l);
        ((ushort4*)Chi)[i] = make_ushort4(h, h, h, h);
        ((ushort4*)Clo)[i] = make_ushort4(l, l, l, l);
    }
}

// fp32 vector GEMM, B transposed, setup only: X = an @ an^T
__global__ __launch_bounds__(256) void gemm_xt(const float* __restrict__ Aop,
                                               float* __restrict__ Cout) {
    const int LDT = 132;
    const int N = A_DIM, K = D_DIM;
    __shared__ float As[16 * LDT];
    __shared__ float Bs[16 * LDT];
    int m0 = blockIdx.y * 128, n0 = blockIdx.x * 128;
    int tid = threadIdx.x;
    int tx = tid & 15, ty = tid >> 4;
    float acc[8][8];
#pragma unroll
    for (int i = 0; i < 8; i++)
#pragma unroll
        for (int j = 0; j < 8; j++) acc[i][j] = 0.f;
    for (int k0 = 0; k0 < K; k0 += 16) {
#pragma unroll
        for (int s = 0; s < 2; s++) {
            int idx = tid + s * 256;
            int row = idx >> 2, kq = (idx & 3) * 4;
            float4 v = *(const float4*)(Aop + (size_t)(m0 + row) * K + k0 + kq);
            As[(kq + 0) * LDT + row] = v.x;
            As[(kq + 1) * LDT + row] = v.y;
            As[(kq + 2) * LDT + row] = v.z;
            As[(kq + 3) * LDT + row] = v.w;
        }
#pragma unroll
        for (int s = 0; s < 2; s++) {
            int idx = tid + s * 256;
            int row = idx >> 2, kq = (idx & 3) * 4;
            float4 v = *(const float4*)(Aop + (size_t)(n0 + row) * K + k0 + kq);
            Bs[(kq + 0) * LDT + row] = v.x;
            Bs[(kq + 1) * LDT + row] = v.y;
            Bs[(kq + 2) * LDT + row] = v.z;
            Bs[(kq + 3) * LDT + row] = v.w;
        }
        __syncthreads();
#pragma unroll
        for (int kk = 0; kk < 16; kk++) {
            float a[8], b[8];
            *(float4*)(a)     = *(const float4*)(As + kk * LDT + ty * 8);
            *(float4*)(a + 4) = *(const float4*)(As + kk * LDT + ty * 8 + 4);
            *(float4*)(b)     = *(const float4*)(Bs + kk * LDT + tx * 8);
            *(float4*)(b + 4) = *(const float4*)(Bs + kk * LDT + tx * 8 + 4);
#pragma unroll
            for (int i = 0; i < 8; i++)
#pragma unroll
                for (int j = 0; j < 8; j++) acc[i][j] = fmaf(a[i], b[j], acc[i][j]);
        }
        __syncthreads();
    }
#pragma unroll
    for (int i = 0; i < 8; i++) {
        int row = m0 + ty * 8 + i;
#pragma unroll
        for (int j = 0; j < 8; j += 4) {
            int col = n0 + tx * 8 + j;
            float4 v = make_float4(acc[i][j], acc[i][j + 1], acc[i][j + 2], acc[i][j + 3]);
            *(float4*)(Cout + (size_t)row * N + col) = v;
        }
    }
}

// qt = Yn @ An^T  (bf16x2 pair-pair MFMA, K=768), swizzled 1D grid of 1024
__global__ __launch_bounds__(256) void qt_mfma(const unsigned short* __restrict__ Ynh,
                                               const unsigned short* __restrict__ Ynl,
                                               const unsigned short* __restrict__ Anh,
                                               const unsigned short* __restrict__ Anl,
                                               float* __restrict__ qt) {
    __shared__ unsigned short lds[16384];
    int tid = threadIdx.x;
    int w = tid >> 6, lane = tid & 63;
    int wm = w >> 1, wn = w & 1;
    int m0, n0;
    swz(blockIdx.x, m0, n0);

    f32x4 acc[4][4];
#pragma unroll
    for (int i = 0; i < 4; i++)
#pragma unroll
        for (int j = 0; j < 4; j++) acc[i][j] = f32x4{0.f, 0.f, 0.f, 0.f};

    const unsigned short* gsrc;
    if (w == 0) gsrc = Ynh + (size_t)m0 * D_DIM;
    else if (w == 1) gsrc = Ynl + (size_t)m0 * D_DIM;
    else if (w == 2) gsrc = Anh + (size_t)n0 * D_DIM;
    else gsrc = Anl + (size_t)n0 * D_DIM;
    unsigned short* ltile = lds + w * 4096;
    for (int k0 = 0; k0 < D_DIM; k0 += 32) {
        stage_tile8(gsrc, D_DIM, k0, ltile, lane);
        __syncthreads();
        mfma_k32(lds, wm, wn, lane, acc);
        __syncthreads();
    }

    int crow = (lane >> 4) * 4, ccol = lane & 15;
#pragma unroll
    for (int i = 0; i < 4; i++) {
        int gm = m0 + wm * 64 + i * 16 + crow;
#pragma unroll
        for (int j = 0; j < 4; j++) {
            int gn = n0 + wn * 64 + j * 16 + ccol;
#pragma unroll
            for (int r = 0; r < 4; r++)
                qt[(size_t)(gm + r) * A_DIM + gn] = acc[i][j][r];
        }
    }
}

// ---------------- nondiff per-iteration kernels ----------------

// one-time init: both key banks, num_amg/cxc/cq, both scal banks
__global__ __launch_bounds__(256) void init_kernel(unsigned long long* __restrict__ keys,
                                                   float* __restrict__ num_amg,
                                                   float* __restrict__ cxc,
                                                   float* __restrict__ cq,
                                                   float* __restrict__ scal) {
    int i = blockIdx.x * 256 + threadIdx.x;
    num_amg[i] = 0.f;
    cxc[i] = 0.f;
    cq[i] = 0.f;
    if (i < 2 * A_DIM) keys[i] = ~0ULL;
    if (i < 8) scal[i] = 0.f;
}

// stats: block per atom a; reads Kcur, adds scalCur/num_amg; resets Knext[a].
__global__ __launch_bounds__(256) void stats_kernel(const float* __restrict__ Xf,
                                                    const unsigned long long* __restrict__ Kcur,
                                                    const unsigned short* __restrict__ Chi,
                                                    const unsigned short* __restrict__ Clo,
                                                    const float* __restrict__ qt,
                                                    const float* __restrict__ cxc,
                                                    float* __restrict__ num_amg,
                                                    float* __restrict__ scalCur,
                                                    unsigned long long* __restrict__ Knext) {
    __shared__ float red[16];
    int a = blockIdx.x;
    int ba = (int)(unsigned int)(Kcur[a] & 0xFFFFFFFFULL);
    const float* xr = Xf + (size_t)a * A_DIM;
    const unsigned short* ch = Chi + (size_t)ba * A_DIM;
    const unsigned short* cl = Clo + (size_t)ba * A_DIM;
    float ps = 0.f, xs = 0.f;
    for (int i = threadIdx.x; i < A_DIM; i += 256) {
        float xv = xr[i];
        if ((int)(unsigned int)(Kcur[i] & 0xFFFFFFFFULL) == ba) ps += xv;
        xs += xv * (bf2f(ch[i]) + bf2f(cl[i]));
    }
    float s1p = (threadIdx.x < 16) ? cxc[(a << 4) + threadIdx.x] : 0.f;
    block_reduce_sum3(ps, xs, s1p, red);
    if (threadIdx.x == 0) {
        atomicAdd(&scalCur[0], ps);
        atomicAdd(&scalCur[2], xs);
        atomicAdd(&scalCur[1], s1p);
        atomicAdd(&num_amg[ba], xs - qt[(size_t)ba * A_DIM + a]);
        Knext[a] = ~0ULL;     // reset other bank for next iteration's argmin
    }
}

// thin update before a refresh GEMM: c only (refresh rewrites XC exactly);
// resets cxc/cq/num_amg for the refresh's atomicAdds.
__global__ __launch_bounds__(256) void ndupdate_c(unsigned short* __restrict__ Chi,
                                                  unsigned short* __restrict__ Clo,
                                                  const unsigned long long* __restrict__ Kprev,
                                                  float* __restrict__ cxc,
                                                  float* __restrict__ cq,
                                                  float* __restrict__ num_amg,
                                                  const float* __restrict__ scalPrev) {
    int b = blockIdx.x;
    float den = scalPrev[0] + scalPrev[1] - 2.f * scalPrev[2] + EPS_C;
    float lam = clamp01((cxc[b] - cq[b] - num_amg[b]) / den);
    float om = 1.f - lam;
    int i = threadIdx.x;
    ushort4* h4 = (ushort4*)(Chi + (size_t)b * A_DIM);
    ushort4* l4 = (ushort4*)(Clo + (size_t)b * A_DIM);
    ushort4 h = h4[i], l = l4[i];
    int b0 = (int)(unsigned int)Kprev[i * 4 + 0];
    int b1 = (int)(unsigned int)Kprev[i * 4 + 1];
    int b2 = (int)(unsigned int)Kprev[i * 4 + 2];
    int b3 = (int)(unsigned int)Kprev[i * 4 + 3];
    float c0 = om * (bf2f(h.x) + bf2f(l.x)) + ((b0 == b) ? lam : 0.f);
    float c1 = om * (bf2f(h.y) + bf2f(l.y)) + ((b1 == b) ? lam : 0.f);
    float c2 = om * (bf2f(h.z) + bf2f(l.z)) + ((b2 == b) ? lam : 0.f);
    float c3 = om * (bf2f(h.w) + bf2f(l.w)) + ((b3 == b) ? lam : 0.f);
    split2(c0, h.x, l.x);
    split2(c1, h.y, l.y);
    split2(c2, h.z, l.z);
    split2(c3, h.w, l.w);
    h4[i] = h; l4[i] = l;
    __syncthreads();
    if (i == 0) {
        cxc[b] = 0.f;
        cq[b] = 0.f;
        num_amg[b] = 0.f;
    }
}

// full update after iter 29: c + XC recurrence (diff's rinit needs XC_30)
__global__ __launch_bounds__(256) void ndupdate_full(unsigned short* __restrict__ Chi,
                                                     unsigned short* __restrict__ Clo,
                                                     const unsigned long long* __restrict__ Kprev,
                                                     const float* __restrict__ cxc,
                                                     const float* __restrict__ cq,
                                                     const float* __restrict__ num_amg,
                                                     const float* __restrict__ scalPrev,
                                                     float* __restrict__ XC,
                                                     const float* __restrict__ Xf) {
    __shared__ int mlist[1024];
    __shared__ int mcount;
    int b = blockIdx.x;
    int i = threadIdx.x;
    if (i == 0) mcount = 0;
    float den = scalPrev[0] + scalPrev[1] - 2.f * scalPrev[2] + EPS_C;
    float lam = clamp01((cxc[b] - cq[b] - num_amg[b]) / den);
    float om = 1.f - lam;
    ushort4* h4 = (ushort4*)(Chi + (size_t)b * A_DIM);
    ushort4* l4 = (ushort4*)(Clo + (size_t)b * A_DIM);
    ushort4 h = h4[i], l = l4[i];
    int b0 = (int)(unsigned int)Kprev[i * 4 + 0];
    int b1 = (int)(unsigned int)Kprev[i * 4 + 1];
    int b2 = (int)(unsigned int)Kprev[i * 4 + 2];
    int b3 = (int)(unsigned int)Kprev[i * 4 + 3];
    float c0 = om * (bf2f(h.x) + bf2f(l.x)) + ((b0 == b) ? lam : 0.f);
    float c1 = om * (bf2f(h.y) + bf2f(l.y)) + ((b1 == b) ? lam : 0.f);
    float c2 = om * (bf2f(h.z) + bf2f(l.z)) + ((b2 == b) ? lam : 0.f);
    float c3 = om * (bf2f(h.w) + bf2f(l.w)) + ((b3 == b) ? lam : 0.f);
    split2(c0, h.x, l.x);
    split2(c1, h.y, l.y);
    split2(c2, h.z, l.z);
    split2(c3, h.w, l.w);
    h4[i] = h; l4[i] = l;
    __syncthreads();
    for (int a = i; a < A_DIM; a += 256)
        if ((int)(unsigned int)Kprev[a] == b) { int p = atomicAdd(&mcount, 1); mlist[p] = a; }
    __syncthreads();
    float4 xv = *(float4*)(XC + (size_t)b * A_DIM + i * 4);
    xv.x *= om; xv.y *= om; xv.z *= om; xv.w *= om;
    int mc = mcount;
    for (int m = 0; m < mc; m++) {
        float4 av = *(const float4*)(Xf + (size_t)mlist[m] * A_DIM + i * 4);
        xv.x += lam * av.x; xv.y += lam * av.y;
        xv.z += lam * av.z; xv.w += lam * av.w;
    }
    *(float4*)(XC + (size_t)b * A_DIM + i * 4) = xv;
}

// ---------------- diff-phase kernels ----------------

// R = XC - qt (in place in Greg), once at diff entry; qt becomes the Xd buffer.
__global__ __launch_bounds__(256) void rinit_kernel(float* __restrict__ XC,
                                                    const float* __restrict__ qt) {
    size_t i = (size_t)blockIdx.x * 256 + threadIdx.x;
    float4 x = ((const float4*)XC)[i];
    float4 q = ((const float4*)qt)[i];
    x.x -= q.x; x.y -= q.y; x.z -= q.z; x.w -= q.w;
    ((float4*)XC)[i] = x;
}

// one-time softmax at diff entry: d_0 = sm(R_0) - c_0, num_cg_0; resets scal3 slot0
__global__ __launch_bounds__(256) void softmax_kernel(const float* __restrict__ R,
                                                      unsigned short* __restrict__ Chi,
                                                      unsigned short* __restrict__ Clo,
                                                      float* __restrict__ num_cg,
                                                      float* __restrict__ scal3) {
    __shared__ float red[16];
    int b = blockIdx.x;
    int i = threadIdx.x;
    if (b == 0 && i == 0) *scal3 = 0.f;
    const float4* g4 = (const float4*)(R + (size_t)b * A_DIM);
    ushort4* h4 = (ushort4*)(Chi + (size_t)b * A_DIM);
    ushort4* l4 = (ushort4*)(Clo + (size_t)b * A_DIM);
    float4 g = g4[i];
    ushort4 h = h4[i], l = l4[i];
    float c0 = bf2f(h.x) + bf2f(l.x);
    float c1 = bf2f(h.y) + bf2f(l.y);
    float c2 = bf2f(h.z) + bf2f(l.z);
    float c3 = bf2f(h.w) + bf2f(l.w);
    float4 t = make_float4(-TEMP_C * g.x, -TEMP_C * g.y, -TEMP_C * g.z, -TEMP_C * g.w);
    float m = fmaxf(fmaxf(t.x, t.y), fmaxf(t.z, t.w));
    float M = block_reduce_max(m, red);
    float4 e = make_float4(expf(t.x - M), expf(t.y - M), expf(t.z - M), expf(t.w - M));
    float S = block_reduce_sum(e.x + e.y + e.z + e.w, red);
    float inv = 1.f / S;
    float4 sm = make_float4(e.x * inv, e.y * inv, e.z * inv, e.w * inv);
    float np = (c0 - sm.x) * g.x + (c1 - sm.y) * g.y + (c2 - sm.z) * g.z + (c3 - sm.w) * g.w;
    split2(sm.x - c0, h.x, l.x);
    split2(sm.y - c1, h.y, l.y);
    split2(sm.z - c2, h.z, l.z);
    split2(sm.w - c3, h.w, l.w);
    h4[i] = h; l4[i] = l;
    float nt = block_reduce_sum(np, red);
    if (i == 0) num_cg[b] = nt;
}

// fused diff update: sm_t from R_t -> lam -> c_{t+1} = sm_t - om*d_t;
// R_{t+1} = R_t + lam*Xd; if !LAST: sm_{t+1}, d_{t+1} -> Chi/Clo, num_{t+1};
// else write c_{t+1}. Resets the OTHER scal3 slot (s3next) for the next GEMM.
template <int LAST>
__global__ __launch_bounds__(256) void dupdate_fused(float* __restrict__ R,
                                                     const float* __restrict__ Xd,
                                                     unsigned short* __restrict__ Chi,
                                                     unsigned short* __restrict__ Clo,
                                                     float* __restrict__ num_cg,
                                                     const float* __restrict__ s3cur,
                                                     float* __restrict__ s3next) {
    __shared__ float red[16];
    int b = blockIdx.x;
    int i = threadIdx.x;
    if (!LAST && b == 0 && i == 0) *s3next = 0.f;
    float4* r4 = (float4*)(R + (size_t)b * A_DIM);
    float4 g = r4[i];
    // sm_t (bitwise-identical sequence to softmax_kernel)
    float4 t = make_float4(-TEMP_C * g.x, -TEMP_C * g.y, -TEMP_C * g.z, -TEMP_C * g.w);
    float m = fmaxf(fmaxf(t.x, t.y), fmaxf(t.z, t.w));
    float M = block_reduce_max(m, red);
    float4 e = make_float4(expf(t.x - M), expf(t.y - M), expf(t.z - M), expf(t.w - M));
    float S = block_reduce_sum(e.x + e.y + e.z + e.w, red);
    float inv = 1.f / S;
    float4 sm = make_float4(e.x * inv, e.y * inv, e.z * inv, e.w * inv);
    float den = *s3cur + EPS_C;
    float lam = clamp01(num_cg[b] / den);
    float om = 1.f - lam;
    ushort4* h4 = (ushort4*)(Chi + (size_t)b * A_DIM);
    ushort4* l4 = (ushort4*)(Clo + (size_t)b * A_DIM);
    ushort4 h = h4[i], l = l4[i];          // d_t
    float c0 = sm.x - om * (bf2f(h.x) + bf2f(l.x));
    float c1 = sm.y - om * (bf2f(h.y) + bf2f(l.y));
    float c2 = sm.z - om * (bf2f(h.z) + bf2f(l.z));
    float c3 = sm.w - om * (bf2f(h.w) + bf2f(l.w));
    float4 xd = ((const float4*)(Xd + (size_t)b * A_DIM))[i];
    g.x += lam * xd.x; g.y += lam * xd.y;
    g.z += lam * xd.z; g.w += lam * xd.w;
    r4[i] = g;                              // R_{t+1}
    if (LAST) {
        split2(c0, h.x, l.x);
        split2(c1, h.y, l.y);
        split2(c2, h.z, l.z);
        split2(c3, h.w, l.w);
        h4[i] = h; l4[i] = l;
    } else {
        // sm_{t+1} from R_{t+1}
        float4 t2 = make_float4(-TEMP_C * g.x, -TEMP_C * g.y, -TEMP_C * g.z, -TEMP_C * g.w);
        float m2 = fmaxf(fmaxf(t2.x, t2.y), fmaxf(t2.z, t2.w));
        float M2 = block_reduce_max(m2, red);
        float4 e2 = make_float4(expf(t2.x - M2), expf(t2.y - M2),
                                expf(t2.z - M2), expf(t2.w - M2));
        float S2 = block_reduce_sum(e2.x + e2.y + e2.z + e2.w, red);
        float inv2 = 1.f / S2;
        float4 sm2 = make_float4(e2.x * inv2, e2.y * inv2, e2.z * inv2, e2.w * inv2);
        float np = (c0 - sm2.x) * g.x + (c1 - sm2.y) * g.y +
                   (c2 - sm2.z) * g.z + (c3 - sm2.w) * g.w;
        split2(sm2.x - c0, h.x, l.x);
        split2(sm2.y - c1, h.y, l.y);
        split2(sm2.z - c2, h.z, l.z);
        split2(sm2.w - c3, h.w, l.w);
        h4[i] = h; l4[i] = l;               // d_{t+1}
        float nt = block_reduce_sum(np, red);
        if (i == 0) num_cg[b] = nt;
    }
}

// recon: out[b, n] = (c_b . anT[:,n]) * ynorm[b]
__global__ __launch_bounds__(256) void mfma_recon(const unsigned short* __restrict__ Chi,
                                                  const unsigned short* __restrict__ Clo,
                                                  const unsigned short* __restrict__ AnTh,
                                                  const unsigned short* __restrict__ AnTl,
                                                  const float* __restrict__ ynorm,
                                                  float* __restrict__ out) {
    __shared__ unsigned short lds[16384];
    int tid = threadIdx.x;
    int w = tid >> 6, lane = tid & 63;
    int wm = w >> 1, wn = w & 1;
    int m0 = blockIdx.y * 128, n0 = blockIdx.x * 128;

    f32x4 acc[4][4];
#pragma unroll
    for (int i = 0; i < 4; i++)
#pragma unroll
        for (int j = 0; j < 4; j++) acc[i][j] = f32x4{0.f, 0.f, 0.f, 0.f};

    const unsigned short* gsrc;
    if (w == 0) gsrc = Chi + (size_t)m0 * A_DIM;
    else if (w == 1) gsrc = Clo + (size_t)m0 * A_DIM;
    else if (w == 2) gsrc = AnTh + (size_t)n0 * A_DIM;
    else gsrc = AnTl + (size_t)n0 * A_DIM;
    unsigned short* ltile = lds + w * 4096;
    for (int k0 = 0; k0 < A_DIM; k0 += 32) {
        stage_tile8(gsrc, A_DIM, k0, ltile, lane);
        __syncthreads();
        mfma_k32(lds, wm, wn, lane, acc);
        __syncthreads();
    }

    int crow = (lane >> 4) * 4, ccol = lane & 15;
#pragma unroll
    for (int i = 0; i < 4; i++) {
        int gm = m0 + wm * 64 + i * 16 + crow;
#pragma unroll
        for (int j = 0; j < 4; j++) {
            int gn = n0 + wn * 64 + j * 16 + ccol;
#pragma unroll
            for (int r = 0; r < 4; r++)
                out[(size_t)(gm + r) * D_DIM + gn] = acc[i][j][r] * ynorm[gm + r];
        }
    }
}

// ---------------- host launch ----------------

extern "C" void kernel_launch(void* const* d_in, const int* in_sizes, int n_in,
                              void* d_out, int out_size, void* d_ws, size_t ws_size,
                              hipStream_t stream) {
    const float* y = (const float*)d_in[0];      // [B, 768]
    const float* atoms = (const float*)d_in[1];  // [A, 768]
    float* out = (float*)d_out;                  // [B, 768]

    char* ws = (char*)d_ws;
    size_t off = 0;
    auto alloc = [&](size_t bytes) -> void* {
        void* p = ws + off;
        off += (bytes + 255) & ~(size_t)255;
        return p;
    };
    const size_t BA = (size_t)B_DIM * A_DIM;
    unsigned short* Chi = (unsigned short*)alloc(BA * 2);            // 32 MiB
    unsigned short* Clo = (unsigned short*)alloc(BA * 2);            // 32 MiB
    float* Greg = (float*)alloc(BA * 4);                             // 64 MiB (aliased)
    float* qt = (float*)alloc(BA * 4);                               // 64 MiB (-> Xd in diff)
    unsigned short* Xhi = (unsigned short*)alloc((size_t)A_DIM * A_DIM * 2);  // 2 MiB
    unsigned short* Xlo = (unsigned short*)alloc((size_t)A_DIM * A_DIM * 2);  // 2 MiB
    float* Xf = (float*)alloc((size_t)A_DIM * A_DIM * 4);            // 4 MiB
    float* ynorm = (float*)alloc(B_DIM * 4);
    float* anrm  = (float*)alloc(A_DIM * 4);
    float* cxc   = (float*)alloc(B_DIM * 4);
    float* cq    = (float*)alloc(B_DIM * 4);
    float* num_amg = (float*)alloc(B_DIM * 4);
    float* num_cg  = (float*)alloc(B_DIM * 4);
    unsigned long long* keys = (unsigned long long*)alloc(2 * A_DIM * 8);  // K0 | K1
    float* scal = (float*)alloc(256);   // banks: [0..3] and [4..7]; s3 slots 3/7
    (void)ws_size; (void)in_sizes; (void)n_in; (void)out_size;

    // Greg aliases:
    float* an = Greg;                                                 // 3 MiB
    unsigned short* Anh = (unsigned short*)(an + (size_t)A_DIM * D_DIM);          // 1.5 MiB
    unsigned short* Anl = Anh + (size_t)A_DIM * D_DIM;                            // 1.5 MiB
    unsigned short* Ynh = Anl + (size_t)A_DIM * D_DIM;                            // 24 MiB
    unsigned short* Ynl = Ynh + (size_t)B_DIM * D_DIM;                            // 24 MiB
    float* XC = Greg;                                                 // nondiff phase
    float* R  = Greg;                                                 // diff phase (= XC - qt)
    float* Xd = qt;                                                   // diff phase
    unsigned short* AnTh = (unsigned short*)Greg;                     // post-diff recon
    unsigned short* AnTl = (unsigned short*)Greg + (size_t)D_DIM * A_DIM;

    // ---- setup ----
    ynorm_split_kernel<<<B_DIM, 256, 0, stream>>>(y, ynorm, Ynh, Ynl);
    anorm_kernel<<<A_DIM, 256, 0, stream>>>(atoms, an, anrm, Anh, Anl);
    gemm_xt<<<dim3(A_DIM / 128, A_DIM / 128), 256, 0, stream>>>(an, Xf);
    split_kernel<<<A_DIM * A_DIM / 4 / 256, 256, 0, stream>>>(Xf, Xhi, Xlo, A_DIM * A_DIM / 4);
    qt_mfma<<<1024, 256, 0, stream>>>(Ynh, Ynl, Anh, Anl, qt);
    fill_pair_kernel<<<(int)(BA / 4 / 256), 256, 0, stream>>>(Chi, Clo, BA / 4);
    init_kernel<<<B_DIM / 256, 256, 0, stream>>>(keys, num_amg, cxc, cq, scal);

    // ---- 30 nondiff steps ----
    for (int t = 0; t < 30; t++) {
        int cur = t & 1, prev = 1 - cur;
        unsigned long long* Kcur = keys + cur * A_DIM;
        unsigned long long* Kprev = keys + prev * A_DIM;
        unsigned long long* Knext = keys + ((t + 1) & 1) * A_DIM;
        float* sCur = scal + cur * 4;
        float* sPrev = scal + prev * 4;
        if ((t & 7) == 0) {
            // refresh (t even -> Kcur = K0, sCur = scal[0..3]; gemm resets scal[0..3])
            gemm256<0><<<256, 512, 0, stream>>>(Chi, Clo, Xhi, Xlo, qt,
                                                Kcur, cxc, cq, scal, nullptr, nullptr, XC);
        } else {
            fgrad<<<256, 256, 0, stream>>>(qt, Chi, Clo, XC, Xf, Kprev, Kcur,
                                           cxc, cq, num_amg, sPrev, sCur);
        }
        stats_kernel<<<A_DIM, 256, 0, stream>>>(Xf, Kcur, Chi, Clo, qt, cxc,
                                                num_amg, sCur, Knext);
        if (t == 7 || t == 15 || t == 23)
            ndupdate_c<<<B_DIM, 256, 0, stream>>>(Chi, Clo, Kcur, cxc, cq,
                                                  num_amg, sCur);
        if (t == 29)
            ndupdate_full<<<B_DIM, 256, 0, stream>>>(Chi, Clo, Kcur, cxc, cq,
                                                     num_amg, sCur, XC, Xf);
    }

    // ---- 10 diff steps: R-tracking + fused softmax/update ----
    rinit_kernel<<<(int)(BA / 4 / 256), 256, 0, stream>>>(XC, qt);   // R = XC - qt
    softmax_kernel<<<B_DIM, 256, 0, stream>>>(R, Chi, Clo, num_cg, &scal[3]);
    for (int t = 0; t < 10; t++) {
        float* s3cur = &scal[3 + (t & 1) * 4];
        float* s3next = &scal[3 + ((t + 1) & 1) * 4];
        gemm256<3><<<256, 512, 0, stream>>>(Chi, Clo, Xhi, Xlo, nullptr,
                                            nullptr, nullptr, nullptr, nullptr,
                                            Xd, s3cur, nullptr);
        if (t < 9)
            dupdate_fused<0><<<B_DIM, 256, 0, stream>>>(R, Xd, Chi, Clo, num_cg,
                                                        s3cur, s3next);
        else
            dupdate_fused<1><<<B_DIM, 256, 0, stream>>>(R, Xd, Chi, Clo, num_cg,
                                                        s3cur, nullptr);
    }

    // ---- recon ----
    atrans_split_kernel<<<D_DIM, 256, 0, stream>>>(atoms, anrm, AnTh, AnTl);
    mfma_recon<<<dim3(D_DIM / 128, B_DIM / 128), 256, 0, stream>>>(Chi, Clo, AnTh, AnTl,
                                                                   ynorm, out);
}

// Round 10
// 5369.179 us; speedup vs baseline: 1.5031x; 1.0430x over previous
//
#include <hip/hip_runtime.h>
#include <hip/hip_bf16.h>
#include <math.h>

// Problem constants
#define A_DIM 1024      // NB_ATOMS
#define D_DIM 768       // 3*16*16
#define B_DIM 16384     // BATCH
#define TEMP_C 100.0f
#define EPS_C 1e-8f

// Round 15: fgrad occupancy fix (the round-14 PMC-reconstruction shows fgrad
// ~85us x26 at ~3.7 TB/s with 1 wave/SIMD -> latency-bound).
//  - fgrad: 512 blocks x 512 threads (8 waves x 4 rows; LDS 64KB -> 2 blk/CU
//    -> 4 waves/SIMD). Ballot masks + Xf match-scan only when lam!=0;
//    lam==0 rows skip the c/XC stores (c'=c, XC'=XC exactly).
//  - everything else byte-identical to round 14 (verified 4.88e-4):
//    keys/scal double-buffer choreography, gemm256<0/3>, stats, ndupdate_c/
//    full, diff R-tracking with fused softmax/update.

typedef __attribute__((ext_vector_type(8))) short short8;
typedef __attribute__((ext_vector_type(4))) float f32x4;
#define MFMA16(a, b, c) __builtin_amdgcn_mfma_f32_16x16x32_bf16(a, b, c, 0, 0, 0)

typedef __attribute__((address_space(3))) unsigned char lds_byte;
typedef __attribute__((address_space(1))) const unsigned char g_byte;
__device__ __forceinline__ void async_copy16(const void* gptr, void* lptr) {
    __builtin_amdgcn_global_load_lds((g_byte*)gptr, (lds_byte*)lptr, 16, 0, 0);
}

#define SCHED0 __builtin_amdgcn_sched_barrier(0)
#define ASM_BAR asm volatile("s_barrier" ::: "memory")

// XCD-slab swizzle for 1024-block GEMM grids (qt_mfma only)
__device__ __forceinline__ void swz(int i, int& m0, int& n0) {
    int xcd = i & 7, j = i >> 3;
    m0 = ((xcd << 4) + (j >> 3)) << 7;
    n0 = (j & 7) << 7;
}

// ---------------- reductions ----------------

__device__ __forceinline__ float wave_sum(float v) {
#pragma unroll
    for (int m = 1; m < 64; m <<= 1) v += __shfl_xor(v, m);
    return v;
}
__device__ __forceinline__ float wave_max(float v) {
#pragma unroll
    for (int m = 1; m < 64; m <<= 1) v = fmaxf(v, __shfl_xor(v, m));
    return v;
}

__device__ __forceinline__ float block_reduce_sum(float v, float* red) {
    int t = threadIdx.x;
    v = wave_sum(v);
    if ((t & 63) == 0) red[t >> 6] = v;
    __syncthreads();
    float r = red[0] + red[1] + red[2] + red[3];
    __syncthreads();
    return r;
}

__device__ __forceinline__ float block_reduce_max(float v, float* red) {
    int t = threadIdx.x;
    v = wave_max(v);
    if ((t & 63) == 0) red[t >> 6] = v;
    __syncthreads();
    float r = fmaxf(fmaxf(red[0], red[1]), fmaxf(red[2], red[3]));
    __syncthreads();
    return r;
}

__device__ __forceinline__ void block_reduce_sum3(float& a, float& b, float& c, float* red) {
    int t = threadIdx.x;
    a = wave_sum(a);
    b = wave_sum(b);
    c = wave_sum(c);
    if ((t & 63) == 0) {
        int w = t >> 6;
        red[w] = a; red[4 + w] = b; red[8 + w] = c;
    }
    __syncthreads();
    a = red[0] + red[1] + red[2] + red[3];
    b = red[4] + red[5] + red[6] + red[7];
    c = red[8] + red[9] + red[10] + red[11];
    __syncthreads();
}

// ---------------- small helpers ----------------

__device__ __forceinline__ unsigned int fkey(float v) {
    unsigned int u = __float_as_uint(v);
    return u ^ ((u & 0x80000000u) ? 0xFFFFFFFFu : 0x80000000u);
}

__device__ __forceinline__ unsigned short f2bf(float x) {
    unsigned int u = __float_as_uint(x);
    return (unsigned short)((u + 0x7FFFu + ((u >> 16) & 1u)) >> 16);
}
__device__ __forceinline__ float bf2f(unsigned short h) {
    return __uint_as_float(((unsigned int)h) << 16);
}
__device__ __forceinline__ void split2(float x, unsigned short& hi, unsigned short& lo) {
    hi = f2bf(x);
    lo = f2bf(x - bf2f(hi));
}
__device__ __forceinline__ float clamp01(float x) {
    return fminf(fmaxf(x, 0.f), 1.f);
}

// ---------------- 128^2 MFMA building blocks (qt_mfma / mfma_recon) ----------------

__device__ __forceinline__ void stage_tile8(const unsigned short* gsrc, int stride, int k0,
                                            unsigned short* ltile, int lane) {
    int srow = lane >> 2;
    int scol = (lane & 3) * 8;
#pragma unroll
    for (int s = 0; s < 8; s++) {
        const unsigned short* src = gsrc + (size_t)(s * 16 + srow) * stride + k0 + scol;
        async_copy16(src, ltile + s * 512);
    }
}

// 3-product (pair x pair) K=32 step
__device__ __forceinline__ void mfma_k32(const unsigned short* lds, int wm, int wn, int lane,
                                         f32x4 acc[4][4]) {
    int frow = lane & 15, fk = (lane >> 4) * 8;
    short8 ah[4], al[4], bh[4], bl[4];
#pragma unroll
    for (int t = 0; t < 4; t++) {
        int ar = (wm * 64 + t * 16 + frow) * 32 + fk;
        ah[t] = *(const short8*)&lds[ar];
        al[t] = *(const short8*)&lds[4096 + ar];
        int br = (wn * 64 + t * 16 + frow) * 32 + fk;
        bh[t] = *(const short8*)&lds[8192 + br];
        bl[t] = *(const short8*)&lds[12288 + br];
    }
#pragma unroll
    for (int i = 0; i < 4; i++)
#pragma unroll
        for (int j = 0; j < 4; j++) {
            acc[i][j] = MFMA16(ah[i], bh[j], acc[i][j]);
            acc[i][j] = MFMA16(ah[i], bl[j], acc[i][j]);
            acc[i][j] = MFMA16(al[i], bh[j], acc[i][j]);
        }
}

// ---------------- 256^2 phase-split pipelined GEMM core (pair-A, 3-product) ----------------
// MODE 0: A = (Chi,Clo), nondiff epilogue (argmin/cxc/cq) + XC refresh write
// MODE 3: A = (d-hi,d-lo), epilogue Xd write + scal3 += sum(d * Xd)

template <int PART>
__device__ __forceinline__ void stage_part(unsigned short* buf,
                                           const unsigned short* Ahi,
                                           const unsigned short* Alo,
                                           const unsigned short* Xhi,
                                           const unsigned short* Xlo,
                                           int m0, int n0, int k0, int t) {
    constexpr int AHI = 0;
    constexpr int ALO = 8192;
    constexpr int BHI = 16384;
    constexpr int BLO = 24576;
    int r = t >> 2;
    int cg = (t & 3) ^ ((t >> 3) & 3);    // pre-swizzled source chunk
    size_t col = (size_t)k0 + cg * 8;
    if constexpr (PART == 0) {
        async_copy16(Ahi + (size_t)(m0 + r) * A_DIM + col,       buf + AHI + t * 8);
        async_copy16(Ahi + (size_t)(m0 + 128 + r) * A_DIM + col, buf + AHI + 4096 + t * 8);
    } else if constexpr (PART == 1) {
        async_copy16(Alo + (size_t)(m0 + r) * A_DIM + col,       buf + ALO + t * 8);
        async_copy16(Alo + (size_t)(m0 + 128 + r) * A_DIM + col, buf + ALO + 4096 + t * 8);
    } else if constexpr (PART == 2) {
        async_copy16(Xhi + (size_t)(n0 + r) * A_DIM + col,       buf + BHI + t * 8);
        async_copy16(Xhi + (size_t)(n0 + 128 + r) * A_DIM + col, buf + BHI + 4096 + t * 8);
    } else {
        async_copy16(Xlo + (size_t)(n0 + r) * A_DIM + col,       buf + BLO + t * 8);
        async_copy16(Xlo + (size_t)(n0 + 128 + r) * A_DIM + col, buf + BLO + 4096 + t * 8);
    }
}

__device__ __forceinline__ void mfma_mi3(short8 ah, short8 al,
                                         const short8 bh[4], const short8 bl[4],
                                         f32x4* accRow) {
#pragma unroll
    for (int j = 0; j < 4; j++) {
        accRow[j] = MFMA16(ah, bh[j], accRow[j]);
        accRow[j] = MFMA16(ah, bl[j], accRow[j]);
        accRow[j] = MFMA16(al, bh[j], accRow[j]);
    }
}

template <int MODE>
__global__ __launch_bounds__(512, 2) void gemm256(const unsigned short* __restrict__ Ahi,
                                                  const unsigned short* __restrict__ Alo,
                                                  const unsigned short* __restrict__ Xhi,
                                                  const unsigned short* __restrict__ Xlo,
                                                  const float* __restrict__ qt,
                                                  unsigned long long* __restrict__ keys,
                                                  float* __restrict__ cxc,
                                                  float* __restrict__ cq,
                                                  float* __restrict__ scal,
                                                  float* __restrict__ G,
                                                  float* __restrict__ scal3,
                                                  float* __restrict__ XC) {
    constexpr int BUFS = 32768;   // shorts per buffer (128 KiB total LDS)
    constexpr int AHI = 0;
    constexpr int ALO = 8192;
    constexpr int BHI = 16384;
    constexpr int BLO = 24576;
    __shared__ unsigned short lds[2 * BUFS];
    __shared__ float red[8];
    int tid = threadIdx.x;
    if (MODE == 0 && blockIdx.x == 0 && tid < 4) scal[tid] = 0.f;
    int w = tid >> 6, lane = tid & 63;
    int wm = w >> 2, wn = w & 3;          // 2 x 4 wave grid
    int bi = blockIdx.x;
    int xcd = bi & 7, bj = bi >> 3;
    int m0 = ((xcd << 3) + (bj >> 2)) << 8;
    int n0 = (bj & 3) << 8;

    f32x4 acc[8][4];
#pragma unroll
    for (int i = 0; i < 8; i++)
#pragma unroll
        for (int j = 0; j < 4; j++) acc[i][j] = f32x4{0.f, 0.f, 0.f, 0.f};

    int frow = lane & 15;
    int sw = ((lane >> 4) ^ ((frow >> 1) & 3)) * 8;   // read-side chunk swizzle

    stage_part<0>(lds, Ahi, Alo, Xhi, Xlo, m0, n0, 0, tid);
    stage_part<1>(lds, Ahi, Alo, Xhi, Xlo, m0, n0, 0, tid);
    stage_part<2>(lds, Ahi, Alo, Xhi, Xlo, m0, n0, 0, tid);
    stage_part<3>(lds, Ahi, Alo, Xhi, Xlo, m0, n0, 0, tid);

    int cur = 0;
    for (int ks = 0; ks < 32; ++ks) {
        unsigned short* rb = lds + cur * BUFS;
        unsigned short* wb = lds + (cur ^ 1) * BUFS;
        const bool pf = (ks < 31);
        const int k1 = (ks + 1) * 32;

        if (pf) {
            stage_part<0>(wb, Ahi, Alo, Xhi, Xlo, m0, n0, k1, tid);
            SCHED0;
            asm volatile("s_waitcnt vmcnt(2)" ::: "memory");
        } else {
            asm volatile("s_waitcnt vmcnt(0)" ::: "memory");
        }
        SCHED0; ASM_BAR; SCHED0;

        short8 bh[4], bl[4];
#pragma unroll
        for (int j = 0; j < 4; j++) {
            int br = wn * 64 + j * 16 + frow;
            bh[j] = *(const short8*)&rb[BHI + br * 32 + sw];
            bl[j] = *(const short8*)&rb[BLO + br * 32 + sw];
        }
        {
            int ar0 = wm * 128 + 0 * 16 + frow, ar1 = wm * 128 + 1 * 16 + frow;
            short8 a0h = *(const short8*)&rb[AHI + ar0 * 32 + sw];
            short8 a1h = *(const short8*)&rb[AHI + ar1 * 32 + sw];
            short8 a0l = *(const short8*)&rb[ALO + ar0 * 32 + sw];
            short8 a1l = *(const short8*)&rb[ALO + ar1 * 32 + sw];
            if (pf) stage_part<1>(wb, Ahi, Alo, Xhi, Xlo, m0, n0, k1, tid);
            SCHED0; ASM_BAR; SCHED0;
            asm volatile("s_waitcnt lgkmcnt(0)" ::: "memory"); SCHED0;
            __builtin_amdgcn_s_setprio(1);
            mfma_mi3(a0h, a0l, bh, bl, acc[0]);
            mfma_mi3(a1h, a1l, bh, bl, acc[1]);
            __builtin_amdgcn_s_setprio(0);
            SCHED0; ASM_BAR; SCHED0;
        }
#pragma unroll
        for (int ph = 1; ph < 4; ph++) {
            int mia = 2 * ph, mib = 2 * ph + 1;
            int ara = wm * 128 + mia * 16 + frow, arb = wm * 128 + mib * 16 + frow;
            short8 aah = *(const short8*)&rb[AHI + ara * 32 + sw];
            short8 abh = *(const short8*)&rb[AHI + arb * 32 + sw];
            short8 aal = *(const short8*)&rb[ALO + ara * 32 + sw];
            short8 abl = *(const short8*)&rb[ALO + arb * 32 + sw];
            if (pf) {
                if (ph == 1) stage_part<2>(wb, Ahi, Alo, Xhi, Xlo, m0, n0, k1, tid);
                if (ph == 2) stage_part<3>(wb, Ahi, Alo, Xhi, Xlo, m0, n0, k1, tid);
            }
            SCHED0; ASM_BAR; SCHED0;
            asm volatile("s_waitcnt lgkmcnt(0)" ::: "memory"); SCHED0;
            __builtin_amdgcn_s_setprio(1);
            mfma_mi3(aah, aal, bh, bl, acc[mia]);
            mfma_mi3(abh, abl, bh, bl, acc[mib]);
            __builtin_amdgcn_s_setprio(0);
            SCHED0; ASM_BAR; SCHED0;
        }
        cur ^= 1;
    }

    int crow = (lane >> 4) * 4, ccol = lane & 15;
    if constexpr (MODE == 0) {
        unsigned long long best[4] = {~0ULL, ~0ULL, ~0ULL, ~0ULL};
#pragma unroll
        for (int mi = 0; mi < 8; mi++)
#pragma unroll
            for (int r = 0; r < 4; r++) {
                int gm = m0 + wm * 128 + mi * 16 + crow + r;
                float pcx = 0.f, pcq = 0.f;
#pragma unroll
                for (int jj = 0; jj < 4; jj++) {
                    int gn = n0 + wn * 64 + jj * 16 + ccol;
                    size_t idx = (size_t)gm * A_DIM + gn;
                    float c = bf2f(Ahi[idx]) + bf2f(Alo[idx]);
                    float q = qt[idx];
                    float xc = acc[mi][jj][r];
                    XC[idx] = xc;               // refresh the tracked X@c
                    pcx += c * xc;
                    pcq += c * q;
                    unsigned long long key =
                        ((unsigned long long)fkey(xc - q) << 32) | (unsigned int)gm;
                    if (key < best[jj]) best[jj] = key;
                }
                for (int mm = 1; mm < 16; mm <<= 1) {
                    pcx += __shfl_xor(pcx, mm, 16);
                    pcq += __shfl_xor(pcq, mm, 16);
                }
                if (ccol == 0) {
                    atomicAdd(&cxc[gm], pcx);
                    atomicAdd(&cq[gm], pcq);
                }
            }
#pragma unroll
        for (int jj = 0; jj < 4; jj++) {
            int gn = n0 + wn * 64 + jj * 16 + ccol;
            unsigned long long o = __shfl_xor(best[jj], 16);
            if (o < best[jj]) best[jj] = o;
            o = __shfl_xor(best[jj], 32);
            if (o < best[jj]) best[jj] = o;
            if ((lane >> 4) == 0) atomicMin(&keys[gn], best[jj]);
        }
    } else {
        // MODE 3: Xd = acc -> G; denom partial = sum(d * Xd) -> scal3
        float part = 0.f;
#pragma unroll
        for (int mi = 0; mi < 8; mi++)
#pragma unroll
            for (int r = 0; r < 4; r++) {
                int gm = m0 + wm * 128 + mi * 16 + crow + r;
#pragma unroll
                for (int jj = 0; jj < 4; jj++) {
                    int gn = n0 + wn * 64 + jj * 16 + ccol;
                    size_t idx = (size_t)gm * A_DIM + gn;
                    float d = bf2f(Ahi[idx]) + bf2f(Alo[idx]);
                    float xd = acc[mi][jj][r];
                    G[idx] = xd;
                    part += xd * d;
                }
            }
        part = wave_sum(part);
        if (lane == 0) red[w] = part;
        __syncthreads();
        if (tid == 0) {
            float tot = red[0] + red[1] + red[2] + red[3] +
                        red[4] + red[5] + red[6] + red[7];
            atomicAdd(scal3, tot);
        }
    }
}

// ---------------- nondiff fused stream: update(t-1) + grad/argmin(t) ----------------
// Round 15: 512 blocks x 512 thr (8 waves x 4 rows each = 32 rows/block;
// 64KB lkeys -> 2 blocks/CU -> 4 waves/SIMD). Lam==0 rows skip the c/XC
// stores (exact no-op) and the ballot/match scan.
__global__ __launch_bounds__(512) void fgrad(const float* __restrict__ qt,
                                             unsigned short* __restrict__ Chi,
                                             unsigned short* __restrict__ Clo,
                                             float* __restrict__ XC,
                                             const float* __restrict__ Xf,
                                             const unsigned long long* __restrict__ Kprev,
                                             unsigned long long* __restrict__ Kcur,
                                             float* __restrict__ cxc,
                                             float* __restrict__ cq,
                                             float* __restrict__ num_amg,
                                             const float* __restrict__ scalPrev,
                                             float* __restrict__ scalCur) {
    __shared__ unsigned long long lkeys[8][1024];   // 64 KiB
    int tid = threadIdx.x;
    if (blockIdx.x == 0 && tid < 4) scalCur[tid] = 0.f;   // other blocks read scalPrev only
    int w = tid >> 6, lane = tid & 63;
    int b0 = blockIdx.x * 32;
    float den = scalPrev[0] + scalPrev[1] - 2.f * scalPrev[2] + EPS_C;

    unsigned int klow[16];
#pragma unroll
    for (int s = 0; s < 16; s++) klow[s] = (unsigned int)Kprev[lane + s * 64];

    unsigned long long best[16];
#pragma unroll
    for (int i = 0; i < 16; i++) best[i] = ~0ULL;

    for (int rr = 0; rr < 4; ++rr) {
        int b = b0 + w + rr * 8;
        float lam = clamp01((cxc[b] - cq[b] - num_amg[b]) / den);
        float om = 1.f - lam;
        const bool active = (lam != 0.f);    // wave-uniform

        unsigned short* hr = Chi + (size_t)b * A_DIM;
        unsigned short* lr = Clo + (size_t)b * A_DIM;
        float* xcr = XC + (size_t)b * A_DIM;
        const float* qr = qt + (size_t)b * A_DIM;
        float dx = 0.f, dq = 0.f;

        if (active) {
            unsigned long long mask[16];
#pragma unroll
            for (int s = 0; s < 16; s++) mask[s] = __ballot(klow[s] == (unsigned int)b);
#pragma unroll
            for (int ch = 0; ch < 4; ++ch) {
                int col = ch * 256 + lane * 4;
                ushort4 hv = *(const ushort4*)(hr + col);
                ushort4 lv = *(const ushort4*)(lr + col);
                float4 xv = *(const float4*)(xcr + col);
                float4 qv = *(const float4*)(qr + col);
                int sel = lane >> 4;
                unsigned long long mw =
                    (sel == 0) ? mask[ch * 4 + 0] :
                    (sel == 1) ? mask[ch * 4 + 1] :
                    (sel == 2) ? mask[ch * 4 + 2] : mask[ch * 4 + 3];
                unsigned int ind4 = (unsigned int)((mw >> ((lane & 15) * 4)) & 0xFULL);
                float c0 = om * (bf2f(hv.x) + bf2f(lv.x)) + ((ind4 & 1u) ? lam : 0.f);
                float c1 = om * (bf2f(hv.y) + bf2f(lv.y)) + ((ind4 & 2u) ? lam : 0.f);
                float c2 = om * (bf2f(hv.z) + bf2f(lv.z)) + ((ind4 & 4u) ? lam : 0.f);
                float c3 = om * (bf2f(hv.w) + bf2f(lv.w)) + ((ind4 & 8u) ? lam : 0.f);
                xv.x *= om; xv.y *= om; xv.z *= om; xv.w *= om;
#pragma unroll
                for (int s = 0; s < 16; s++) {
                    unsigned long long m = mask[s];
                    while (m) {   // wave-uniform
                        int a = __ffsll(m) - 1 + s * 64;
                        m &= m - 1;
                        float4 av = *(const float4*)(Xf + (size_t)a * A_DIM + col);
                        xv.x += lam * av.x; xv.y += lam * av.y;
                        xv.z += lam * av.z; xv.w += lam * av.w;
                    }
                }
                split2(c0, hv.x, lv.x);
                split2(c1, hv.y, lv.y);
                split2(c2, hv.z, lv.z);
                split2(c3, hv.w, lv.w);
                *(ushort4*)(hr + col) = hv;
                *(ushort4*)(lr + col) = lv;
                *(float4*)(xcr + col) = xv;
                float g0 = xv.x - qv.x, g1 = xv.y - qv.y, g2 = xv.z - qv.z, g3 = xv.w - qv.w;
                dx += c0 * xv.x + c1 * xv.y + c2 * xv.z + c3 * xv.w;
                dq += c0 * qv.x + c1 * qv.y + c2 * qv.z + c3 * qv.w;
                unsigned long long k0 = ((unsigned long long)fkey(g0) << 32) | (unsigned int)b;
                unsigned long long k1 = ((unsigned long long)fkey(g1) << 32) | (unsigned int)b;
                unsigned long long k2 = ((unsigned long long)fkey(g2) << 32) | (unsigned int)b;
                unsigned long long k3 = ((unsigned long long)fkey(g3) << 32) | (unsigned int)b;
                if (k0 < best[ch * 4 + 0]) best[ch * 4 + 0] = k0;
                if (k1 < best[ch * 4 + 1]) best[ch * 4 + 1] = k1;
                if (k2 < best[ch * 4 + 2]) best[ch * 4 + 2] = k2;
                if (k3 < best[ch * 4 + 3]) best[ch * 4 + 3] = k3;
            }
        } else {
            // lam == 0: c' = c, XC' = XC exactly -> no stores, no match scan
#pragma unroll
            for (int ch = 0; ch < 4; ++ch) {
                int col = ch * 256 + lane * 4;
                ushort4 hv = *(const ushort4*)(hr + col);
                ushort4 lv = *(const ushort4*)(lr + col);
                float4 xv = *(const float4*)(xcr + col);
                float4 qv = *(const float4*)(qr + col);
                float c0 = bf2f(hv.x) + bf2f(lv.x);
                float c1 = bf2f(hv.y) + bf2f(lv.y);
                float c2 = bf2f(hv.z) + bf2f(lv.z);
                float c3 = bf2f(hv.w) + bf2f(lv.w);
                float g0 = xv.x - qv.x, g1 = xv.y - qv.y, g2 = xv.z - qv.z, g3 = xv.w - qv.w;
                dx += c0 * xv.x + c1 * xv.y + c2 * xv.z + c3 * xv.w;
                dq += c0 * qv.x + c1 * qv.y + c2 * qv.z + c3 * qv.w;
                unsigned long long k0 = ((unsigned long long)fkey(g0) << 32) | (unsigned int)b;
                unsigned long long k1 = ((unsigned long long)fkey(g1) << 32) | (unsigned int)b;
                unsigned long long k2 = ((unsigned long long)fkey(g2) << 32) | (unsigned int)b;
                unsigned long long k3 = ((unsigned long long)fkey(g3) << 32) | (unsigned int)b;
                if (k0 < best[ch * 4 + 0]) best[ch * 4 + 0] = k0;
                if (k1 < best[ch * 4 + 1]) best[ch * 4 + 1] = k1;
                if (k2 < best[ch * 4 + 2]) best[ch * 4 + 2] = k2;
                if (k3 < best[ch * 4 + 3]) best[ch * 4 + 3] = k3;
            }
        }
        dx = wave_sum(dx);
        dq = wave_sum(dq);
        if (lane == 0) {
            cxc[b] = dx;          // row-owned overwrite (old value already consumed)
            cq[b] = dq;
            num_amg[b] = 0.f;     // reset for this iteration's stats atomics
        }
    }
#pragma unroll
    for (int ch = 0; ch < 4; ++ch)
#pragma unroll
        for (int j = 0; j < 4; ++j)
            lkeys[w][ch * 256 + lane * 4 + j] = best[ch * 4 + j];
    __syncthreads();
    for (int i = tid; i < 1024; i += 512) {
        unsigned long long v = lkeys[0][i];
        if (lkeys[1][i] < v) v = lkeys[1][i];
        if (lkeys[2][i] < v) v = lkeys[2][i];
        if (lkeys[3][i] < v) v = lkeys[3][i];
        if (lkeys[4][i] < v) v = lkeys[4][i];
        if (lkeys[5][i] < v) v = lkeys[5][i];
        if (lkeys[6][i] < v) v = lkeys[6][i];
        if (lkeys[7][i] < v) v = lkeys[7][i];
        atomicMin(&Kcur[i], v);
    }
}

// ---------------- setup kernels ----------------

__global__ __launch_bounds__(256) void ynorm_split_kernel(const float* __restrict__ y,
                                                          float* __restrict__ ynorm,
                                                          unsigned short* __restrict__ Ynh,
                                                          unsigned short* __restrict__ Ynl) {
    __shared__ float red[16];
    int b = blockIdx.x;
    const float* row = y + (size_t)b * D_DIM;
    float s = 0.f;
    for (int i = threadIdx.x; i < D_DIM; i += 256) s += fabsf(row[i]);
    float tot = block_reduce_sum(s, red);
    float inv = 1.f / tot;
    unsigned short* oh = Ynh + (size_t)b * D_DIM;
    unsigned short* ol = Ynl + (size_t)b * D_DIM;
    for (int i = threadIdx.x; i < D_DIM; i += 256) {
        unsigned short h, l;
        split2(row[i] * inv, h, l);
        oh[i] = h; ol[i] = l;
    }
    if (threadIdx.x == 0) ynorm[b] = tot;
}

__global__ __launch_bounds__(256) void anorm_kernel(const float* __restrict__ atoms,
                                                    float* __restrict__ an,
                                                    float* __restrict__ anrm,
                                                    unsigned short* __restrict__ Anh,
                                                    unsigned short* __restrict__ Anl) {
    __shared__ float red[16];
    int a = blockIdx.x;
    const float* row = atoms + (size_t)a * D_DIM;
    float s = 0.f;
    for (int i = threadIdx.x; i < D_DIM; i += 256) s += fabsf(row[i]);
    float tot = block_reduce_sum(s, red);
    float inv = 1.f / tot;
    for (int i = threadIdx.x; i < D_DIM; i += 256) {
        float v = row[i] * inv;
        an[(size_t)a * D_DIM + i] = v;
        unsigned short h, l;
        split2(v, h, l);
        Anh[(size_t)a * D_DIM + i] = h;
        Anl[(size_t)a * D_DIM + i] = l;
    }
    if (threadIdx.x == 0) anrm[a] = tot;
}

__global__ __launch_bounds__(256) void atrans_split_kernel(const float* __restrict__ atoms,
                                                           const float* __restrict__ anrm,
                                                           unsigned short* __restrict__ AnTh,
                                                           unsigned short* __restrict__ AnTl) {
    int n = blockIdx.x;
    for (int k = threadIdx.x; k < A_DIM; k += 256) {
        float v = atoms[(size_t)k * D_DIM + n] / anrm[k];
        unsigned short h, l;
        split2(v, h, l);
        AnTh[(size_t)n * A_DIM + k] = h;
        AnTl[(size_t)n * A_DIM + k] = l;
    }
}

__global__ __launch_bounds__(256) void split_kernel(const float* __restrict__ src,
                                                    unsigned short* __restrict__ hi,
                                                    unsigned short* __restrict__ lo,
                                                    int n4) {
    int i = blockIdx.x * 256 + threadIdx.x;
    if (i < n4) {
        float4 v = ((const float4*)src)[i];
        ushort4 h, l;
        split2(v.x, h.x, l.x);
        split2(v.y, h.y, l.y);
        split2(v.z, h.z, l.z);
        split2(v.w, h.w, l.w);
        ((ushort4*)hi)[i] = h;
        ((ushort4*)lo)[i] = l;
    }
}

__global__ __launch_bounds__(256) void fill_pair_kernel(unsigned short* __restrict__ Chi,
                                                        unsigned short* __restrict__ Clo,
                                                        size_t n4) {
    size_t i = (size_t)blockIdx.x * 256 + threadIdx.x;
    if (i < n4) {
        unsigned short h, l;
        split2(1.f / A_DIM, h, l);
        ((ushort4*)Chi)[i] = make_ushort4(h, h, h, h);
        ((ushort4*)Clo)[i] = make_ushort4(l, l, l, l);
    }
}

// fp32 vector GEMM, B transposed, setup only: X = an @ an^T
__global__ __launch_bounds__(256) void gemm_xt(const float* __restrict__ Aop,
                                               float* __restrict__ Cout) {
    const int LDT = 132;
    const int N = A_DIM, K = D_DIM;
    __shared__ float As[16 * LDT];
    __shared__ float Bs[16 * LDT];
    int m0 = blockIdx.y * 128, n0 = blockIdx.x * 128;
    int tid = threadIdx.x;
    int tx = tid & 15, ty = tid >> 4;
    float acc[8][8];
#pragma unroll
    for (int i = 0; i < 8; i++)
#pragma unroll
        for (int j = 0; j < 8; j++) acc[i][j] = 0.f;
    for (int k0 = 0; k0 < K; k0 += 16) {
#pragma unroll
        for (int s = 0; s < 2; s++) {
            int idx = tid + s * 256;
            int row = idx >> 2, kq = (idx & 3) * 4;
            float4 v = *(const float4*)(Aop + (size_t)(m0 + row) * K + k0 + kq);
            As[(kq + 0) * LDT + row] = v.x;
            As[(kq + 1) * LDT + row] = v.y;
            As[(kq + 2) * LDT + row] = v.z;
            As[(kq + 3) * LDT + row] = v.w;
        }
#pragma unroll
        for (int s = 0; s < 2; s++) {
            int idx = tid + s * 256;
            int row = idx >> 2, kq = (idx & 3) * 4;
            float4 v = *(const float4*)(Aop + (size_t)(n0 + row) * K + k0 + kq);
            Bs[(kq + 0) * LDT + row] = v.x;
            Bs[(kq + 1) * LDT + row] = v.y;
            Bs[(kq + 2) * LDT + row] = v.z;
            Bs[(kq + 3) * LDT + row] = v.w;
        }
        __syncthreads();
#pragma unroll
        for (int kk = 0; kk < 16; kk++) {
            float a[8], b[8];
            *(float4*)(a)     = *(const float4*)(As + kk * LDT + ty * 8);
            *(float4*)(a + 4) = *(const float4*)(As + kk * LDT + ty * 8 + 4);
            *(float4*)(b)     = *(const float4*)(Bs + kk * LDT + tx * 8);
            *(float4*)(b + 4) = *(const float4*)(Bs + kk * LDT + tx * 8 + 4);
#pragma unroll
            for (int i = 0; i < 8; i++)
#pragma unroll
                for (int j = 0; j < 8; j++) acc[i][j] = fmaf(a[i], b[j], acc[i][j]);
        }
        __syncthreads();
    }
#pragma unroll
    for (int i = 0; i < 8; i++) {
        int row = m0 + ty * 8 + i;
#pragma unroll
        for (int j = 0; j < 8; j += 4) {
            int col = n0 + tx * 8 + j;
            float4 v = make_float4(acc[i][j], acc[i][j + 1], acc[i][j + 2], acc[i][j + 3]);
            *(float4*)(Cout + (size_t)row * N + col) = v;
        }
    }
}

// qt = Yn @ An^T  (bf16x2 pair-pair MFMA, K=768), swizzled 1D grid of 1024
__global__ __launch_bounds__(256) void qt_mfma(const unsigned short* __restrict__ Ynh,
                                               const unsigned short* __restrict__ Ynl,
                                               const unsigned short* __restrict__ Anh,
                                               const unsigned short* __restrict__ Anl,
                                               float* __restrict__ qt) {
    __shared__ unsigned short lds[16384];
    int tid = threadIdx.x;
    int w = tid >> 6, lane = tid & 63;
    int wm = w >> 1, wn = w & 1;
    int m0, n0;
    swz(blockIdx.x, m0, n0);

    f32x4 acc[4][4];
#pragma unroll
    for (int i = 0; i < 4; i++)
#pragma unroll
        for (int j = 0; j < 4; j++) acc[i][j] = f32x4{0.f, 0.f, 0.f, 0.f};

    const unsigned short* gsrc;
    if (w == 0) gsrc = Ynh + (size_t)m0 * D_DIM;
    else if (w == 1) gsrc = Ynl + (size_t)m0 * D_DIM;
    else if (w == 2) gsrc = Anh + (size_t)n0 * D_DIM;
    else gsrc = Anl + (size_t)n0 * D_DIM;
    unsigned short* ltile = lds + w * 4096;
    for (int k0 = 0; k0 < D_DIM; k0 += 32) {
        stage_tile8(gsrc, D_DIM, k0, ltile, lane);
        __syncthreads();
        mfma_k32(lds, wm, wn, lane, acc);
        __syncthreads();
    }

    int crow = (lane >> 4) * 4, ccol = lane & 15;
#pragma unroll
    for (int i = 0; i < 4; i++) {
        int gm = m0 + wm * 64 + i * 16 + crow;
#pragma unroll
        for (int j = 0; j < 4; j++) {
            int gn = n0 + wn * 64 + j * 16 + ccol;
#pragma unroll
            for (int r = 0; r < 4; r++)
                qt[(size_t)(gm + r) * A_DIM + gn] = acc[i][j][r];
        }
    }
}

// ---------------- nondiff per-iteration kernels ----------------

// one-time init: both key banks, num_amg/cxc/cq, both scal banks
__global__ __launch_bounds__(256) void init_kernel(unsigned long long* __restrict__ keys,
                                                   float* __restrict__ num_amg,
                                                   float* __restrict__ cxc,
                                                   float* __restrict__ cq,
                                                   float* __restrict__ scal) {
    int i = blockIdx.x * 256 + threadIdx.x;
    num_amg[i] = 0.f;
    cxc[i] = 0.f;
    cq[i] = 0.f;
    if (i < 2 * A_DIM) keys[i] = ~0ULL;
    if (i < 8) scal[i] = 0.f;
}

// stats: block per atom a; reads Kcur, adds scalCur/num_amg; resets Knext[a].
__global__ __launch_bounds__(256) void stats_kernel(const float* __restrict__ Xf,
                                                    const unsigned long long* __restrict__ Kcur,
                                                    const unsigned short* __restrict__ Chi,
                                                    const unsigned short* __restrict__ Clo,
                                                    const float* __restrict__ qt,
                                                    const float* __restrict__ cxc,
                                                    float* __restrict__ num_amg,
                                                    float* __restrict__ scalCur,
                                                    unsigned long long* __restrict__ Knext) {
    __shared__ float red[16];
    int a = blockIdx.x;
    int ba = (int)(unsigned int)(Kcur[a] & 0xFFFFFFFFULL);
    const float* xr = Xf + (size_t)a * A_DIM;
    const unsigned short* ch = Chi + (size_t)ba * A_DIM;
    const unsigned short* cl = Clo + (size_t)ba * A_DIM;
    float ps = 0.f, xs = 0.f;
    for (int i = threadIdx.x; i < A_DIM; i += 256) {
        float xv = xr[i];
        if ((int)(unsigned int)(Kcur[i] & 0xFFFFFFFFULL) == ba) ps += xv;
        xs += xv * (bf2f(ch[i]) + bf2f(cl[i]));
    }
    float s1p = (threadIdx.x < 16) ? cxc[(a << 4) + threadIdx.x] : 0.f;
    block_reduce_sum3(ps, xs, s1p, red);
    if (threadIdx.x == 0) {
        atomicAdd(&scalCur[0], ps);
        atomicAdd(&scalCur[2], xs);
        atomicAdd(&scalCur[1], s1p);
        atomicAdd(&num_amg[ba], xs - qt[(size_t)ba * A_DIM + a]);
        Knext[a] = ~0ULL;     // reset other bank for next iteration's argmin
    }
}

// thin update before a refresh GEMM: c only (refresh rewrites XC exactly);
// resets cxc/cq/num_amg for the refresh's atomicAdds.
__global__ __launch_bounds__(256) void ndupdate_c(unsigned short* __restrict__ Chi,
                                                  unsigned short* __restrict__ Clo,
                                                  const unsigned long long* __restrict__ Kprev,
                                                  float* __restrict__ cxc,
                                                  float* __restrict__ cq,
                                                  float* __restrict__ num_amg,
                                                  const float* __restrict__ scalPrev) {
    int b = blockIdx.x;
    float den = scalPrev[0] + scalPrev[1] - 2.f * scalPrev[2] + EPS_C;
    float lam = clamp01((cxc[b] - cq[b] - num_amg[b]) / den);
    float om = 1.f - lam;
    int i = threadIdx.x;
    ushort4* h4 = (ushort4*)(Chi + (size_t)b * A_DIM);
    ushort4* l4 = (ushort4*)(Clo + (size_t)b * A_DIM);
    ushort4 h = h4[i], l = l4[i];
    int b0 = (int)(unsigned int)Kprev[i * 4 + 0];
    int b1 = (int)(unsigned int)Kprev[i * 4 + 1];
    int b2 = (int)(unsigned int)Kprev[i * 4 + 2];
    int b3 = (int)(unsigned int)Kprev[i * 4 + 3];
    float c0 = om * (bf2f(h.x) + bf2f(l.x)) + ((b0 == b) ? lam : 0.f);
    float c1 = om * (bf2f(h.y) + bf2f(l.y)) + ((b1 == b) ? lam : 0.f);
    float c2 = om * (bf2f(h.z) + bf2f(l.z)) + ((b2 == b) ? lam : 0.f);
    float c3 = om * (bf2f(h.w) + bf2f(l.w)) + ((b3 == b) ? lam : 0.f);
    split2(c0, h.x, l.x);
    split2(c1, h.y, l.y);
    split2(c2, h.z, l.z);
    split2(c3, h.w, l.w);
    h4[i] = h; l4[i] = l;
    __syncthreads();
    if (i == 0) {
        cxc[b] = 0.f;
        cq[b] = 0.f;
        num_amg[b] = 0.f;
    }
}

// full update after iter 29: c + XC recurrence (diff's rinit needs XC_30)
__global__ __launch_bounds__(256) void ndupdate_full(unsigned short* __restrict__ Chi,
                                                     unsigned short* __restrict__ Clo,
                                                     const unsigned long long* __restrict__ Kprev,
                                                     const float* __restrict__ cxc,
                                                     const float* __restrict__ cq,
                                                     const float* __restrict__ num_amg,
                                                     const float* __restrict__ scalPrev,
                                                     float* __restrict__ XC,
                                                     const float* __restrict__ Xf) {
    __shared__ int mlist[1024];
    __shared__ int mcount;
    int b = blockIdx.x;
    int i = threadIdx.x;
    if (i == 0) mcount = 0;
    float den = scalPrev[0] + scalPrev[1] - 2.f * scalPrev[2] + EPS_C;
    float lam = clamp01((cxc[b] - cq[b] - num_amg[b]) / den);
    float om = 1.f - lam;
    ushort4* h4 = (ushort4*)(Chi + (size_t)b * A_DIM);
    ushort4* l4 = (ushort4*)(Clo + (size_t)b * A_DIM);
    ushort4 h = h4[i], l = l4[i];
    int b0 = (int)(unsigned int)Kprev[i * 4 + 0];
    int b1 = (int)(unsigned int)Kprev[i * 4 + 1];
    int b2 = (int)(unsigned int)Kprev[i * 4 + 2];
    int b3 = (int)(unsigned int)Kprev[i * 4 + 3];
    float c0 = om * (bf2f(h.x) + bf2f(l.x)) + ((b0 == b) ? lam : 0.f);
    float c1 = om * (bf2f(h.y) + bf2f(l.y)) + ((b1 == b) ? lam : 0.f);
    float c2 = om * (bf2f(h.z) + bf2f(l.z)) + ((b2 == b) ? lam : 0.f);
    float c3 = om * (bf2f(h.w) + bf2f(l.w)) + ((b3 == b) ? lam : 0.f);
    split2(c0, h.x, l.x);
    split2(c1, h.y, l.y);
    split2(c2, h.z, l.z);
    split2(c3, h.w, l.w);
    h4[i] = h; l4[i] = l;
    __syncthreads();
    for (int a = i; a < A_DIM; a += 256)
        if ((int)(unsigned int)Kprev[a] == b) { int p = atomicAdd(&mcount, 1); mlist[p] = a; }
    __syncthreads();
    float4 xv = *(float4*)(XC + (size_t)b * A_DIM + i * 4);
    xv.x *= om; xv.y *= om; xv.z *= om; xv.w *= om;
    int mc = mcount;
    for (int m = 0; m < mc; m++) {
        float4 av = *(const float4*)(Xf + (size_t)mlist[m] * A_DIM + i * 4);
        xv.x += lam * av.x; xv.y += lam * av.y;
        xv.z += lam * av.z; xv.w += lam * av.w;
    }
    *(float4*)(XC + (size_t)b * A_DIM + i * 4) = xv;
}

// ---------------- diff-phase kernels ----------------

// R = XC - qt (in place in Greg), once at diff entry; qt becomes the Xd buffer.
__global__ __launch_bounds__(256) void rinit_kernel(float* __restrict__ XC,
                                                    const float* __restrict__ qt) {
    size_t i = (size_t)blockIdx.x * 256 + threadIdx.x;
    float4 x = ((const float4*)XC)[i];
    float4 q = ((const float4*)qt)[i];
    x.x -= q.x; x.y -= q.y; x.z -= q.z; x.w -= q.w;
    ((float4*)XC)[i] = x;
}

// one-time softmax at diff entry: d_0 = sm(R_0) - c_0, num_cg_0; resets scal3 slot0
__global__ __launch_bounds__(256) void softmax_kernel(const float* __restrict__ R,
                                                      unsigned short* __restrict__ Chi,
                                                      unsigned short* __restrict__ Clo,
                                                      float* __restrict__ num_cg,
                                                      float* __restrict__ scal3) {
    __shared__ float red[16];
    int b = blockIdx.x;
    int i = threadIdx.x;
    if (b == 0 && i == 0) *scal3 = 0.f;
    const float4* g4 = (const float4*)(R + (size_t)b * A_DIM);
    ushort4* h4 = (ushort4*)(Chi + (size_t)b * A_DIM);
    ushort4* l4 = (ushort4*)(Clo + (size_t)b * A_DIM);
    float4 g = g4[i];
    ushort4 h = h4[i], l = l4[i];
    float c0 = bf2f(h.x) + bf2f(l.x);
    float c1 = bf2f(h.y) + bf2f(l.y);
    float c2 = bf2f(h.z) + bf2f(l.z);
    float c3 = bf2f(h.w) + bf2f(l.w);
    float4 t = make_float4(-TEMP_C * g.x, -TEMP_C * g.y, -TEMP_C * g.z, -TEMP_C * g.w);
    float m = fmaxf(fmaxf(t.x, t.y), fmaxf(t.z, t.w));
    float M = block_reduce_max(m, red);
    float4 e = make_float4(expf(t.x - M), expf(t.y - M), expf(t.z - M), expf(t.w - M));
    float S = block_reduce_sum(e.x + e.y + e.z + e.w, red);
    float inv = 1.f / S;
    float4 sm = make_float4(e.x * inv, e.y * inv, e.z * inv, e.w * inv);
    float np = (c0 - sm.x) * g.x + (c1 - sm.y) * g.y + (c2 - sm.z) * g.z + (c3 - sm.w) * g.w;
    split2(sm.x - c0, h.x, l.x);
    split2(sm.y - c1, h.y, l.y);
    split2(sm.z - c2, h.z, l.z);
    split2(sm.w - c3, h.w, l.w);
    h4[i] = h; l4[i] = l;
    float nt = block_reduce_sum(np, red);
    if (i == 0) num_cg[b] = nt;
}

// fused diff update: sm_t from R_t -> lam -> c_{t+1} = sm_t - om*d_t;
// R_{t+1} = R_t + lam*Xd; if !LAST: sm_{t+1}, d_{t+1} -> Chi/Clo, num_{t+1};
// else write c_{t+1}. Resets the OTHER scal3 slot (s3next) for the next GEMM.
template <int LAST>
__global__ __launch_bounds__(256) void dupdate_fused(float* __restrict__ R,
                                                     const float* __restrict__ Xd,
                                                     unsigned short* __restrict__ Chi,
                                                     unsigned short* __restrict__ Clo,
                                                     float* __restrict__ num_cg,
                                                     const float* __restrict__ s3cur,
                                                     float* __restrict__ s3next) {
    __shared__ float red[16];
    int b = blockIdx.x;
    int i = threadIdx.x;
    if (!LAST && b == 0 && i == 0) *s3next = 0.f;
    float4* r4 = (float4*)(R + (size_t)b * A_DIM);
    float4 g = r4[i];
    // sm_t (bitwise-identical sequence to softmax_kernel)
    float4 t = make_float4(-TEMP_C * g.x, -TEMP_C * g.y, -TEMP_C * g.z, -TEMP_C * g.w);
    float m = fmaxf(fmaxf(t.x, t.y), fmaxf(t.z, t.w));
    float M = block_reduce_max(m, red);
    float4 e = make_float4(expf(t.x - M), expf(t.y - M), expf(t.z - M), expf(t.w - M));
    float S = block_reduce_sum(e.x + e.y + e.z + e.w, red);
    float inv = 1.f / S;
    float4 sm = make_float4(e.x * inv, e.y * inv, e.z * inv, e.w * inv);
    float den = *s3cur + EPS_C;
    float lam = clamp01(num_cg[b] / den);
    float om = 1.f - lam;
    ushort4* h4 = (ushort4*)(Chi + (size_t)b * A_DIM);
    ushort4* l4 = (ushort4*)(Clo + (size_t)b * A_DIM);
    ushort4 h = h4[i], l = l4[i];          // d_t
    float c0 = sm.x - om * (bf2f(h.x) + bf2f(l.x));
    float c1 = sm.y - om * (bf2f(h.y) + bf2f(l.y));
    float c2 = sm.z - om * (bf2f(h.z) + bf2f(l.z));
    float c3 = sm.w - om * (bf2f(h.w) + bf2f(l.w));
    float4 xd = ((const float4*)(Xd + (size_t)b * A_DIM))[i];
    g.x += lam * xd.x; g.y += lam * xd.y;
    g.z += lam * xd.z; g.w += lam * xd.w;
    r4[i] = g;                              // R_{t+1}
    if (LAST) {
        split2(c0, h.x, l.x);
        split2(c1, h.y, l.y);
        split2(c2, h.z, l.z);
        split2(c3, h.w, l.w);
        h4[i] = h; l4[i] = l;
    } else {
        // sm_{t+1} from R_{t+1}
        float4 t2 = make_float4(-TEMP_C * g.x, -TEMP_C * g.y, -TEMP_C * g.z, -TEMP_C * g.w);
        float m2 = fmaxf(fmaxf(t2.x, t2.y), fmaxf(t2.z, t2.w));
        float M2 = block_reduce_max(m2, red);
        float4 e2 = make_float4(expf(t2.x - M2), expf(t2.y - M2),
                                expf(t2.z - M2), expf(t2.w - M2));
        float S2 = block_reduce_sum(e2.x + e2.y + e2.z + e2.w, red);
        float inv2 = 1.f / S2;
        float4 sm2 = make_float4(e2.x * inv2, e2.y * inv2, e2.z * inv2, e2.w * inv2);
        float np = (c0 - sm2.x) * g.x + (c1 - sm2.y) * g.y +
                   (c2 - sm2.z) * g.z + (c3 - sm2.w) * g.w;
        split2(sm2.x - c0, h.x, l.x);
        split2(sm2.y - c1, h.y, l.y);
        split2(sm2.z - c2, h.z, l.z);
        split2(sm2.w - c3, h.w, l.w);
        h4[i] = h; l4[i] = l;               // d_{t+1}
        float nt = block_reduce_sum(np, red);
        if (i == 0) num_cg[b] = nt;
    }
}

// recon: out[b, n] = (c_b . anT[:,n]) * ynorm[b]
__global__ __launch_bounds__(256) void mfma_recon(const unsigned short* __restrict__ Chi,
                                                  const unsigned short* __restrict__ Clo,
                                                  const unsigned short* __restrict__ AnTh,
                                                  const unsigned short* __restrict__ AnTl,
                                                  const float* __restrict__ ynorm,
                                                  float* __restrict__ out) {
    __shared__ unsigned short lds[16384];
    int tid = threadIdx.x;
    int w = tid >> 6, lane = tid & 63;
    int wm = w >> 1, wn = w & 1;
    int m0 = blockIdx.y * 128, n0 = blockIdx.x * 128;

    f32x4 acc[4][4];
#pragma unroll
    for (int i = 0; i < 4; i++)
#pragma unroll
        for (int j = 0; j < 4; j++) acc[i][j] = f32x4{0.f, 0.f, 0.f, 0.f};

    const unsigned short* gsrc;
    if (w == 0) gsrc = Chi + (size_t)m0 * A_DIM;
    else if (w == 1) gsrc = Clo + (size_t)m0 * A_DIM;
    else if (w == 2) gsrc = AnTh + (size_t)n0 * A_DIM;
    else gsrc = AnTl + (size_t)n0 * A_DIM;
    unsigned short* ltile = lds + w * 4096;
    for (int k0 = 0; k0 < A_DIM; k0 += 32) {
        stage_tile8(gsrc, A_DIM, k0, ltile, lane);
        __syncthreads();
        mfma_k32(lds, wm, wn, lane, acc);
        __syncthreads();
    }

    int crow = (lane >> 4) * 4, ccol = lane & 15;
#pragma unroll
    for (int i = 0; i < 4; i++) {
        int gm = m0 + wm * 64 + i * 16 + crow;
#pragma unroll
        for (int j = 0; j < 4; j++) {
            int gn = n0 + wn * 64 + j * 16 + ccol;
#pragma unroll
            for (int r = 0; r < 4; r++)
                out[(size_t)(gm + r) * D_DIM + gn] = acc[i][j][r] * ynorm[gm + r];
        }
    }
}

// ---------------- host launch ----------------

extern "C" void kernel_launch(void* const* d_in, const int* in_sizes, int n_in,
                              void* d_out, int out_size, void* d_ws, size_t ws_size,
                              hipStream_t stream) {
    const float* y = (const float*)d_in[0];      // [B, 768]
    const float* atoms = (const float*)d_in[1];  // [A, 768]
    float* out = (float*)d_out;                  // [B, 768]

    char* ws = (char*)d_ws;
    size_t off = 0;
    auto alloc = [&](size_t bytes) -> void* {
        void* p = ws + off;
        off += (bytes + 255) & ~(size_t)255;
        return p;
    };
    const size_t BA = (size_t)B_DIM * A_DIM;
    unsigned short* Chi = (unsigned short*)alloc(BA * 2);            // 32 MiB
    unsigned short* Clo = (unsigned short*)alloc(BA * 2);            // 32 MiB
    float* Greg = (float*)alloc(BA * 4);                             // 64 MiB (aliased)
    float* qt = (float*)alloc(BA * 4);                               // 64 MiB (-> Xd in diff)
    unsigned short* Xhi = (unsigned short*)alloc((size_t)A_DIM * A_DIM * 2);  // 2 MiB
    unsigned short* Xlo = (unsigned short*)alloc((size_t)A_DIM * A_DIM * 2);  // 2 MiB
    float* Xf = (float*)alloc((size_t)A_DIM * A_DIM * 4);            // 4 MiB
    float* ynorm = (float*)alloc(B_DIM * 4);
    float* anrm  = (float*)alloc(A_DIM * 4);
    float* cxc   = (float*)alloc(B_DIM * 4);
    float* cq    = (float*)alloc(B_DIM * 4);
    float* num_amg = (float*)alloc(B_DIM * 4);
    float* num_cg  = (float*)alloc(B_DIM * 4);
    unsigned long long* keys = (unsigned long long*)alloc(2 * A_DIM * 8);  // K0 | K1
    float* scal = (float*)alloc(256);   // banks: [0..3] and [4..7]; s3 slots 3/7
    (void)ws_size; (void)in_sizes; (void)n_in; (void)out_size;

    // Greg aliases:
    float* an = Greg;                                                 // 3 MiB
    unsigned short* Anh = (unsigned short*)(an + (size_t)A_DIM * D_DIM);          // 1.5 MiB
    unsigned short* Anl = Anh + (size_t)A_DIM * D_DIM;                            // 1.5 MiB
    unsigned short* Ynh = Anl + (size_t)A_DIM * D_DIM;                            // 24 MiB
    unsigned short* Ynl = Ynh + (size_t)B_DIM * D_DIM;                            // 24 MiB
    float* XC = Greg;                                                 // nondiff phase
    float* R  = Greg;                                                 // diff phase (= XC - qt)
    float* Xd = qt;                                                   // diff phase
    unsigned short* AnTh = (unsigned short*)Greg;                     // post-diff recon
    unsigned short* AnTl = (unsigned short*)Greg + (size_t)D_DIM * A_DIM;

    // ---- setup ----
    ynorm_split_kernel<<<B_DIM, 256, 0, stream>>>(y, ynorm, Ynh, Ynl);
    anorm_kernel<<<A_DIM, 256, 0, stream>>>(atoms, an, anrm, Anh, Anl);
    gemm_xt<<<dim3(A_DIM / 128, A_DIM / 128), 256, 0, stream>>>(an, Xf);
    split_kernel<<<A_DIM * A_DIM / 4 / 256, 256, 0, stream>>>(Xf, Xhi, Xlo, A_DIM * A_DIM / 4);
    qt_mfma<<<1024, 256, 0, stream>>>(Ynh, Ynl, Anh, Anl, qt);
    fill_pair_kernel<<<(int)(BA / 4 / 256), 256, 0, stream>>>(Chi, Clo, BA / 4);
    init_kernel<<<B_DIM / 256, 256, 0, stream>>>(keys, num_amg, cxc, cq, scal);

    // ---- 30 nondiff steps ----
    for (int t = 0; t < 30; t++) {
        int cur = t & 1, prev = 1 - cur;
        unsigned long long* Kcur = keys + cur * A_DIM;
        unsigned long long* Kprev = keys + prev * A_DIM;
        unsigned long long* Knext = keys + ((t + 1) & 1) * A_DIM;
        float* sCur = scal + cur * 4;
        float* sPrev = scal + prev * 4;
        if ((t & 7) == 0) {
            // refresh (t even -> Kcur = K0, sCur = scal[0..3]; gemm resets scal[0..3])
            gemm256<0><<<256, 512, 0, stream>>>(Chi, Clo, Xhi, Xlo, qt,
                                                Kcur, cxc, cq, scal, nullptr, nullptr, XC);
        } else {
            fgrad<<<512, 512, 0, stream>>>(qt, Chi, Clo, XC, Xf, Kprev, Kcur,
                                           cxc, cq, num_amg, sPrev, sCur);
        }
        stats_kernel<<<A_DIM, 256, 0, stream>>>(Xf, Kcur, Chi, Clo, qt, cxc,
                                                num_amg, sCur, Knext);
        if (t == 7 || t == 15 || t == 23)
            ndupdate_c<<<B_DIM, 256, 0, stream>>>(Chi, Clo, Kcur, cxc, cq,
                                                  num_amg, sCur);
        if (t == 29)
            ndupdate_full<<<B_DIM, 256, 0, stream>>>(Chi, Clo, Kcur, cxc, cq,
                                                     num_amg, sCur, XC, Xf);
    }

    // ---- 10 diff steps: R-tracking + fused softmax/update ----
    rinit_kernel<<<(int)(BA / 4 / 256), 256, 0, stream>>>(XC, qt);   // R = XC - qt
    softmax_kernel<<<B_DIM, 256, 0, stream>>>(R, Chi, Clo, num_cg, &scal[3]);
    for (int t = 0; t < 10; t++) {
        float* s3cur = &scal[3 + (t & 1) * 4];
        float* s3next = &scal[3 + ((t + 1) & 1) * 4];
        gemm256<3><<<256, 512, 0, stream>>>(Chi, Clo, Xhi, Xlo, nullptr,
                                            nullptr, nullptr, nullptr, nullptr,
                                            Xd, s3cur, nullptr);
        if (t < 9)
            dupdate_fused<0><<<B_DIM, 256, 0, stream>>>(R, Xd, Chi, Clo, num_cg,
                                                        s3cur, s3next);
        else
            dupdate_fused<1><<<B_DIM, 256, 0, stream>>>(R, Xd, Chi, Clo, num_cg,
                                                        s3cur, nullptr);
    }

    // ---- recon ----
    atrans_split_kernel<<<D_DIM, 256, 0, stream>>>(atoms, anrm, AnTh, AnTl);
    mfma_recon<<<dim3(D_DIM / 128, B_DIM / 128), 256, 0, stream>>>(Chi, Clo, AnTh, AnTl,
                                                                   ynorm, out);
}

// Round 11
// 5030.094 us; speedup vs baseline: 1.6044x; 1.0674x over previous
//
#include <hip/hip_runtime.h>
#include <hip/hip_bf16.h>
#include <math.h>

// Problem constants
#define A_DIM 1024      // NB_ATOMS
#define D_DIM 768       // 3*16*16
#define B_DIM 16384     // BATCH
#define TEMP_C 100.0f
#define EPS_C 1e-8f

// Round 16: G-tracking + refresh thinning.
//  - Track G = X@c - qt (the grad) instead of XC in the nondiff phase.
//    Algebra (exact): cxc-cq = c.G -> lam numerator needs NO qt read;
//    cq recurrence cq' = (1-lam)cq + lam*sum_{matched a} qt[b,a] (sparse);
//    G' = (1-lam)G + lam*T - lam*qt_row == XC' - qt exactly. lam==0 rows
//    read only c+G. Refresh GEMM epilogue stores xc-q; ndupdate_full gains
//    the -lam*qt term; rinit DELETED (diff's R is G's buffer).
//  - Refreshes thinned to t in {0,16} (windows 15/13 iters; diff already runs
//    10 tracked iters refresh-free, bit-identical). ndupdate_c only at t=15.
//  - fgrad geometry unchanged from round 15 (512x512, 8 waves x 4 rows,
//    lam==0 skip). gemm256 schedule, stats, diff fused path unchanged.

typedef __attribute__((ext_vector_type(8))) short short8;
typedef __attribute__((ext_vector_type(4))) float f32x4;
#define MFMA16(a, b, c) __builtin_amdgcn_mfma_f32_16x16x32_bf16(a, b, c, 0, 0, 0)

typedef __attribute__((address_space(3))) unsigned char lds_byte;
typedef __attribute__((address_space(1))) const unsigned char g_byte;
__device__ __forceinline__ void async_copy16(const void* gptr, void* lptr) {
    __builtin_amdgcn_global_load_lds((g_byte*)gptr, (lds_byte*)lptr, 16, 0, 0);
}

#define SCHED0 __builtin_amdgcn_sched_barrier(0)
#define ASM_BAR asm volatile("s_barrier" ::: "memory")

// XCD-slab swizzle for 1024-block GEMM grids (qt_mfma only)
__device__ __forceinline__ void swz(int i, int& m0, int& n0) {
    int xcd = i & 7, j = i >> 3;
    m0 = ((xcd << 4) + (j >> 3)) << 7;
    n0 = (j & 7) << 7;
}

// ---------------- reductions ----------------

__device__ __forceinline__ float wave_sum(float v) {
#pragma unroll
    for (int m = 1; m < 64; m <<= 1) v += __shfl_xor(v, m);
    return v;
}
__device__ __forceinline__ float wave_max(float v) {
#pragma unroll
    for (int m = 1; m < 64; m <<= 1) v = fmaxf(v, __shfl_xor(v, m));
    return v;
}

__device__ __forceinline__ float block_reduce_sum(float v, float* red) {
    int t = threadIdx.x;
    v = wave_sum(v);
    if ((t & 63) == 0) red[t >> 6] = v;
    __syncthreads();
    float r = red[0] + red[1] + red[2] + red[3];
    __syncthreads();
    return r;
}

__device__ __forceinline__ float block_reduce_max(float v, float* red) {
    int t = threadIdx.x;
    v = wave_max(v);
    if ((t & 63) == 0) red[t >> 6] = v;
    __syncthreads();
    float r = fmaxf(fmaxf(red[0], red[1]), fmaxf(red[2], red[3]));
    __syncthreads();
    return r;
}

__device__ __forceinline__ void block_reduce_sum3(float& a, float& b, float& c, float* red) {
    int t = threadIdx.x;
    a = wave_sum(a);
    b = wave_sum(b);
    c = wave_sum(c);
    if ((t & 63) == 0) {
        int w = t >> 6;
        red[w] = a; red[4 + w] = b; red[8 + w] = c;
    }
    __syncthreads();
    a = red[0] + red[1] + red[2] + red[3];
    b = red[4] + red[5] + red[6] + red[7];
    c = red[8] + red[9] + red[10] + red[11];
    __syncthreads();
}

// ---------------- small helpers ----------------

__device__ __forceinline__ unsigned int fkey(float v) {
    unsigned int u = __float_as_uint(v);
    return u ^ ((u & 0x80000000u) ? 0xFFFFFFFFu : 0x80000000u);
}

__device__ __forceinline__ unsigned short f2bf(float x) {
    unsigned int u = __float_as_uint(x);
    return (unsigned short)((u + 0x7FFFu + ((u >> 16) & 1u)) >> 16);
}
__device__ __forceinline__ float bf2f(unsigned short h) {
    return __uint_as_float(((unsigned int)h) << 16);
}
__device__ __forceinline__ void split2(float x, unsigned short& hi, unsigned short& lo) {
    hi = f2bf(x);
    lo = f2bf(x - bf2f(hi));
}
__device__ __forceinline__ float clamp01(float x) {
    return fminf(fmaxf(x, 0.f), 1.f);
}

// ---------------- 128^2 MFMA building blocks (qt_mfma / mfma_recon) ----------------

__device__ __forceinline__ void stage_tile8(const unsigned short* gsrc, int stride, int k0,
                                            unsigned short* ltile, int lane) {
    int srow = lane >> 2;
    int scol = (lane & 3) * 8;
#pragma unroll
    for (int s = 0; s < 8; s++) {
        const unsigned short* src = gsrc + (size_t)(s * 16 + srow) * stride + k0 + scol;
        async_copy16(src, ltile + s * 512);
    }
}

// 3-product (pair x pair) K=32 step
__device__ __forceinline__ void mfma_k32(const unsigned short* lds, int wm, int wn, int lane,
                                         f32x4 acc[4][4]) {
    int frow = lane & 15, fk = (lane >> 4) * 8;
    short8 ah[4], al[4], bh[4], bl[4];
#pragma unroll
    for (int t = 0; t < 4; t++) {
        int ar = (wm * 64 + t * 16 + frow) * 32 + fk;
        ah[t] = *(const short8*)&lds[ar];
        al[t] = *(const short8*)&lds[4096 + ar];
        int br = (wn * 64 + t * 16 + frow) * 32 + fk;
        bh[t] = *(const short8*)&lds[8192 + br];
        bl[t] = *(const short8*)&lds[12288 + br];
    }
#pragma unroll
    for (int i = 0; i < 4; i++)
#pragma unroll
        for (int j = 0; j < 4; j++) {
            acc[i][j] = MFMA16(ah[i], bh[j], acc[i][j]);
            acc[i][j] = MFMA16(ah[i], bl[j], acc[i][j]);
            acc[i][j] = MFMA16(al[i], bh[j], acc[i][j]);
        }
}

// ---------------- 256^2 phase-split pipelined GEMM core (pair-A, 3-product) ----------------
// MODE 0: A = (Chi,Clo), nondiff epilogue (argmin/cxc/cq) + G refresh (xc - qt)
// MODE 3: A = (d-hi,d-lo), epilogue Xd write + scal3 += sum(d * Xd)

template <int PART>
__device__ __forceinline__ void stage_part(unsigned short* buf,
                                           const unsigned short* Ahi,
                                           const unsigned short* Alo,
                                           const unsigned short* Xhi,
                                           const unsigned short* Xlo,
                                           int m0, int n0, int k0, int t) {
    constexpr int AHI = 0;
    constexpr int ALO = 8192;
    constexpr int BHI = 16384;
    constexpr int BLO = 24576;
    int r = t >> 2;
    int cg = (t & 3) ^ ((t >> 3) & 3);    // pre-swizzled source chunk
    size_t col = (size_t)k0 + cg * 8;
    if constexpr (PART == 0) {
        async_copy16(Ahi + (size_t)(m0 + r) * A_DIM + col,       buf + AHI + t * 8);
        async_copy16(Ahi + (size_t)(m0 + 128 + r) * A_DIM + col, buf + AHI + 4096 + t * 8);
    } else if constexpr (PART == 1) {
        async_copy16(Alo + (size_t)(m0 + r) * A_DIM + col,       buf + ALO + t * 8);
        async_copy16(Alo + (size_t)(m0 + 128 + r) * A_DIM + col, buf + ALO + 4096 + t * 8);
    } else if constexpr (PART == 2) {
        async_copy16(Xhi + (size_t)(n0 + r) * A_DIM + col,       buf + BHI + t * 8);
        async_copy16(Xhi + (size_t)(n0 + 128 + r) * A_DIM + col, buf + BHI + 4096 + t * 8);
    } else {
        async_copy16(Xlo + (size_t)(n0 + r) * A_DIM + col,       buf + BLO + t * 8);
        async_copy16(Xlo + (size_t)(n0 + 128 + r) * A_DIM + col, buf + BLO + 4096 + t * 8);
    }
}

__device__ __forceinline__ void mfma_mi3(short8 ah, short8 al,
                                         const short8 bh[4], const short8 bl[4],
                                         f32x4* accRow) {
#pragma unroll
    for (int j = 0; j < 4; j++) {
        accRow[j] = MFMA16(ah, bh[j], accRow[j]);
        accRow[j] = MFMA16(ah, bl[j], accRow[j]);
        accRow[j] = MFMA16(al, bh[j], accRow[j]);
    }
}

template <int MODE>
__global__ __launch_bounds__(512, 2) void gemm256(const unsigned short* __restrict__ Ahi,
                                                  const unsigned short* __restrict__ Alo,
                                                  const unsigned short* __restrict__ Xhi,
                                                  const unsigned short* __restrict__ Xlo,
                                                  const float* __restrict__ qt,
                                                  unsigned long long* __restrict__ keys,
                                                  float* __restrict__ cxc,
                                                  float* __restrict__ cq,
                                                  float* __restrict__ scal,
                                                  float* __restrict__ G,
                                                  float* __restrict__ scal3,
                                                  float* __restrict__ Gout) {
    constexpr int BUFS = 32768;   // shorts per buffer (128 KiB total LDS)
    constexpr int AHI = 0;
    constexpr int ALO = 8192;
    constexpr int BHI = 16384;
    constexpr int BLO = 24576;
    __shared__ unsigned short lds[2 * BUFS];
    __shared__ float red[8];
    int tid = threadIdx.x;
    if (MODE == 0 && blockIdx.x == 0 && tid < 4) scal[tid] = 0.f;
    int w = tid >> 6, lane = tid & 63;
    int wm = w >> 2, wn = w & 3;          // 2 x 4 wave grid
    int bi = blockIdx.x;
    int xcd = bi & 7, bj = bi >> 3;
    int m0 = ((xcd << 3) + (bj >> 2)) << 8;
    int n0 = (bj & 3) << 8;

    f32x4 acc[8][4];
#pragma unroll
    for (int i = 0; i < 8; i++)
#pragma unroll
        for (int j = 0; j < 4; j++) acc[i][j] = f32x4{0.f, 0.f, 0.f, 0.f};

    int frow = lane & 15;
    int sw = ((lane >> 4) ^ ((frow >> 1) & 3)) * 8;   // read-side chunk swizzle

    stage_part<0>(lds, Ahi, Alo, Xhi, Xlo, m0, n0, 0, tid);
    stage_part<1>(lds, Ahi, Alo, Xhi, Xlo, m0, n0, 0, tid);
    stage_part<2>(lds, Ahi, Alo, Xhi, Xlo, m0, n0, 0, tid);
    stage_part<3>(lds, Ahi, Alo, Xhi, Xlo, m0, n0, 0, tid);

    int cur = 0;
    for (int ks = 0; ks < 32; ++ks) {
        unsigned short* rb = lds + cur * BUFS;
        unsigned short* wb = lds + (cur ^ 1) * BUFS;
        const bool pf = (ks < 31);
        const int k1 = (ks + 1) * 32;

        if (pf) {
            stage_part<0>(wb, Ahi, Alo, Xhi, Xlo, m0, n0, k1, tid);
            SCHED0;
            asm volatile("s_waitcnt vmcnt(2)" ::: "memory");
        } else {
            asm volatile("s_waitcnt vmcnt(0)" ::: "memory");
        }
        SCHED0; ASM_BAR; SCHED0;

        short8 bh[4], bl[4];
#pragma unroll
        for (int j = 0; j < 4; j++) {
            int br = wn * 64 + j * 16 + frow;
            bh[j] = *(const short8*)&rb[BHI + br * 32 + sw];
            bl[j] = *(const short8*)&rb[BLO + br * 32 + sw];
        }
        {
            int ar0 = wm * 128 + 0 * 16 + frow, ar1 = wm * 128 + 1 * 16 + frow;
            short8 a0h = *(const short8*)&rb[AHI + ar0 * 32 + sw];
            short8 a1h = *(const short8*)&rb[AHI + ar1 * 32 + sw];
            short8 a0l = *(const short8*)&rb[ALO + ar0 * 32 + sw];
            short8 a1l = *(const short8*)&rb[ALO + ar1 * 32 + sw];
            if (pf) stage_part<1>(wb, Ahi, Alo, Xhi, Xlo, m0, n0, k1, tid);
            SCHED0; ASM_BAR; SCHED0;
            asm volatile("s_waitcnt lgkmcnt(0)" ::: "memory"); SCHED0;
            __builtin_amdgcn_s_setprio(1);
            mfma_mi3(a0h, a0l, bh, bl, acc[0]);
            mfma_mi3(a1h, a1l, bh, bl, acc[1]);
            __builtin_amdgcn_s_setprio(0);
            SCHED0; ASM_BAR; SCHED0;
        }
#pragma unroll
        for (int ph = 1; ph < 4; ph++) {
            int mia = 2 * ph, mib = 2 * ph + 1;
            int ara = wm * 128 + mia * 16 + frow, arb = wm * 128 + mib * 16 + frow;
            short8 aah = *(const short8*)&rb[AHI + ara * 32 + sw];
            short8 abh = *(const short8*)&rb[AHI + arb * 32 + sw];
            short8 aal = *(const short8*)&rb[ALO + ara * 32 + sw];
            short8 abl = *(const short8*)&rb[ALO + arb * 32 + sw];
            if (pf) {
                if (ph == 1) stage_part<2>(wb, Ahi, Alo, Xhi, Xlo, m0, n0, k1, tid);
                if (ph == 2) stage_part<3>(wb, Ahi, Alo, Xhi, Xlo, m0, n0, k1, tid);
            }
            SCHED0; ASM_BAR; SCHED0;
            asm volatile("s_waitcnt lgkmcnt(0)" ::: "memory"); SCHED0;
            __builtin_amdgcn_s_setprio(1);
            mfma_mi3(aah, aal, bh, bl, acc[mia]);
            mfma_mi3(abh, abl, bh, bl, acc[mib]);
            __builtin_amdgcn_s_setprio(0);
            SCHED0; ASM_BAR; SCHED0;
        }
        cur ^= 1;
    }

    int crow = (lane >> 4) * 4, ccol = lane & 15;
    if constexpr (MODE == 0) {
        unsigned long long best[4] = {~0ULL, ~0ULL, ~0ULL, ~0ULL};
#pragma unroll
        for (int mi = 0; mi < 8; mi++)
#pragma unroll
            for (int r = 0; r < 4; r++) {
                int gm = m0 + wm * 128 + mi * 16 + crow + r;
                float pcx = 0.f, pcq = 0.f;
#pragma unroll
                for (int jj = 0; jj < 4; jj++) {
                    int gn = n0 + wn * 64 + jj * 16 + ccol;
                    size_t idx = (size_t)gm * A_DIM + gn;
                    float c = bf2f(Ahi[idx]) + bf2f(Alo[idx]);
                    float q = qt[idx];
                    float xc = acc[mi][jj][r];
                    float g = xc - q;
                    Gout[idx] = g;              // refresh the tracked grad G
                    pcx += c * xc;
                    pcq += c * q;
                    unsigned long long key =
                        ((unsigned long long)fkey(g) << 32) | (unsigned int)gm;
                    if (key < best[jj]) best[jj] = key;
                }
                for (int mm = 1; mm < 16; mm <<= 1) {
                    pcx += __shfl_xor(pcx, mm, 16);
                    pcq += __shfl_xor(pcq, mm, 16);
                }
                if (ccol == 0) {
                    atomicAdd(&cxc[gm], pcx);
                    atomicAdd(&cq[gm], pcq);
                }
            }
#pragma unroll
        for (int jj = 0; jj < 4; jj++) {
            int gn = n0 + wn * 64 + jj * 16 + ccol;
            unsigned long long o = __shfl_xor(best[jj], 16);
            if (o < best[jj]) best[jj] = o;
            o = __shfl_xor(best[jj], 32);
            if (o < best[jj]) best[jj] = o;
            if ((lane >> 4) == 0) atomicMin(&keys[gn], best[jj]);
        }
    } else {
        // MODE 3: Xd = acc -> G; denom partial = sum(d * Xd) -> scal3
        float part = 0.f;
#pragma unroll
        for (int mi = 0; mi < 8; mi++)
#pragma unroll
            for (int r = 0; r < 4; r++) {
                int gm = m0 + wm * 128 + mi * 16 + crow + r;
#pragma unroll
                for (int jj = 0; jj < 4; jj++) {
                    int gn = n0 + wn * 64 + jj * 16 + ccol;
                    size_t idx = (size_t)gm * A_DIM + gn;
                    float d = bf2f(Ahi[idx]) + bf2f(Alo[idx]);
                    float xd = acc[mi][jj][r];
                    G[idx] = xd;
                    part += xd * d;
                }
            }
        part = wave_sum(part);
        if (lane == 0) red[w] = part;
        __syncthreads();
        if (tid == 0) {
            float tot = red[0] + red[1] + red[2] + red[3] +
                        red[4] + red[5] + red[6] + red[7];
            atomicAdd(scal3, tot);
        }
    }
}

// ---------------- nondiff fused stream (G-tracking) ----------------
// 512 blocks x 512 thr; 8 waves x 4 rows. Applies c/G update from iter t-1
// (Kprev ballot masks, scalars), computes cg = c.G (lam numerator = cg -
// num_amg since cxc - cq == c.G), cq by sparse recurrence, argmin -> Kcur.
// lam==0 rows: only c+G read, no qt, no stores.
__global__ __launch_bounds__(512) void fgrad(const float* __restrict__ qt,
                                             unsigned short* __restrict__ Chi,
                                             unsigned short* __restrict__ Clo,
                                             float* __restrict__ G,
                                             const float* __restrict__ Xf,
                                             const unsigned long long* __restrict__ Kprev,
                                             unsigned long long* __restrict__ Kcur,
                                             float* __restrict__ cxc,
                                             float* __restrict__ cq,
                                             float* __restrict__ num_amg,
                                             const float* __restrict__ scalPrev,
                                             float* __restrict__ scalCur) {
    __shared__ unsigned long long lkeys[8][1024];   // 64 KiB
    int tid = threadIdx.x;
    if (blockIdx.x == 0 && tid < 4) scalCur[tid] = 0.f;   // other blocks read scalPrev only
    int w = tid >> 6, lane = tid & 63;
    int b0 = blockIdx.x * 32;
    float den = scalPrev[0] + scalPrev[1] - 2.f * scalPrev[2] + EPS_C;

    unsigned int klow[16];
#pragma unroll
    for (int s = 0; s < 16; s++) klow[s] = (unsigned int)Kprev[lane + s * 64];

    unsigned long long best[16];
#pragma unroll
    for (int i = 0; i < 16; i++) best[i] = ~0ULL;

    for (int rr = 0; rr < 4; ++rr) {
        int b = b0 + w + rr * 8;
        float cqold = cq[b];
        float lam = clamp01((cxc[b] - cqold - num_amg[b]) / den);
        float om = 1.f - lam;
        const bool active = (lam != 0.f);    // wave-uniform

        unsigned short* hr = Chi + (size_t)b * A_DIM;
        unsigned short* lr = Clo + (size_t)b * A_DIM;
        float* gr = G + (size_t)b * A_DIM;
        const float* qr = qt + (size_t)b * A_DIM;
        float cg = 0.f, sq = 0.f;

        if (active) {
            unsigned long long mask[16];
#pragma unroll
            for (int s = 0; s < 16; s++) mask[s] = __ballot(klow[s] == (unsigned int)b);
#pragma unroll
            for (int ch = 0; ch < 4; ++ch) {
                int col = ch * 256 + lane * 4;
                ushort4 hv = *(const ushort4*)(hr + col);
                ushort4 lv = *(const ushort4*)(lr + col);
                float4 gv = *(const float4*)(gr + col);
                float4 qv = *(const float4*)(qr + col);
                int sel = lane >> 4;
                unsigned long long mw =
                    (sel == 0) ? mask[ch * 4 + 0] :
                    (sel == 1) ? mask[ch * 4 + 1] :
                    (sel == 2) ? mask[ch * 4 + 2] : mask[ch * 4 + 3];
                unsigned int ind4 = (unsigned int)((mw >> ((lane & 15) * 4)) & 0xFULL);
                float c0 = om * (bf2f(hv.x) + bf2f(lv.x)) + ((ind4 & 1u) ? lam : 0.f);
                float c1 = om * (bf2f(hv.y) + bf2f(lv.y)) + ((ind4 & 2u) ? lam : 0.f);
                float c2 = om * (bf2f(hv.z) + bf2f(lv.z)) + ((ind4 & 4u) ? lam : 0.f);
                float c3 = om * (bf2f(hv.w) + bf2f(lv.w)) + ((ind4 & 8u) ? lam : 0.f);
                // G' = om*G + lam*T - lam*qt  (== XC' - qt exactly)
                gv.x *= om; gv.y *= om; gv.z *= om; gv.w *= om;
#pragma unroll
                for (int s = 0; s < 16; s++) {
                    unsigned long long m = mask[s];
                    while (m) {   // wave-uniform
                        int a = __ffsll(m) - 1 + s * 64;
                        m &= m - 1;
                        float4 av = *(const float4*)(Xf + (size_t)a * A_DIM + col);
                        gv.x += lam * av.x; gv.y += lam * av.y;
                        gv.z += lam * av.z; gv.w += lam * av.w;
                    }
                }
                gv.x -= lam * qv.x; gv.y -= lam * qv.y;
                gv.z -= lam * qv.z; gv.w -= lam * qv.w;
                // sparse cq term: sum of qt over matched atoms
                sq += ((ind4 & 1u) ? qv.x : 0.f) + ((ind4 & 2u) ? qv.y : 0.f) +
                      ((ind4 & 4u) ? qv.z : 0.f) + ((ind4 & 8u) ? qv.w : 0.f);
                split2(c0, hv.x, lv.x);
                split2(c1, hv.y, lv.y);
                split2(c2, hv.z, lv.z);
                split2(c3, hv.w, lv.w);
                *(ushort4*)(hr + col) = hv;
                *(ushort4*)(lr + col) = lv;
                *(float4*)(gr + col) = gv;
                cg += c0 * gv.x + c1 * gv.y + c2 * gv.z + c3 * gv.w;
                unsigned long long k0 = ((unsigned long long)fkey(gv.x) << 32) | (unsigned int)b;
                unsigned long long k1 = ((unsigned long long)fkey(gv.y) << 32) | (unsigned int)b;
                unsigned long long k2 = ((unsigned long long)fkey(gv.z) << 32) | (unsigned int)b;
                unsigned long long k3 = ((unsigned long long)fkey(gv.w) << 32) | (unsigned int)b;
                if (k0 < best[ch * 4 + 0]) best[ch * 4 + 0] = k0;
                if (k1 < best[ch * 4 + 1]) best[ch * 4 + 1] = k1;
                if (k2 < best[ch * 4 + 2]) best[ch * 4 + 2] = k2;
                if (k3 < best[ch * 4 + 3]) best[ch * 4 + 3] = k3;
            }
        } else {
            // lam == 0: c' = c, G' = G exactly -> no stores, no qt read
#pragma unroll
            for (int ch = 0; ch < 4; ++ch) {
                int col = ch * 256 + lane * 4;
                ushort4 hv = *(const ushort4*)(hr + col);
                ushort4 lv = *(const ushort4*)(lr + col);
                float4 gv = *(const float4*)(gr + col);
                float c0 = bf2f(hv.x) + bf2f(lv.x);
                float c1 = bf2f(hv.y) + bf2f(lv.y);
                float c2 = bf2f(hv.z) + bf2f(lv.z);
                float c3 = bf2f(hv.w) + bf2f(lv.w);
                cg += c0 * gv.x + c1 * gv.y + c2 * gv.z + c3 * gv.w;
                unsigned long long k0 = ((unsigned long long)fkey(gv.x) << 32) | (unsigned int)b;
                unsigned long long k1 = ((unsigned long long)fkey(gv.y) << 32) | (unsigned int)b;
                unsigned long long k2 = ((unsigned long long)fkey(gv.z) << 32) | (unsigned int)b;
                unsigned long long k3 = ((unsigned long long)fkey(gv.w) << 32) | (unsigned int)b;
                if (k0 < best[ch * 4 + 0]) best[ch * 4 + 0] = k0;
                if (k1 < best[ch * 4 + 1]) best[ch * 4 + 1] = k1;
                if (k2 < best[ch * 4 + 2]) best[ch * 4 + 2] = k2;
                if (k3 < best[ch * 4 + 3]) best[ch * 4 + 3] = k3;
            }
        }
        cg = wave_sum(cg);
        if (active) sq = wave_sum(sq);
        if (lane == 0) {
            float cqn = active ? (om * cqold + lam * sq) : cqold;
            cq[b] = cqn;          // row-owned
            cxc[b] = cg + cqn;    // c.Xc == c.G + c.q
            num_amg[b] = 0.f;     // reset for this iteration's stats atomics
        }
    }
#pragma unroll
    for (int ch = 0; ch < 4; ++ch)
#pragma unroll
        for (int j = 0; j < 4; ++j)
            lkeys[w][ch * 256 + lane * 4 + j] = best[ch * 4 + j];
    __syncthreads();
    for (int i = tid; i < 1024; i += 512) {
        unsigned long long v = lkeys[0][i];
        if (lkeys[1][i] < v) v = lkeys[1][i];
        if (lkeys[2][i] < v) v = lkeys[2][i];
        if (lkeys[3][i] < v) v = lkeys[3][i];
        if (lkeys[4][i] < v) v = lkeys[4][i];
        if (lkeys[5][i] < v) v = lkeys[5][i];
        if (lkeys[6][i] < v) v = lkeys[6][i];
        if (lkeys[7][i] < v) v = lkeys[7][i];
        atomicMin(&Kcur[i], v);
    }
}

// ---------------- setup kernels ----------------

__global__ __launch_bounds__(256) void ynorm_split_kernel(const float* __restrict__ y,
                                                          float* __restrict__ ynorm,
                                                          unsigned short* __restrict__ Ynh,
                                                          unsigned short* __restrict__ Ynl) {
    __shared__ float red[16];
    int b = blockIdx.x;
    const float* row = y + (size_t)b * D_DIM;
    float s = 0.f;
    for (int i = threadIdx.x; i < D_DIM; i += 256) s += fabsf(row[i]);
    float tot = block_reduce_sum(s, red);
    float inv = 1.f / tot;
    unsigned short* oh = Ynh + (size_t)b * D_DIM;
    unsigned short* ol = Ynl + (size_t)b * D_DIM;
    for (int i = threadIdx.x; i < D_DIM; i += 256) {
        unsigned short h, l;
        split2(row[i] * inv, h, l);
        oh[i] = h; ol[i] = l;
    }
    if (threadIdx.x == 0) ynorm[b] = tot;
}

__global__ __launch_bounds__(256) void anorm_kernel(const float* __restrict__ atoms,
                                                    float* __restrict__ an,
                                                    float* __restrict__ anrm,
                                                    unsigned short* __restrict__ Anh,
                                                    unsigned short* __restrict__ Anl) {
    __shared__ float red[16];
    int a = blockIdx.x;
    const float* row = atoms + (size_t)a * D_DIM;
    float s = 0.f;
    for (int i = threadIdx.x; i < D_DIM; i += 256) s += fabsf(row[i]);
    float tot = block_reduce_sum(s, red);
    float inv = 1.f / tot;
    for (int i = threadIdx.x; i < D_DIM; i += 256) {
        float v = row[i] * inv;
        an[(size_t)a * D_DIM + i] = v;
        unsigned short h, l;
        split2(v, h, l);
        Anh[(size_t)a * D_DIM + i] = h;
        Anl[(size_t)a * D_DIM + i] = l;
    }
    if (threadIdx.x == 0) anrm[a] = tot;
}

__global__ __launch_bounds__(256) void atrans_split_kernel(const float* __restrict__ atoms,
                                                           const float* __restrict__ anrm,
                                                           unsigned short* __restrict__ AnTh,
                                                           unsigned short* __restrict__ AnTl) {
    int n = blockIdx.x;
    for (int k = threadIdx.x; k < A_DIM; k += 256) {
        float v = atoms[(size_t)k * D_DIM + n] / anrm[k];
        unsigned short h, l;
        split2(v, h, l);
        AnTh[(size_t)n * A_DIM + k] = h;
        AnTl[(size_t)n * A_DIM + k] = l;
    }
}

__global__ __launch_bounds__(256) void split_kernel(const float* __restrict__ src,
                                                    unsigned short* __restrict__ hi,
                                                    unsigned short* __restrict__ lo,
                                                    int n4) {
    int i = blockIdx.x * 256 + threadIdx.x;
    if (i < n4) {
        float4 v = ((const float4*)src)[i];
        ushort4 h, l;
        split2(v.x, h.x, l.x);
        split2(v.y, h.y, l.y);
        split2(v.z, h.z, l.z);
        split2(v.w, h.w, l.w);
        ((ushort4*)hi)[i] = h;
        ((ushort4*)lo)[i] = l;
    }
}

__global__ __launch_bounds__(256) void fill_pair_kernel(unsigned short* __restrict__ Chi,
                                                        unsigned short* __restrict__ Clo,
                                                        size_t n4) {
    size_t i = (size_t)blockIdx.x * 256 + threadIdx.x;
    if (i < n4) {
        unsigned short h, l;
        split2(1.f / A_DIM, h, l);
        ((ushort4*)Chi)[i] = make_ushort4(h, h, h, h);
        ((ushort4*)Clo)[i] = make_ushort4(l, l, l, l);
    }
}

// fp32 vector GEMM, B transposed, setup only: X = an @ an^T
__global__ __launch_bounds__(256) void gemm_xt(const float* __restrict__ Aop,
                                               float* __restrict__ Cout) {
    const int LDT = 132;
    const int N = A_DIM, K = D_DIM;
    __shared__ float As[16 * LDT];
    __shared__ float Bs[16 * LDT];
    int m0 = blockIdx.y * 128, n0 = blockIdx.x * 128;
    int tid = threadIdx.x;
    int tx = tid & 15, ty = tid >> 4;
    float acc[8][8];
#pragma unroll
    for (int i = 0; i < 8; i++)
#pragma unroll
        for (int j = 0; j < 8; j++) acc[i][j] = 0.f;
    for (int k0 = 0; k0 < K; k0 += 16) {
#pragma unroll
        for (int s = 0; s < 2; s++) {
            int idx = tid + s * 256;
            int row = idx >> 2, kq = (idx & 3) * 4;
            float4 v = *(const float4*)(Aop + (size_t)(m0 + row) * K + k0 + kq);
            As[(kq + 0) * LDT + row] = v.x;
            As[(kq + 1) * LDT + row] = v.y;
            As[(kq + 2) * LDT + row] = v.z;
            As[(kq + 3) * LDT + row] = v.w;
        }
#pragma unroll
        for (int s = 0; s < 2; s++) {
            int idx = tid + s * 256;
            int row = idx >> 2, kq = (idx & 3) * 4;
            float4 v = *(const float4*)(Aop + (size_t)(n0 + row) * K + k0 + kq);
            Bs[(kq + 0) * LDT + row] = v.x;
            Bs[(kq + 1) * LDT + row] = v.y;
            Bs[(kq + 2) * LDT + row] = v.z;
            Bs[(kq + 3) * LDT + row] = v.w;
        }
        __syncthreads();
#pragma unroll
        for (int kk = 0; kk < 16; kk++) {
            float a[8], b[8];
            *(float4*)(a)     = *(const float4*)(As + kk * LDT + ty * 8);
            *(float4*)(a + 4) = *(const float4*)(As + kk * LDT + ty * 8 + 4);
            *(float4*)(b)     = *(const float4*)(Bs + kk * LDT + tx * 8);
            *(float4*)(b + 4) = *(const float4*)(Bs + kk * LDT + tx * 8 + 4);
#pragma unroll
            for (int i = 0; i < 8; i++)
#pragma unroll
                for (int j = 0; j < 8; j++) acc[i][j] = fmaf(a[i], b[j], acc[i][j]);
        }
        __syncthreads();
    }
#pragma unroll
    for (int i = 0; i < 8; i++) {
        int row = m0 + ty * 8 + i;
#pragma unroll
        for (int j = 0; j < 8; j += 4) {
            int col = n0 + tx * 8 + j;
            float4 v = make_float4(acc[i][j], acc[i][j + 1], acc[i][j + 2], acc[i][j + 3]);
            *(float4*)(Cout + (size_t)row * N + col) = v;
        }
    }
}

// qt = Yn @ An^T  (bf16x2 pair-pair MFMA, K=768), swizzled 1D grid of 1024
__global__ __launch_bounds__(256) void qt_mfma(const unsigned short* __restrict__ Ynh,
                                               const unsigned short* __restrict__ Ynl,
                                               const unsigned short* __restrict__ Anh,
                                               const unsigned short* __restrict__ Anl,
                                               float* __restrict__ qt) {
    __shared__ unsigned short lds[16384];
    int tid = threadIdx.x;
    int w = tid >> 6, lane = tid & 63;
    int wm = w >> 1, wn = w & 1;
    int m0, n0;
    swz(blockIdx.x, m0, n0);

    f32x4 acc[4][4];
#pragma unroll
    for (int i = 0; i < 4; i++)
#pragma unroll
        for (int j = 0; j < 4; j++) acc[i][j] = f32x4{0.f, 0.f, 0.f, 0.f};

    const unsigned short* gsrc;
    if (w == 0) gsrc = Ynh + (size_t)m0 * D_DIM;
    else if (w == 1) gsrc = Ynl + (size_t)m0 * D_DIM;
    else if (w == 2) gsrc = Anh + (size_t)n0 * D_DIM;
    else gsrc = Anl + (size_t)n0 * D_DIM;
    unsigned short* ltile = lds + w * 4096;
    for (int k0 = 0; k0 < D_DIM; k0 += 32) {
        stage_tile8(gsrc, D_DIM, k0, ltile, lane);
        __syncthreads();
        mfma_k32(lds, wm, wn, lane, acc);
        __syncthreads();
    }

    int crow = (lane >> 4) * 4, ccol = lane & 15;
#pragma unroll
    for (int i = 0; i < 4; i++) {
        int gm = m0 + wm * 64 + i * 16 + crow;
#pragma unroll
        for (int j = 0; j < 4; j++) {
            int gn = n0 + wn * 64 + j * 16 + ccol;
#pragma unroll
            for (int r = 0; r < 4; r++)
                qt[(size_t)(gm + r) * A_DIM + gn] = acc[i][j][r];
        }
    }
}

// ---------------- nondiff per-iteration kernels ----------------

// one-time init: both key banks, num_amg/cxc/cq, both scal banks
__global__ __launch_bounds__(256) void init_kernel(unsigned long long* __restrict__ keys,
                                                   float* __restrict__ num_amg,
                                                   float* __restrict__ cxc,
                                                   float* __restrict__ cq,
                                                   float* __restrict__ scal) {
    int i = blockIdx.x * 256 + threadIdx.x;
    num_amg[i] = 0.f;
    cxc[i] = 0.f;
    cq[i] = 0.f;
    if (i < 2 * A_DIM) keys[i] = ~0ULL;
    if (i < 8) scal[i] = 0.f;
}

// stats: block per atom a; reads Kcur, adds scalCur/num_amg; resets Knext[a].
__global__ __launch_bounds__(256) void stats_kernel(const float* __restrict__ Xf,
                                                    const unsigned long long* __restrict__ Kcur,
                                                    const unsigned short* __restrict__ Chi,
                                                    const unsigned short* __restrict__ Clo,
                                                    const float* __restrict__ qt,
                                                    const float* __restrict__ cxc,
                                                    float* __restrict__ num_amg,
                                                    float* __restrict__ scalCur,
                                                    unsigned long long* __restrict__ Knext) {
    __shared__ float red[16];
    int a = blockIdx.x;
    int ba = (int)(unsigned int)(Kcur[a] & 0xFFFFFFFFULL);
    const float* xr = Xf + (size_t)a * A_DIM;
    const unsigned short* ch = Chi + (size_t)ba * A_DIM;
    const unsigned short* cl = Clo + (size_t)ba * A_DIM;
    float ps = 0.f, xs = 0.f;
    for (int i = threadIdx.x; i < A_DIM; i += 256) {
        float xv = xr[i];
        if ((int)(unsigned int)(Kcur[i] & 0xFFFFFFFFULL) == ba) ps += xv;
        xs += xv * (bf2f(ch[i]) + bf2f(cl[i]));
    }
    float s1p = (threadIdx.x < 16) ? cxc[(a << 4) + threadIdx.x] : 0.f;
    block_reduce_sum3(ps, xs, s1p, red);
    if (threadIdx.x == 0) {
        atomicAdd(&scalCur[0], ps);
        atomicAdd(&scalCur[2], xs);
        atomicAdd(&scalCur[1], s1p);
        atomicAdd(&num_amg[ba], xs - qt[(size_t)ba * A_DIM + a]);
        Knext[a] = ~0ULL;     // reset other bank for next iteration's argmin
    }
}

// thin update before a refresh GEMM: c only (refresh rewrites G exactly);
// resets cxc/cq/num_amg for the refresh's atomicAdds.
__global__ __launch_bounds__(256) void ndupdate_c(unsigned short* __restrict__ Chi,
                                                  unsigned short* __restrict__ Clo,
                                                  const unsigned long long* __restrict__ Kprev,
                                                  float* __restrict__ cxc,
                                                  float* __restrict__ cq,
                                                  float* __restrict__ num_amg,
                                                  const float* __restrict__ scalPrev) {
    int b = blockIdx.x;
    float den = scalPrev[0] + scalPrev[1] - 2.f * scalPrev[2] + EPS_C;
    float lam = clamp01((cxc[b] - cq[b] - num_amg[b]) / den);
    float om = 1.f - lam;
    int i = threadIdx.x;
    ushort4* h4 = (ushort4*)(Chi + (size_t)b * A_DIM);
    ushort4* l4 = (ushort4*)(Clo + (size_t)b * A_DIM);
    ushort4 h = h4[i], l = l4[i];
    int b0 = (int)(unsigned int)Kprev[i * 4 + 0];
    int b1 = (int)(unsigned int)Kprev[i * 4 + 1];
    int b2 = (int)(unsigned int)Kprev[i * 4 + 2];
    int b3 = (int)(unsigned int)Kprev[i * 4 + 3];
    float c0 = om * (bf2f(h.x) + bf2f(l.x)) + ((b0 == b) ? lam : 0.f);
    float c1 = om * (bf2f(h.y) + bf2f(l.y)) + ((b1 == b) ? lam : 0.f);
    float c2 = om * (bf2f(h.z) + bf2f(l.z)) + ((b2 == b) ? lam : 0.f);
    float c3 = om * (bf2f(h.w) + bf2f(l.w)) + ((b3 == b) ? lam : 0.f);
    split2(c0, h.x, l.x);
    split2(c1, h.y, l.y);
    split2(c2, h.z, l.z);
    split2(c3, h.w, l.w);
    h4[i] = h; l4[i] = l;
    __syncthreads();
    if (i == 0) {
        cxc[b] = 0.f;
        cq[b] = 0.f;
        num_amg[b] = 0.f;
    }
}

// full update after iter 29: c + G recurrence (diff needs G_30 = Xc_30 - qt)
__global__ __launch_bounds__(256) void ndupdate_full(unsigned short* __restrict__ Chi,
                                                     unsigned short* __restrict__ Clo,
                                                     const unsigned long long* __restrict__ Kprev,
                                                     const float* __restrict__ cxc,
                                                     const float* __restrict__ cq,
                                                     const float* __restrict__ num_amg,
                                                     const float* __restrict__ scalPrev,
                                                     float* __restrict__ G,
                                                     const float* __restrict__ Xf,
                                                     const float* __restrict__ qt) {
    __shared__ int mlist[1024];
    __shared__ int mcount;
    int b = blockIdx.x;
    int i = threadIdx.x;
    if (i == 0) mcount = 0;
    float den = scalPrev[0] + scalPrev[1] - 2.f * scalPrev[2] + EPS_C;
    float lam = clamp01((cxc[b] - cq[b] - num_amg[b]) / den);
    float om = 1.f - lam;
    ushort4* h4 = (ushort4*)(Chi + (size_t)b * A_DIM);
    ushort4* l4 = (ushort4*)(Clo + (size_t)b * A_DIM);
    ushort4 h = h4[i], l = l4[i];
    int b0 = (int)(unsigned int)Kprev[i * 4 + 0];
    int b1 = (int)(unsigned int)Kprev[i * 4 + 1];
    int b2 = (int)(unsigned int)Kprev[i * 4 + 2];
    int b3 = (int)(unsigned int)Kprev[i * 4 + 3];
    float c0 = om * (bf2f(h.x) + bf2f(l.x)) + ((b0 == b) ? lam : 0.f);
    float c1 = om * (bf2f(h.y) + bf2f(l.y)) + ((b1 == b) ? lam : 0.f);
    float c2 = om * (bf2f(h.z) + bf2f(l.z)) + ((b2 == b) ? lam : 0.f);
    float c3 = om * (bf2f(h.w) + bf2f(l.w)) + ((b3 == b) ? lam : 0.f);
    split2(c0, h.x, l.x);
    split2(c1, h.y, l.y);
    split2(c2, h.z, l.z);
    split2(c3, h.w, l.w);
    h4[i] = h; l4[i] = l;
    __syncthreads();
    for (int a = i; a < A_DIM; a += 256)
        if ((int)(unsigned int)Kprev[a] == b) { int p = atomicAdd(&mcount, 1); mlist[p] = a; }
    __syncthreads();
    float4 gv = *(float4*)(G + (size_t)b * A_DIM + i * 4);
    float4 qv = *(const float4*)(qt + (size_t)b * A_DIM + i * 4);
    gv.x *= om; gv.y *= om; gv.z *= om; gv.w *= om;
    int mc = mcount;
    for (int m = 0; m < mc; m++) {
        float4 av = *(const float4*)(Xf + (size_t)mlist[m] * A_DIM + i * 4);
        gv.x += lam * av.x; gv.y += lam * av.y;
        gv.z += lam * av.z; gv.w += lam * av.w;
    }
    gv.x -= lam * qv.x; gv.y -= lam * qv.y;
    gv.z -= lam * qv.z; gv.w -= lam * qv.w;
    *(float4*)(G + (size_t)b * A_DIM + i * 4) = gv;
}

// ---------------- diff-phase kernels ----------------

// one-time softmax at diff entry: d_0 = sm(G_30) - c_0, num_cg_0; resets scal3 slot0
__global__ __launch_bounds__(256) void softmax_kernel(const float* __restrict__ R,
                                                      unsigned short* __restrict__ Chi,
                                                      unsigned short* __restrict__ Clo,
                                                      float* __restrict__ num_cg,
                                                      float* __restrict__ scal3) {
    __shared__ float red[16];
    int b = blockIdx.x;
    int i = threadIdx.x;
    if (b == 0 && i == 0) *scal3 = 0.f;
    const float4* g4 = (const float4*)(R + (size_t)b * A_DIM);
    ushort4* h4 = (ushort4*)(Chi + (size_t)b * A_DIM);
    ushort4* l4 = (ushort4*)(Clo + (size_t)b * A_DIM);
    float4 g = g4[i];
    ushort4 h = h4[i], l = l4[i];
    float c0 = bf2f(h.x) + bf2f(l.x);
    float c1 = bf2f(h.y) + bf2f(l.y);
    float c2 = bf2f(h.z) + bf2f(l.z);
    float c3 = bf2f(h.w) + bf2f(l.w);
    float4 t = make_float4(-TEMP_C * g.x, -TEMP_C * g.y, -TEMP_C * g.z, -TEMP_C * g.w);
    float m = fmaxf(fmaxf(t.x, t.y), fmaxf(t.z, t.w));
    float M = block_reduce_max(m, red);
    float4 e = make_float4(expf(t.x - M), expf(t.y - M), expf(t.z - M), expf(t.w - M));
    float S = block_reduce_sum(e.x + e.y + e.z + e.w, red);
    float inv = 1.f / S;
    float4 sm = make_float4(e.x * inv, e.y * inv, e.z * inv, e.w * inv);
    float np = (c0 - sm.x) * g.x + (c1 - sm.y) * g.y + (c2 - sm.z) * g.z + (c3 - sm.w) * g.w;
    split2(sm.x - c0, h.x, l.x);
    split2(sm.y - c1, h.y, l.y);
    split2(sm.z - c2, h.z, l.z);
    split2(sm.w - c3, h.w, l.w);
    h4[i] = h; l4[i] = l;
    float nt = block_reduce_sum(np, red);
    if (i == 0) num_cg[b] = nt;
}

// fused diff update: sm_t from R_t -> lam -> c_{t+1} = sm_t - om*d_t;
// R_{t+1} = R_t + lam*Xd; if !LAST: sm_{t+1}, d_{t+1} -> Chi/Clo, num_{t+1};
// else write c_{t+1}. Resets the OTHER scal3 slot (s3next) for the next GEMM.
template <int LAST>
__global__ __launch_bounds__(256) void dupdate_fused(float* __restrict__ R,
                                                     const float* __restrict__ Xd,
                                                     unsigned short* __restrict__ Chi,
                                                     unsigned short* __restrict__ Clo,
                                                     float* __restrict__ num_cg,
                                                     const float* __restrict__ s3cur,
                                                     float* __restrict__ s3next) {
    __shared__ float red[16];
    int b = blockIdx.x;
    int i = threadIdx.x;
    if (!LAST && b == 0 && i == 0) *s3next = 0.f;
    float4* r4 = (float4*)(R + (size_t)b * A_DIM);
    float4 g = r4[i];
    // sm_t (bitwise-identical sequence to softmax_kernel)
    float4 t = make_float4(-TEMP_C * g.x, -TEMP_C * g.y, -TEMP_C * g.z, -TEMP_C * g.w);
    float m = fmaxf(fmaxf(t.x, t.y), fmaxf(t.z, t.w));
    float M = block_reduce_max(m, red);
    float4 e = make_float4(expf(t.x - M), expf(t.y - M), expf(t.z - M), expf(t.w - M));
    float S = block_reduce_sum(e.x + e.y + e.z + e.w, red);
    float inv = 1.f / S;
    float4 sm = make_float4(e.x * inv, e.y * inv, e.z * inv, e.w * inv);
    float den = *s3cur + EPS_C;
    float lam = clamp01(num_cg[b] / den);
    float om = 1.f - lam;
    ushort4* h4 = (ushort4*)(Chi + (size_t)b * A_DIM);
    ushort4* l4 = (ushort4*)(Clo + (size_t)b * A_DIM);
    ushort4 h = h4[i], l = l4[i];          // d_t
    float c0 = sm.x - om * (bf2f(h.x) + bf2f(l.x));
    float c1 = sm.y - om * (bf2f(h.y) + bf2f(l.y));
    float c2 = sm.z - om * (bf2f(h.z) + bf2f(l.z));
    float c3 = sm.w - om * (bf2f(h.w) + bf2f(l.w));
    float4 xd = ((const float4*)(Xd + (size_t)b * A_DIM))[i];
    g.x += lam * xd.x; g.y += lam * xd.y;
    g.z += lam * xd.z; g.w += lam * xd.w;
    r4[i] = g;                              // R_{t+1}
    if (LAST) {
        split2(c0, h.x, l.x);
        split2(c1, h.y, l.y);
        split2(c2, h.z, l.z);
        split2(c3, h.w, l.w);
        h4[i] = h; l4[i] = l;
    } else {
        // sm_{t+1} from R_{t+1}
        float4 t2 = make_float4(-TEMP_C * g.x, -TEMP_C * g.y, -TEMP_C * g.z, -TEMP_C * g.w);
        float m2 = fmaxf(fmaxf(t2.x, t2.y), fmaxf(t2.z, t2.w));
        float M2 = block_reduce_max(m2, red);
        float4 e2 = make_float4(expf(t2.x - M2), expf(t2.y - M2),
                                expf(t2.z - M2), expf(t2.w - M2));
        float S2 = block_reduce_sum(e2.x + e2.y + e2.z + e2.w, red);
        float inv2 = 1.f / S2;
        float4 sm2 = make_float4(e2.x * inv2, e2.y * inv2, e2.z * inv2, e2.w * inv2);
        float np = (c0 - sm2.x) * g.x + (c1 - sm2.y) * g.y +
                   (c2 - sm2.z) * g.z + (c3 - sm2.w) * g.w;
        split2(sm2.x - c0, h.x, l.x);
        split2(sm2.y - c1, h.y, l.y);
        split2(sm2.z - c2, h.z, l.z);
        split2(sm2.w - c3, h.w, l.w);
        h4[i] = h; l4[i] = l;               // d_{t+1}
        float nt = block_reduce_sum(np, red);
        if (i == 0) num_cg[b] = nt;
    }
}

// recon: out[b, n] = (c_b . anT[:,n]) * ynorm[b]
__global__ __launch_bounds__(256) void mfma_recon(const unsigned short* __restrict__ Chi,
                                                  const unsigned short* __restrict__ Clo,
                                                  const unsigned short* __restrict__ AnTh,
                                                  const unsigned short* __restrict__ AnTl,
                                                  const float* __restrict__ ynorm,
                                                  float* __restrict__ out) {
    __shared__ unsigned short lds[16384];
    int tid = threadIdx.x;
    int w = tid >> 6, lane = tid & 63;
    int wm = w >> 1, wn = w & 1;
    int m0 = blockIdx.y * 128, n0 = blockIdx.x * 128;

    f32x4 acc[4][4];
#pragma unroll
    for (int i = 0; i < 4; i++)
#pragma unroll
        for (int j = 0; j < 4; j++) acc[i][j] = f32x4{0.f, 0.f, 0.f, 0.f};

    const unsigned short* gsrc;
    if (w == 0) gsrc = Chi + (size_t)m0 * A_DIM;
    else if (w == 1) gsrc = Clo + (size_t)m0 * A_DIM;
    else if (w == 2) gsrc = AnTh + (size_t)n0 * A_DIM;
    else gsrc = AnTl + (size_t)n0 * A_DIM;
    unsigned short* ltile = lds + w * 4096;
    for (int k0 = 0; k0 < A_DIM; k0 += 32) {
        stage_tile8(gsrc, A_DIM, k0, ltile, lane);
        __syncthreads();
        mfma_k32(lds, wm, wn, lane, acc);
        __syncthreads();
    }

    int crow = (lane >> 4) * 4, ccol = lane & 15;
#pragma unroll
    for (int i = 0; i < 4; i++) {
        int gm = m0 + wm * 64 + i * 16 + crow;
#pragma unroll
        for (int j = 0; j < 4; j++) {
            int gn = n0 + wn * 64 + j * 16 + ccol;
#pragma unroll
            for (int r = 0; r < 4; r++)
                out[(size_t)(gm + r) * D_DIM + gn] = acc[i][j][r] * ynorm[gm + r];
        }
    }
}

// ---------------- host launch ----------------

extern "C" void kernel_launch(void* const* d_in, const int* in_sizes, int n_in,
                              void* d_out, int out_size, void* d_ws, size_t ws_size,
                              hipStream_t stream) {
    const float* y = (const float*)d_in[0];      // [B, 768]
    const float* atoms = (const float*)d_in[1];  // [A, 768]
    float* out = (float*)d_out;                  // [B, 768]

    char* ws = (char*)d_ws;
    size_t off = 0;
    auto alloc = [&](size_t bytes) -> void* {
        void* p = ws + off;
        off += (bytes + 255) & ~(size_t)255;
        return p;
    };
    const size_t BA = (size_t)B_DIM * A_DIM;
    unsigned short* Chi = (unsigned short*)alloc(BA * 2);            // 32 MiB
    unsigned short* Clo = (unsigned short*)alloc(BA * 2);            // 32 MiB
    float* Greg = (float*)alloc(BA * 4);                             // 64 MiB (aliased)
    float* qt = (float*)alloc(BA * 4);                               // 64 MiB (-> Xd in diff)
    unsigned short* Xhi = (unsigned short*)alloc((size_t)A_DIM * A_DIM * 2);  // 2 MiB
    unsigned short* Xlo = (unsigned short*)alloc((size_t)A_DIM * A_DIM * 2);  // 2 MiB
    float* Xf = (float*)alloc((size_t)A_DIM * A_DIM * 4);            // 4 MiB
    float* ynorm = (float*)alloc(B_DIM * 4);
    float* anrm  = (float*)alloc(A_DIM * 4);
    float* cxc   = (float*)alloc(B_DIM * 4);
    float* cq    = (float*)alloc(B_DIM * 4);
    float* num_amg = (float*)alloc(B_DIM * 4);
    float* num_cg  = (float*)alloc(B_DIM * 4);
    unsigned long long* keys = (unsigned long long*)alloc(2 * A_DIM * 8);  // K0 | K1
    float* scal = (float*)alloc(256);   // banks: [0..3] and [4..7]; s3 slots 3/7
    (void)ws_size; (void)in_sizes; (void)n_in; (void)out_size;

    // Greg aliases:
    float* an = Greg;                                                 // 3 MiB
    unsigned short* Anh = (unsigned short*)(an + (size_t)A_DIM * D_DIM);          // 1.5 MiB
    unsigned short* Anl = Anh + (size_t)A_DIM * D_DIM;                            // 1.5 MiB
    unsigned short* Ynh = Anl + (size_t)A_DIM * D_DIM;                            // 24 MiB
    unsigned short* Ynl = Ynh + (size_t)B_DIM * D_DIM;                            // 24 MiB
    float* G = Greg;                                                  // nondiff grad / diff R
    float* Xd = qt;                                                   // diff phase
    unsigned short* AnTh = (unsigned short*)Greg;                     // post-diff recon
    unsigned short* AnTl = (unsigned short*)Greg + (size_t)D_DIM * A_DIM;

    // ---- setup ----
    ynorm_split_kernel<<<B_DIM, 256, 0, stream>>>(y, ynorm, Ynh, Ynl);
    anorm_kernel<<<A_DIM, 256, 0, stream>>>(atoms, an, anrm, Anh, Anl);
    gemm_xt<<<dim3(A_DIM / 128, A_DIM / 128), 256, 0, stream>>>(an, Xf);
    split_kernel<<<A_DIM * A_DIM / 4 / 256, 256, 0, stream>>>(Xf, Xhi, Xlo, A_DIM * A_DIM / 4);
    qt_mfma<<<1024, 256, 0, stream>>>(Ynh, Ynl, Anh, Anl, qt);
    fill_pair_kernel<<<(int)(BA / 4 / 256), 256, 0, stream>>>(Chi, Clo, BA / 4);
    init_kernel<<<B_DIM / 256, 256, 0, stream>>>(keys, num_amg, cxc, cq, scal);

    // ---- 30 nondiff steps (refresh at t=0,16 only; G-tracking otherwise) ----
    for (int t = 0; t < 30; t++) {
        int cur = t & 1, prev = 1 - cur;
        unsigned long long* Kcur = keys + cur * A_DIM;
        unsigned long long* Kprev = keys + prev * A_DIM;
        unsigned long long* Knext = keys + ((t + 1) & 1) * A_DIM;
        float* sCur = scal + cur * 4;
        float* sPrev = scal + prev * 4;
        if (t == 0 || t == 16) {
            // refresh (even t -> Kcur = K0, sCur = scal[0..3]; gemm resets scal[0..3])
            gemm256<0><<<256, 512, 0, stream>>>(Chi, Clo, Xhi, Xlo, qt,
                                                Kcur, cxc, cq, scal, nullptr, nullptr, G);
        } else {
            fgrad<<<512, 512, 0, stream>>>(qt, Chi, Clo, G, Xf, Kprev, Kcur,
                                           cxc, cq, num_amg, sPrev, sCur);
        }
        stats_kernel<<<A_DIM, 256, 0, stream>>>(Xf, Kcur, Chi, Clo, qt, cxc,
                                                num_amg, sCur, Knext);
        if (t == 15)
            ndupdate_c<<<B_DIM, 256, 0, stream>>>(Chi, Clo, Kcur, cxc, cq,
                                                  num_amg, sCur);
        if (t == 29)
            ndupdate_full<<<B_DIM, 256, 0, stream>>>(Chi, Clo, Kcur, cxc, cq,
                                                     num_amg, sCur, G, Xf, qt);
    }

    // ---- 10 diff steps: R (= G buffer) tracking + fused softmax/update ----
    softmax_kernel<<<B_DIM, 256, 0, stream>>>(G, Chi, Clo, num_cg, &scal[3]);
    for (int t = 0; t < 10; t++) {
        float* s3cur = &scal[3 + (t & 1) * 4];
        float* s3next = &scal[3 + ((t + 1) & 1) * 4];
        gemm256<3><<<256, 512, 0, stream>>>(Chi, Clo, Xhi, Xlo, nullptr,
                                            nullptr, nullptr, nullptr, nullptr,
                                            Xd, s3cur, nullptr);
        if (t < 9)
            dupdate_fused<0><<<B_DIM, 256, 0, stream>>>(G, Xd, Chi, Clo, num_cg,
                                                        s3cur, s3next);
        else
            dupdate_fused<1><<<B_DIM, 256, 0, stream>>>(G, Xd, Chi, Clo, num_cg,
                                                        s3cur, nullptr);
    }

    // ---- recon ----
    atrans_split_kernel<<<D_DIM, 256, 0, stream>>>(atoms, anrm, AnTh, AnTl);
    mfma_recon<<<dim3(D_DIM / 128, B_DIM / 128), 256, 0, stream>>>(Chi, Clo, AnTh, AnTl,
                                                                   ynorm, out);
}